// Round 6
// baseline (2519.298 us; speedup 1.0000x reference)
//
#include <hip/hip_runtime.h>
#include <cmath>

typedef unsigned short ushort_t;
typedef __attribute__((ext_vector_type(8))) short bf16x8;
typedef __attribute__((ext_vector_type(4))) float f32x4;

// Problem constants (B=2, C=64, H=W=256)
static constexpr int Bn   = 2;
static constexpr int Hn   = 256;
static constexpr int Wn   = 256;
static constexpr int HW   = Hn * Wn;          // 65536
static constexpr int CHW  = 64 * HW;          // 4194304
static constexpr int NCHW = Bn * CHW;         // 8388608
static constexpr int NPIX = Bn * HW;          // 131072
static constexpr float EPSv = 1e-5f;
static constexpr float INV_N = 1.0f / 131072.0f;   // BN count = B*H*W
static constexpr int NSLOT = 64;              // stats slot replication (anti-contention)
static constexpr int STSLOT = NSLOT * 128;    // floats per layer stats region
static constexpr int WFL = 73728;             // ushorts per weight-fragment layer slot

// bf16 round-to-nearest-even (no NaN inputs in this net)
__device__ inline uint32_t bf16_rne(float f) {
  uint32_t u = __float_as_uint(f);
  return (u + 0x7FFFu + ((u >> 16) & 1u)) >> 16;
}
__device__ inline void split_hl(float v, uint32_t& h, uint32_t& l) {
  h = bf16_rne(v);
  l = bf16_rne(v - __uint_as_float(h << 16)) & 0xFFFFu;
}
__device__ inline bf16x8 lds_ld16(const ushort_t* p) {   // 2x ds_read_b64
  union { bf16x8 v; uint2 u[2]; } r;
  r.u[0] = *(const uint2*)p;
  r.u[1] = *(const uint2*)(p + 4);
  return r.v;
}

// async global->LDS, 16B per lane: LDS dest = wave-uniform base + lane*16,
// global src is per-lane (carries the XOR swizzle + OOB zero-page redirect).
typedef __attribute__((address_space(1))) const void glb_void;
typedef __attribute__((address_space(3))) void lds_void;
__device__ inline void gld_lds16(const void* g, void* l) {
  __builtin_amdgcn_global_load_lds((glb_void*)g, (lds_void*)l, 16, 0, 0);
}

// ---------------------------------------------------------------------------
__global__ void transpose_w_kernel(const float* __restrict__ in, float* __restrict__ out,
                                   int NB, int OC, int IC, int K) {
  int total = NB * OC * IC * K;
  for (int i = blockIdx.x * blockDim.x + threadIdx.x; i < total; i += gridDim.x * blockDim.x) {
    int k  = i % K;
    int t  = i / K;
    int ic = t % IC; t /= IC;
    int oc = t % OC;
    int nb = t / OC;
    out[(((size_t)nb * IC + ic) * K + k) * OC + oc] = in[i];
  }
}

// ---------------------------------------------------------------------------
// Weight fragment prep: w[oc][ic][3][3] f32 -> MFMA B-frag order, bf16 hi/lo.
__global__ void prep_wfrag(const float* __restrict__ w, ushort_t* __restrict__ out,
                           int NGp, int ocreal, int wlstride, int olstride) {
  int layer = blockIdx.y;
  int elems = 9 * 2 * NGp * 64 * 8;
  int idx = blockIdx.x * 256 + threadIdx.x;
  if (idx >= elems) return;
  int j = idx & 7, lane = (idx >> 3) & 63;
  int rest = idx >> 9;
  int g = rest % NGp; rest /= NGp;
  int ih = rest & 1, tap = rest >> 1;
  int oc = g * 16 + (lane & 15);
  int ic = ih * 32 + (lane >> 4) * 8 + j;
  float v = 0.0f;
  if (oc < ocreal) v = w[(size_t)layer * wlstride + (oc * 64 + ic) * 9 + tap];
  uint32_t hi, lo;
  split_hl(v, hi, lo);
  out[(size_t)layer * olstride + idx] = (ushort_t)hi;
  out[(size_t)layer * olstride + elems + idx] = (ushort_t)lo;
}

// ---------------------------------------------------------------------------
__global__ void prep_kernel(const float* __restrict__ LowDEM, const float* __restrict__ Point_Ele,
                            const float* __restrict__ Slope, const float* __restrict__ Distance,
                            const float* __restrict__ Level, const float* __restrict__ w0,
                            const float* __restrict__ b0, float* __restrict__ x0) {
  int i = blockIdx.x * blockDim.x + threadIdx.x;
  if (i >= NPIX) return;
  float lv  = Level[i];
  float err = w0[0] * Slope[i] + w0[1] * Distance[i] + w0[2] * lv + b0[0];
  float lm  = (lv != 0.0f) ? 1.0f : 0.0f;
  x0[i] = LowDEM[i] * (1.0f - lm) + Point_Ele[i] + err * lm;
}

// ---------------------------------------------------------------------------
// conv9x9: when hiP != nullptr (fused path) writes X in HWC fp32 layout AND
// the bf16 hi/lo HWC planes; else planar NCHW (legacy).
__global__ __launch_bounds__(256, 2)
void conv9x9_kernel(const float* __restrict__ in, const float* __restrict__ wT,
                    const float* __restrict__ bias, float* __restrict__ out,
                    uint32_t* __restrict__ hiP, uint32_t* __restrict__ loP) {
  const int tx = threadIdx.x & 15, ty = threadIdx.x >> 4;
  const int w0 = blockIdx.x * 16, h0 = blockIdx.y * 16, b = blockIdx.z;
  __shared__ float lds[24 * 24];
  for (int idx = threadIdx.x; idx < 576; idx += 256) {
    int yy = idx / 24, xx = idx - yy * 24;
    int gy = h0 + yy - 4, gx = w0 + xx - 4;
    float v = 0.0f;
    if ((unsigned)gy < 256u && (unsigned)gx < 256u) v = in[b * HW + gy * 256 + gx];
    lds[idx] = v;
  }
  __syncthreads();
  float acc[64];
#pragma unroll
  for (int o = 0; o < 64; o++) acc[o] = 0.0f;
#pragma unroll 1
  for (int i = 0; i < 9; i++) {
#pragma unroll
    for (int j = 0; j < 9; j++) {
      float v = lds[(ty + i) * 24 + tx + j];
      const float* wp = wT + (i * 9 + j) * 64;   // uniform -> s_load
#pragma unroll
      for (int o = 0; o < 64; o++) acc[o] = fmaf(v, wp[o], acc[o]);
    }
  }
  const int p = (h0 + ty) * 256 + (w0 + tx);
  if (hiP) {
    float* op = out + ((size_t)b * HW + p) * 64;      // HWC fp32
#pragma unroll
    for (int o4 = 0; o4 < 16; o4++) {
      float4 v;
      v.x = acc[o4 * 4 + 0] + bias[o4 * 4 + 0];
      v.y = acc[o4 * 4 + 1] + bias[o4 * 4 + 1];
      v.z = acc[o4 * 4 + 2] + bias[o4 * 4 + 2];
      v.w = acc[o4 * 4 + 3] + bias[o4 * 4 + 3];
      *(float4*)(op + o4 * 4) = v;
    }
    uint32_t* hb = hiP + ((size_t)b * HW + p) * 32;
    uint32_t* lb = loP + ((size_t)b * HW + p) * 32;
#pragma unroll
    for (int o2 = 0; o2 < 32; o2++) {
      float v0 = acc[o2 * 2] + bias[o2 * 2];
      float v1 = acc[o2 * 2 + 1] + bias[o2 * 2 + 1];
      uint32_t h0v, l0v, h1v, l1v;
      split_hl(v0, h0v, l0v);
      split_hl(v1, h1v, l1v);
      hb[o2] = h0v | (h1v << 16);
      lb[o2] = l0v | (l1v << 16);
    }
  } else {
    float* op = out + (size_t)b * CHW + p;            // planar (legacy)
#pragma unroll
    for (int o = 0; o < 64; o++) op[o * HW] = acc[o] + bias[o];
  }
}

// ---------------------------------------------------------------------------
// OLD-STYLE MFMA conv3x3 (VALU-transform staging). Used for dc3/dc4 offset
// convs (INHWC) and the legacy (small-ws) path.
// MODE 0 plain / 1 relu(bn) / 2 bn+skip (WRITEY: materialize y). INHWC:
// pixel-major input.
// ---------------------------------------------------------------------------
template <int NG, int MODE, int STATS, int OCLIM, int HASBIAS, int WRITEY, int INHWC>
__global__ __launch_bounds__(256, 3)
void mfma_conv3(const float* __restrict__ in, const float* __restrict__ skip,
                const ushort_t* __restrict__ wf,
                const float* __restrict__ bias, const float* __restrict__ stats_in,
                const float* __restrict__ gg, const float* __restrict__ be,
                float* __restrict__ stats_out, float* __restrict__ yout,
                float* __restrict__ out) {
  const int tid  = threadIdx.x;
  const int lane = tid & 63, wid = tid >> 6;
  const int m = lane & 15, quad = lane >> 4;
  const int x0 = blockIdx.x * 16, y0 = blockIdx.y * 4, b = blockIdx.z;
  constexpr int WT = 2 * NG * 64 * 8;          // ushorts per tap per plane
  __shared__ __align__(16) ushort_t xh[108 * 68];   // hi plane, [spat][ch]
  __shared__ __align__(16) ushort_t xl[108 * 68];   // lo plane
  __shared__ float s_sc[MODE ? 64 : 1], s_sh[MODE ? 64 : 1];
  __shared__ float red[STATS ? 2 * 4 * 64 : 1];
  if (MODE) {
    if (tid < 64) {
      float sum = 0.0f, sq = 0.0f;
      for (int sl = 0; sl < NSLOT; sl++) {
        sum += stats_in[sl * 128 + tid];
        sq  += stats_in[sl * 128 + 64 + tid];
      }
      float mn = sum * INV_N, var = sq * INV_N - mn * mn;
      float s = gg[tid] * rsqrtf(var + EPSv);
      s_sc[tid] = s;
      s_sh[tid] = be[tid] - mn * s;
    }
    __syncthreads();
  }
  const float* inb = in + (size_t)b * CHW;
  const float* skb = MODE == 2 ? skip + (size_t)b * CHW : nullptr;
  float* ytb = WRITEY ? yout + (size_t)b * CHW : nullptr;
  uint32_t* xh32 = (uint32_t*)xh;              // row stride 34 dwords
  uint32_t* xl32 = (uint32_t*)xl;
#pragma unroll
  for (int t = 0; t < 14; t++) {
    int idx = t * 256 + tid;                   // 3456 = 108 spat * 32 ic-pairs
    if (idx < 3456) {
      int r, icp;
      if (INHWC) { icp = idx & 31; r = idx >> 5; }   // tid-contig ic -> coalesced HWC
      else       { r = idx % 108; icp = idx / 108; } // tid-contig px -> coalesced NCHW
      int row = r / 18, col = r - row * 18;
      int gy = y0 - 1 + row, gx = x0 - 1 + col;
      float v0 = 0.0f, v1 = 0.0f;
      if ((unsigned)gy < 256u && (unsigned)gx < 256u) {
        int ic = icp * 2;
        if (INHWC) {
          float2 vv = *(const float2*)&inb[(size_t)(gy * 256 + gx) * 64 + ic];
          v0 = vv.x; v1 = vv.y;
        } else {
          v0 = inb[ic * HW + gy * 256 + gx];
          v1 = inb[(ic + 1) * HW + gy * 256 + gx];
        }
        if (MODE == 1) {
          v0 = fmaxf(fmaf(v0, s_sc[ic], s_sh[ic]), 0.0f);
          v1 = fmaxf(fmaf(v1, s_sc[ic + 1], s_sh[ic + 1]), 0.0f);
        }
        if (MODE == 2) {
          v0 = fmaf(v0, s_sc[ic], s_sh[ic]) + skb[ic * HW + gy * 256 + gx];
          v1 = fmaf(v1, s_sc[ic + 1], s_sh[ic + 1]) + skb[(ic + 1) * HW + gy * 256 + gx];
          if (WRITEY && row >= 1 && row <= 4 && col >= 1 && col <= 16) {
            ytb[ic * HW + gy * 256 + gx] = v0;
            ytb[(ic + 1) * HW + gy * 256 + gx] = v1;
          }
        }
      }
      uint32_t h0, l0, h1, l1;
      split_hl(v0, h0, l0);
      split_hl(v1, h1, l1);
      xh32[r * 34 + icp] = h0 | (h1 << 16);
      xl32[r * 34 + icp] = l0 | (l1 << 16);
    }
  }
  __syncthreads();                             // the ONLY barrier before epilogue
  f32x4 acc[NG];
#pragma unroll
  for (int g = 0; g < NG; g++) acc[g] = (f32x4){0.0f, 0.0f, 0.0f, 0.0f};

  const bf16x8* wfh = (const bf16x8*)wf;                 // hi plane, frag-ordered
  const bf16x8* wfl = (const bf16x8*)(wf + 9 * WT);      // lo plane

#pragma unroll 1
  for (int tap = 0; tap < 9; tap++) {
    bf16x8 bh[2][NG], bl[2][NG];
#pragma unroll
    for (int ih = 0; ih < 2; ih++)
#pragma unroll
      for (int g = 0; g < NG; g++) {
        int fi = ((tap * 2 + ih) * NG + g) * 64 + lane;
        bh[ih][g] = wfh[fi];
        bl[ih][g] = wfl[fi];
      }
    const int dy = tap / 3 - 1, dx = tap % 3 - 1;
    const int spat = (wid + dy + 1) * 18 + (m + dx + 1);
#pragma unroll
    for (int ih = 0; ih < 2; ih++) {
      const int base = spat * 68 + ih * 32 + quad * 8;
      bf16x8 ah = lds_ld16(xh + base);
      bf16x8 al = lds_ld16(xl + base);
#pragma unroll
      for (int g = 0; g < NG; g++) {
        acc[g] = __builtin_amdgcn_mfma_f32_16x16x32_bf16(ah, bh[ih][g], acc[g], 0, 0, 0);
        acc[g] = __builtin_amdgcn_mfma_f32_16x16x32_bf16(al, bh[ih][g], acc[g], 0, 0, 0);
        acc[g] = __builtin_amdgcn_mfma_f32_16x16x32_bf16(ah, bl[ih][g], acc[g], 0, 0, 0);
      }
    }
  }
  // epilogue: D[row=quad*4+r][col=lane&15] -> pixel (y0+wid, x0+quad*4+r), oc=g*16+m
  const int py = y0 + wid;
  float* ob = out + (size_t)b * OCLIM * HW + py * 256 + x0 + quad * 4;
#pragma unroll
  for (int g = 0; g < NG; g++) {
    int oc = g * 16 + m;
    if (oc < OCLIM) {
      float bv = HASBIAS ? bias[oc] : 0.0f;
#pragma unroll
      for (int r = 0; r < 4; r++) ob[oc * HW + r] = acc[g][r] + bv;
    }
    if (STATS) {
      float s  = acc[g][0] + acc[g][1] + acc[g][2] + acc[g][3];
      float s2 = acc[g][0] * acc[g][0] + acc[g][1] * acc[g][1] +
                 acc[g][2] * acc[g][2] + acc[g][3] * acc[g][3];
      s  += __shfl_xor(s, 16, 64);  s  += __shfl_xor(s, 32, 64);
      s2 += __shfl_xor(s2, 16, 64); s2 += __shfl_xor(s2, 32, 64);
      if (lane < 16) {
        red[(0 * 4 + wid) * 64 + g * 16 + lane] = s;
        red[(1 * 4 + wid) * 64 + g * 16 + lane] = s2;
      }
    }
  }
  if (STATS) {
    __syncthreads();
    if (tid < 128) {
      int oc = tid & 63, which = tid >> 6;
      float tot = red[(which * 4 + 0) * 64 + oc] + red[(which * 4 + 1) * 64 + oc] +
                  red[(which * 4 + 2) * 64 + oc] + red[(which * 4 + 3) * 64 + oc];
      int slot = (blockIdx.y * 16 + blockIdx.x) & (NSLOT - 1);
      atomicAdd(&stats_out[slot * 128 + which * 64 + oc], tot);
    }
  }
}

// ---------------------------------------------------------------------------
// R18 chain conv: DMA staging + 16x8 tile (2 rows / wave, 2 M-tiles).
// Each wave reads the ENTIRE 147 KB weight tensor; halving blocks halves
// weight L2 traffic. LDS 46 KB -> 3 blocks/CU. (R18: 46 -> 35 us, WIN.)
// ---------------------------------------------------------------------------
__global__ __launch_bounds__(256, 3)
void mfma_conv3_dma(const ushort_t* __restrict__ hiP, const ushort_t* __restrict__ loP,
                    const ushort_t* __restrict__ wf, const float* __restrict__ zeroPg,
                    float* __restrict__ stats_out, float* __restrict__ out) {
  const int tid  = threadIdx.x;
  const int lane = tid & 63, wid = tid >> 6;
  const int m = lane & 15, quad = lane >> 4;
  const int x0 = blockIdx.x * 16, y0 = blockIdx.y * 8, b = blockIdx.z;
  // 180 spats (18 cols x 10 rows) * 8 chunks(16B) per plane; hi then lo.
  __shared__ __align__(16) ushort_t xs[2880 * 8];   // 46080 B
  __shared__ float red[2 * 4 * 64];
  const size_t bimg = (size_t)b * HW;
  for (int g = wid; g < 45; g += 4) {
    int q  = g * 64 + lane;                 // 0..2879
    int pl = q >= 1440;
    int r  = q - (pl ? 1440 : 0);
    int s  = r >> 3, jl = r & 7;
    int js = jl ^ (s & 7);
    int row = s / 18, col = s - row * 18;
    int gy = y0 - 1 + row, gx = x0 - 1 + col;
    const ushort_t* src = (const ushort_t*)zeroPg;
    if ((unsigned)gy < 256u && (unsigned)gx < 256u)
      src = (pl ? loP : hiP) + ((bimg + (size_t)(gy * 256 + gx)) << 6) + (js << 3);
    gld_lds16(src, (void*)&xs[(size_t)g * 512]);
  }
  __syncthreads();                           // compiler drains vmcnt here

  f32x4 acc[2][4];
#pragma unroll
  for (int t = 0; t < 2; t++)
#pragma unroll
    for (int g = 0; g < 4; g++) acc[t][g] = (f32x4){0.0f, 0.0f, 0.0f, 0.0f};
  const bf16x8* wfh = (const bf16x8*)wf;
  const bf16x8* wfl8 = (const bf16x8*)(wf + 9 * 4096);   // WT = 2*4*64*8 = 4096

#pragma unroll 1
  for (int tap = 0; tap < 9; tap++) {
    bf16x8 bh[2][4], bl[2][4];
#pragma unroll
    for (int ih = 0; ih < 2; ih++)
#pragma unroll
      for (int g = 0; g < 4; g++) {
        int fi = ((tap * 2 + ih) * 4 + g) * 64 + lane;
        bh[ih][g] = wfh[fi];
        bl[ih][g] = wfl8[fi];
      }
    const int dy = tap / 3 - 1, dxx = tap % 3 - 1;
    const int scol = m + dxx + 1;
#pragma unroll
    for (int t = 0; t < 2; t++) {
      const int s  = (wid * 2 + t + dy + 1) * 18 + scol;
      const int s7 = s & 7;
#pragma unroll
      for (int ih = 0; ih < 2; ih++) {
        const int ch = s * 8 + ((ih * 4 + quad) ^ s7);   // swizzled chunk
        bf16x8 ah = *(const bf16x8*)&xs[ch * 8];
        bf16x8 al = *(const bf16x8*)&xs[ch * 8 + 11520]; // lo plane (+1440 chunks)
#pragma unroll
        for (int g = 0; g < 4; g++) {
          acc[t][g] = __builtin_amdgcn_mfma_f32_16x16x32_bf16(ah, bh[ih][g], acc[t][g], 0, 0, 0);
          acc[t][g] = __builtin_amdgcn_mfma_f32_16x16x32_bf16(al, bh[ih][g], acc[t][g], 0, 0, 0);
          acc[t][g] = __builtin_amdgcn_mfma_f32_16x16x32_bf16(ah, bl[ih][g], acc[t][g], 0, 0, 0);
        }
      }
    }
  }
  // HWC epilogue: rows y0+wid*2+t, pixel col x0+quad*4+r, oc = g*16+m
#pragma unroll
  for (int g = 0; g < 4; g++) {
    int oc = g * 16 + m;
    float s = 0.0f, s2 = 0.0f;
#pragma unroll
    for (int t = 0; t < 2; t++) {
      const int py = y0 + wid * 2 + t;
      float* ob = out + ((size_t)b * HW + (size_t)py * 256 + x0) * 64;
#pragma unroll
      for (int r = 0; r < 4; r++) {
        float v = acc[t][g][r];
        ob[(quad * 4 + r) * 64 + oc] = v;
        s += v;
        s2 += v * v;
      }
    }
    s  += __shfl_xor(s, 16, 64);  s  += __shfl_xor(s, 32, 64);
    s2 += __shfl_xor(s2, 16, 64); s2 += __shfl_xor(s2, 32, 64);
    if (lane < 16) {
      red[(0 * 4 + wid) * 64 + g * 16 + lane] = s;
      red[(1 * 4 + wid) * 64 + g * 16 + lane] = s2;
    }
  }
  __syncthreads();
  if (tid < 128) {
    int oc = tid & 63, which = tid >> 6;
    float tot = red[(which * 4 + 0) * 64 + oc] + red[(which * 4 + 1) * 64 + oc] +
                red[(which * 4 + 2) * 64 + oc] + red[(which * 4 + 3) * 64 + oc];
    int slot = (blockIdx.y * 16 + blockIdx.x) & (NSLOT - 1);
    atomicAdd(&stats_out[slot * 128 + which * 64 + oc], tot);
  }
}

// ---------------------------------------------------------------------------
// R20 offset conv (dc2 only this round — bisect): DMA staging from bf16
// hi/lo planes (16x8, same geometry as chain conv), NG=2, planar-27
// epilogue with bias.
// ---------------------------------------------------------------------------
__global__ __launch_bounds__(256, 3)
void ofs_conv_dma(const ushort_t* __restrict__ hiP, const ushort_t* __restrict__ loP,
                  const ushort_t* __restrict__ wf, const float* __restrict__ zeroPg,
                  const float* __restrict__ bias, float* __restrict__ out) {
  const int tid  = threadIdx.x;
  const int lane = tid & 63, wid = tid >> 6;
  const int m = lane & 15, quad = lane >> 4;
  const int x0 = blockIdx.x * 16, y0 = blockIdx.y * 8, b = blockIdx.z;
  __shared__ __align__(16) ushort_t xs[2880 * 8];   // 46080 B
  const size_t bimg = (size_t)b * HW;
  for (int g = wid; g < 45; g += 4) {
    int q  = g * 64 + lane;
    int pl = q >= 1440;
    int r  = q - (pl ? 1440 : 0);
    int s  = r >> 3, jl = r & 7;
    int js = jl ^ (s & 7);
    int row = s / 18, col = s - row * 18;
    int gy = y0 - 1 + row, gx = x0 - 1 + col;
    const ushort_t* src = (const ushort_t*)zeroPg;
    if ((unsigned)gy < 256u && (unsigned)gx < 256u)
      src = (pl ? loP : hiP) + ((bimg + (size_t)(gy * 256 + gx)) << 6) + (js << 3);
    gld_lds16(src, (void*)&xs[(size_t)g * 512]);
  }
  __syncthreads();

  f32x4 acc[2][2];
#pragma unroll
  for (int t = 0; t < 2; t++)
#pragma unroll
    for (int g = 0; g < 2; g++) acc[t][g] = (f32x4){0.0f, 0.0f, 0.0f, 0.0f};
  const bf16x8* wfh = (const bf16x8*)wf;
  const bf16x8* wfl8 = (const bf16x8*)(wf + 9 * 2048);   // WT = 2*2*64*8 = 2048

#pragma unroll 1
  for (int tap = 0; tap < 9; tap++) {
    bf16x8 bh[2][2], bl[2][2];
#pragma unroll
    for (int ih = 0; ih < 2; ih++)
#pragma unroll
      for (int g = 0; g < 2; g++) {
        int fi = ((tap * 2 + ih) * 2 + g) * 64 + lane;
        bh[ih][g] = wfh[fi];
        bl[ih][g] = wfl8[fi];
      }
    const int dy = tap / 3 - 1, dxx = tap % 3 - 1;
    const int scol = m + dxx + 1;
#pragma unroll
    for (int t = 0; t < 2; t++) {
      const int s  = (wid * 2 + t + dy + 1) * 18 + scol;
      const int s7 = s & 7;
#pragma unroll
      for (int ih = 0; ih < 2; ih++) {
        const int ch = s * 8 + ((ih * 4 + quad) ^ s7);
        bf16x8 ah = *(const bf16x8*)&xs[ch * 8];
        bf16x8 al = *(const bf16x8*)&xs[ch * 8 + 11520];
#pragma unroll
        for (int g = 0; g < 2; g++) {
          acc[t][g] = __builtin_amdgcn_mfma_f32_16x16x32_bf16(ah, bh[ih][g], acc[t][g], 0, 0, 0);
          acc[t][g] = __builtin_amdgcn_mfma_f32_16x16x32_bf16(al, bh[ih][g], acc[t][g], 0, 0, 0);
          acc[t][g] = __builtin_amdgcn_mfma_f32_16x16x32_bf16(ah, bl[ih][g], acc[t][g], 0, 0, 0);
        }
      }
    }
  }
  // planar epilogue (om layout [B][27][HW] kept for dcn's coalesced om reads)
#pragma unroll
  for (int g = 0; g < 2; g++) {
    int oc = g * 16 + m;
    if (oc < 27) {
      float bv = bias[oc];
#pragma unroll
      for (int t = 0; t < 2; t++) {
        const int py = y0 + wid * 2 + t;
        float* ob = out + (size_t)b * 27 * HW + (size_t)oc * HW + py * 256 + x0 + quad * 4;
#pragma unroll
        for (int r = 0; r < 4; r++) ob[r] = acc[t][g][r] + bv;
      }
    }
  }
}

// ---------------------------------------------------------------------------
// R17 transform: all-HWC streaming. Finalize BN of raw conv out t (HWC) and
// materialize bf16 hi/lo HWC planes. TMODE 1: relu(bn(t)) -> planes only.
// TMODE 2: y = bn(t)+skip -> y fp32 HWC + planes. Parallel stats preamble.
// ---------------------------------------------------------------------------
template <int TMODE>
__global__ __launch_bounds__(256, 8)
void bn_split_hwc(const float* __restrict__ t, const float* __restrict__ stats,
                  const float* __restrict__ g, const float* __restrict__ be,
                  const float* __restrict__ skip, float* __restrict__ yout,
                  uint32_t* __restrict__ hiP, uint32_t* __restrict__ loP) {
  __shared__ float part[2][4][64];
  __shared__ float s_sc[64], s_sh[64];
  const int tid = threadIdx.x;
  {
    int c = tid & 63, q = tid >> 6;
    float sum = 0.0f, sq = 0.0f;
    for (int sl = q * 16; sl < q * 16 + 16; sl++) {
      sum += stats[sl * 128 + c];
      sq  += stats[sl * 128 + 64 + c];
    }
    part[0][q][c] = sum;
    part[1][q][c] = sq;
  }
  __syncthreads();
  if (tid < 64) {
    int c = tid;
    float sum = part[0][0][c] + part[0][1][c] + part[0][2][c] + part[0][3][c];
    float sq  = part[1][0][c] + part[1][1][c] + part[1][2][c] + part[1][3][c];
    float mn  = sum * INV_N;
    float var = sq * INV_N - mn * mn;
    float s   = g[c] * rsqrtf(var + EPSv);
    s_sc[c] = s;
    s_sh[c] = be[c] - mn * s;
  }
  __syncthreads();
  const int blk = blockIdx.x;            // 2048 = NPIX/64
  const int b  = blk >> 10;
  const int p0 = (blk & 1023) * 64;
  const size_t base = ((size_t)b * HW + p0) * 64;   // floats (HWC)
  uint32_t* hb = hiP + ((size_t)b * HW + p0) * 32;
  uint32_t* lb = loP + ((size_t)b * HW + p0) * 32;
#pragma unroll
  for (int i = 0; i < 8; i++) {
    int idx = i * 256 + tid;             // 0..2047 = 64 px * 32 ch-pairs
    int p = idx >> 5, c2 = idx & 31;
    size_t off = base + (size_t)p * 64 + c2 * 2;
    float2 v = *(const float2*)&t[off];
    float v0 = fmaf(v.x, s_sc[c2 * 2],     s_sh[c2 * 2]);
    float v1 = fmaf(v.y, s_sc[c2 * 2 + 1], s_sh[c2 * 2 + 1]);
    if (TMODE == 1) {
      v0 = fmaxf(v0, 0.0f);
      v1 = fmaxf(v1, 0.0f);
    } else {
      float2 k = *(const float2*)&skip[off];
      v0 += k.x; v1 += k.y;
      float2 y2; y2.x = v0; y2.y = v1;
      *(float2*)&yout[off] = y2;
    }
    uint32_t h0v, l0v, h1v, l1v;
    split_hl(v0, h0v, l0v);
    split_hl(v1, h1v, l1v);
    hb[p * 32 + c2] = h0v | (h1v << 16);
    lb[p * 32 + c2] = l0v | (l1v << 16);
  }
}

// ---------------------------------------------------------------------------
// R20: x = bn(t)+skip, all-HWC streaming; also emits x's bf16 hi/lo planes
// (feeds the DMA offset conv for dc2).
// ---------------------------------------------------------------------------
__global__ __launch_bounds__(256, 8)
void bn_add_hwc(const float* __restrict__ t, const float* __restrict__ stats,
                const float* __restrict__ g, const float* __restrict__ be,
                const float* __restrict__ skip, float* __restrict__ xout,
                uint32_t* __restrict__ hiP, uint32_t* __restrict__ loP) {
  __shared__ float part[2][4][64];
  __shared__ float s_sc[64], s_sh[64];
  const int tid = threadIdx.x;
  {
    int c = tid & 63, q = tid >> 6;
    float sum = 0.0f, sq = 0.0f;
    for (int sl = q * 16; sl < q * 16 + 16; sl++) {
      sum += stats[sl * 128 + c];
      sq  += stats[sl * 128 + 64 + c];
    }
    part[0][q][c] = sum;
    part[1][q][c] = sq;
  }
  __syncthreads();
  if (tid < 64) {
    int c = tid;
    float sum = part[0][0][c] + part[0][1][c] + part[0][2][c] + part[0][3][c];
    float sq  = part[1][0][c] + part[1][1][c] + part[1][2][c] + part[1][3][c];
    float mn  = sum * INV_N;
    float var = sq * INV_N - mn * mn;
    float s   = g[c] * rsqrtf(var + EPSv);
    s_sc[c] = s;
    s_sh[c] = be[c] - mn * s;
  }
  __syncthreads();
  const int blk = blockIdx.x;            // 2048
  const int b  = blk >> 10;
  const int p0 = (blk & 1023) * 64;
  const size_t base4 = (((size_t)b * HW + p0) * 64) >> 2;   // float4 units
  const float4* t4 = (const float4*)t;
  const float4* k4 = (const float4*)skip;
  float4* x4 = (float4*)xout;
  uint32_t* hb = hiP + ((size_t)b * HW + p0) * 32;
  uint32_t* lb = loP + ((size_t)b * HW + p0) * 32;
#pragma unroll
  for (int i = 0; i < 4; i++) {
    int idx = i * 256 + tid;             // 0..1023 = 64 px * 16 ch-quads
    int c = (idx & 15) * 4;
    int p = idx >> 4;
    float4 v = t4[base4 + idx], k = k4[base4 + idx], r;
    r.x = fmaf(v.x, s_sc[c],     s_sh[c])     + k.x;
    r.y = fmaf(v.y, s_sc[c + 1], s_sh[c + 1]) + k.y;
    r.z = fmaf(v.z, s_sc[c + 2], s_sh[c + 2]) + k.z;
    r.w = fmaf(v.w, s_sc[c + 3], s_sh[c + 3]) + k.w;
    x4[base4 + idx] = r;
    uint32_t h0v, l0v, h1v, l1v, h2v, l2v, h3v, l3v;
    split_hl(r.x, h0v, l0v); split_hl(r.y, h1v, l1v);
    split_hl(r.z, h2v, l2v); split_hl(r.w, h3v, l3v);
    uint2 hv = make_uint2(h0v | (h1v << 16), h2v | (h3v << 16));
    uint2 lv = make_uint2(l0v | (l1v << 16), l2v | (l3v << 16));
    *(uint2*)&hb[p * 32 + (c >> 1)] = hv;
    *(uint2*)&lb[p * 32 + (c >> 1)] = lv;
  }
}

// ---------------------------------------------------------------------------
// Legacy path only: y = BN(t)*g+be + skip (float4).
// ---------------------------------------------------------------------------
__global__ void bn_apply_add_kernel(const float* __restrict__ t, const float* __restrict__ stats,
                                    const float* __restrict__ g, const float* __restrict__ be,
                                    const float* __restrict__ skip, float* __restrict__ out) {
  __shared__ float s_sc[64], s_sh[64];
  if (threadIdx.x < 64) {
    int c = threadIdx.x;
    float sum = 0.0f, sq = 0.0f;
    for (int sl = 0; sl < NSLOT; sl++) {
      sum += stats[sl * 128 + c];
      sq  += stats[sl * 128 + 64 + c];
    }
    float m   = sum * INV_N;
    float var = sq * INV_N - m * m;
    float s   = g[c] * rsqrtf(var + EPSv);
    s_sc[c] = s;
    s_sh[c] = be[c] - m * s;
  }
  __syncthreads();
  const float4* t4 = (const float4*)t;
  const float4* k4 = (const float4*)skip;
  float4* o4 = (float4*)out;
  const int n4 = NCHW / 4;
  for (int i = blockIdx.x * blockDim.x + threadIdx.x; i < n4; i += gridDim.x * blockDim.x) {
    int c = (i >> 14) & 63;
    float s = s_sc[c], h = s_sh[c];
    float4 v = t4[i], kk = k4[i], r;
    r.x = fmaf(v.x, s, h) + kk.x;
    r.y = fmaf(v.y, s, h) + kk.y;
    r.z = fmaf(v.z, s, h) + kk.z;
    r.w = fmaf(v.w, s, h) + kk.w;
    o4[i] = r;
  }
}

// ---------------------------------------------------------------------------
// Legacy path only: fused x = bn(t)+skip -> planar out AND HWC mirror.
// ---------------------------------------------------------------------------
__global__ __launch_bounds__(256, 4)
void bn_tx_kernel(const float* __restrict__ t, const float* __restrict__ stats,
                  const float* __restrict__ g, const float* __restrict__ be,
                  const float* __restrict__ skip, float* __restrict__ outP,
                  float* __restrict__ outHWC) {
  __shared__ float tile[64][65];
  __shared__ float s_sc[64], s_sh[64];
  if (threadIdx.x < 64) {
    int c = threadIdx.x;
    float sum = 0.0f, sq = 0.0f;
    for (int sl = 0; sl < NSLOT; sl++) {
      sum += stats[sl * 128 + c];
      sq  += stats[sl * 128 + 64 + c];
    }
    float m   = sum * INV_N;
    float var = sq * INV_N - m * m;
    float s   = g[c] * rsqrtf(var + EPSv);
    s_sc[c] = s;
    s_sh[c] = be[c] - m * s;
  }
  __syncthreads();
  const int blk = blockIdx.x;            // 2048 = NPIX/64
  const int b = blk >> 10;
  const int p0 = (blk & 1023) * 64;
  const float* tb = t + (size_t)b * CHW;
  const float* kb = skip + (size_t)b * CHW;
  float* oP = outP + (size_t)b * CHW;
  float* oH = outHWC + (size_t)b * CHW;
#pragma unroll
  for (int i = 0; i < 16; i++) {
    int idx = i * 256 + threadIdx.x;
    int c = idx >> 6, p = idx & 63;
    float v = fmaf(tb[c * HW + p0 + p], s_sc[c], s_sh[c]) + kb[c * HW + p0 + p];
    oP[c * HW + p0 + p] = v;
    tile[c][p] = v;
  }
  __syncthreads();
#pragma unroll
  for (int i = 0; i < 16; i++) {
    int idx = i * 256 + threadIdx.x;
    int p = idx >> 6, c = idx & 63;
    oH[(size_t)(p0 + p) * 64 + c] = tile[c][p];
  }
}

// ---------------------------------------------------------------------------
// Deformable conv on MFMA, HWC input (EXACT R18 form, measured-best 166us):
// separated hi/lo planes, 128B rows + 32B-chunk XOR swizzle, double-buffered,
// 1 barrier/tap, __launch_bounds__(256,4). R16 reg-only REGRESSED (194us);
// R19 GL/GF register pipeline FAILED correctness (reverted, bug unlocated).
// FINAL: fuse dc4 bias + conv4.
// ---------------------------------------------------------------------------
template <int NG, int FINAL>
__global__ __launch_bounds__(256, 4)
void dcn_mfma(const float* __restrict__ xhwc, const float* __restrict__ om,
              const ushort_t* __restrict__ wf, const float* __restrict__ bias,
              const float* __restrict__ c4w, const float* __restrict__ c4b,
              float* __restrict__ out) {
  const int tid  = threadIdx.x;
  const int lane = tid & 63, wid = tid >> 6;
  const int m = lane & 15, quad = lane >> 4;
  const int x0 = blockIdx.x * 16, y0 = blockIdx.y * 4, b = blockIdx.z;
  constexpr int WT = 2 * NG * 64 * 8;
  __shared__ __align__(16) ushort_t sh[2][64 * 64];   // hi plane per buffer, 8 KB
  __shared__ __align__(16) ushort_t sl[2][64 * 64];   // lo plane
  const int gpx = tid & 63, cg = tid >> 6;     // gather role: pixel, 16-ch group
  const int gpy = y0 + (gpx >> 4), gxx = x0 + (gpx & 15);
  const float* xb  = xhwc + (size_t)b * CHW;
  const float* omb = om + (size_t)b * 27 * HW + gpy * 256 + gxx;
  const int wchunk = (cg ^ (gpx & 3)) * 16;    // swizzled 32B-chunk base (ushorts)

  auto gather = [&](int tap, int buf) {
    float dyv = omb[tap * HW];
    float dxv = omb[(9 + tap) * HW];
    float mo  = omb[(18 + tap) * HW];
    float mk  = 1.0f / (1.0f + __expf(-mo));
    float ys = fminf(fmaxf((float)(gpy + tap / 3 - 1) + dyv, -2.0f), 258.0f);
    float xs = fminf(fmaxf((float)(gxx + tap % 3 - 1) + dxv, -2.0f), 258.0f);
    float y0f = floorf(ys), x0f = floorf(xs);
    float wy = ys - y0f, wx = xs - x0f;
    int yi = (int)y0f, xi = (int)x0f;
    float vy0 = ((unsigned)yi       < 256u) ? 1.0f : 0.0f;
    float vy1 = ((unsigned)(yi + 1) < 256u) ? 1.0f : 0.0f;
    float vx0 = ((unsigned)xi       < 256u) ? 1.0f : 0.0f;
    float vx1 = ((unsigned)(xi + 1) < 256u) ? 1.0f : 0.0f;
    int cy0 = min(max(yi, 0), 255), cy1 = min(max(yi + 1, 0), 255);
    int cx0 = min(max(xi, 0), 255), cx1 = min(max(xi + 1, 0), 255);
    float W00 = (1.0f - wy) * (1.0f - wx) * mk * vy0 * vx0;
    float W01 = (1.0f - wy) * wx * mk * vy0 * vx1;
    float W10 = wy * (1.0f - wx) * mk * vy1 * vx0;
    float W11 = wy * wx * mk * vy1 * vx1;
    const float* p00 = xb + (size_t)(cy0 * 256 + cx0) * 64 + cg * 16;
    const float* p01 = xb + (size_t)(cy0 * 256 + cx1) * 64 + cg * 16;
    const float* p10 = xb + (size_t)(cy1 * 256 + cx0) * 64 + cg * 16;
    const float* p11 = xb + (size_t)(cy1 * 256 + cx1) * 64 + cg * 16;
#pragma unroll
    for (int q4 = 0; q4 < 4; q4++) {
      float4 a  = ((const float4*)p00)[q4];
      float4 b2 = ((const float4*)p01)[q4];
      float4 c2 = ((const float4*)p10)[q4];
      float4 d2 = ((const float4*)p11)[q4];
      float s0 = W00 * a.x + W01 * b2.x + W10 * c2.x + W11 * d2.x;
      float s1 = W00 * a.y + W01 * b2.y + W10 * c2.y + W11 * d2.y;
      float s2 = W00 * a.z + W01 * b2.z + W10 * c2.z + W11 * d2.z;
      float s3 = W00 * a.w + W01 * b2.w + W10 * c2.w + W11 * d2.w;
      uint32_t h0, l0, h1, l1, h2, l2, h3, l3;
      split_hl(s0, h0, l0); split_hl(s1, h1, l1);
      split_hl(s2, h2, l2); split_hl(s3, h3, l3);
      int wi = gpx * 64 + wchunk + q4 * 4;     // 8B-aligned
      *(uint2*)&sh[buf][wi] = make_uint2(h0 | (h1 << 16), h2 | (h3 << 16));
      *(uint2*)&sl[buf][wi] = make_uint2(l0 | (l1 << 16), l2 | (l3 << 16));
    }
  };

  f32x4 acc[NG];
#pragma unroll
  for (int g = 0; g < NG; g++) acc[g] = (f32x4){0.0f, 0.0f, 0.0f, 0.0f};
  const bf16x8* wfh = (const bf16x8*)wf;
  const bf16x8* wfl = (const bf16x8*)(wf + 9 * WT);
  const int px = wid * 16 + m;                 // this lane's A-row pixel

  gather(0, 0);
  __syncthreads();
#pragma unroll 1
  for (int tap = 0; tap < 9; tap++) {
    const int cur = tap & 1;
    if (tap < 8) gather(tap + 1, cur ^ 1);     // overlaps MFMAs below
#pragma unroll
    for (int ih = 0; ih < 2; ih++) {
      const int c = ih * 2 + (quad >> 1), h = quad & 1;
      const int ri = px * 64 + ((c ^ (px & 3)) * 16) + h * 8;   // 16B-aligned
      bf16x8 ah = *(const bf16x8*)&sh[cur][ri];
      bf16x8 al = *(const bf16x8*)&sl[cur][ri];
#pragma unroll
      for (int g = 0; g < NG; g++) {
        int fi = ((tap * 2 + ih) * NG + g) * 64 + lane;
        bf16x8 bh = wfh[fi], bl = wfl[fi];
        acc[g] = __builtin_amdgcn_mfma_f32_16x16x32_bf16(ah, bh, acc[g], 0, 0, 0);
        acc[g] = __builtin_amdgcn_mfma_f32_16x16x32_bf16(al, bh, acc[g], 0, 0, 0);
        acc[g] = __builtin_amdgcn_mfma_f32_16x16x32_bf16(ah, bl, acc[g], 0, 0, 0);
      }
    }
    __syncthreads();   // writes to buf^1 and reads of cur both done
  }
  const int py = y0 + wid;
  if (FINAL) {
    if (m == 0) {
      float* op = out + (size_t)b * HW + py * 256 + x0 + quad * 4;
#pragma unroll
      for (int r = 0; r < 4; r++) op[r] = c4w[0] * (acc[0][r] + bias[0]) + c4b[0];
    }
  } else {
    float* ob = out + (size_t)b * CHW + ((size_t)py * 256 + x0 + quad * 4) * 64 + m;
#pragma unroll
    for (int g = 0; g < NG; g++)
#pragma unroll
      for (int r = 0; r < 4; r++)
        ob[r * 64 + g * 16] = fmaxf(acc[g][r] + bias[g * 16 + m], 0.0f);
  }
}

// ---------------------------------------------------------------------------
extern "C" void kernel_launch(void* const* d_in, const int* in_sizes, int n_in,
                              void* d_out, int out_size, void* d_ws, size_t ws_size,
                              hipStream_t stream) {
  const float* LowDEM    = (const float*)d_in[0];
  const float* Point_Ele = (const float*)d_in[1];
  const float* Slope     = (const float*)d_in[2];
  const float* Distance  = (const float*)d_in[3];
  const float* Level     = (const float*)d_in[4];
  const float* conv0_w   = (const float*)d_in[5];
  const float* conv0_b   = (const float*)d_in[6];
  const float* conv1_w   = (const float*)d_in[7];
  const float* conv1_b   = (const float*)d_in[8];
  const float* rb_w1     = (const float*)d_in[9];
  const float* rb_g1     = (const float*)d_in[11];
  const float* rb_be1    = (const float*)d_in[12];
  const float* rb_w2     = (const float*)d_in[13];
  const float* rb_g2     = (const float*)d_in[15];
  const float* rb_be2    = (const float*)d_in[16];
  const float* conv2_w   = (const float*)d_in[17];
  const float* bn2_g     = (const float*)d_in[19];
  const float* bn2_be    = (const float*)d_in[20];
  const float* dc2_w     = (const float*)d_in[21];
  const float* dc2_b     = (const float*)d_in[22];
  const float* dc2_ow    = (const float*)d_in[23];
  const float* dc2_ob    = (const float*)d_in[24];
  const float* dc3_w     = (const float*)d_in[25];
  const float* dc3_b     = (const float*)d_in[26];
  const float* dc3_ow    = (const float*)d_in[27];
  const float* dc3_ob    = (const float*)d_in[28];
  const float* dc4_w     = (const float*)d_in[29];
  const float* dc4_b     = (const float*)d_in[30];
  const float* dc4_ow    = (const float*)d_in[31];
  const float* dc4_ob    = (const float*)d_in[32];
  const float* conv4_w   = (const float*)d_in[33];
  const float* conv4_b   = (const float*)d_in[34];

  // small region first, then big buffers
  float* x0   = (float*)d_ws;             // 131072
  float* T1   = x0 + NPIX;                // 5184
  ushort_t* WF = (ushort_t*)(T1 + 5184);  // 39 * WFL ushorts
  float* stats = (float*)(WF + 39 * WFL); // 33 * STSLOT floats
  float* zpg   = stats + 33 * STSLOT;     // 32 floats: DMA zero page
  float* big   = zpg + 32;
  size_t used_small = (size_t)((char*)big - (char*)d_ws);
  bool fused = ws_size >= used_small + 5ull * NCHW * sizeof(float);

  float* bufX = big;                      // X (conv9x9 out; skip for bn2)
  float* bufT = bufX + NCHW;              // raw conv out / offset-conv out
  float* R3   = bufT + NCHW;              // fused: yA   | legacy: bufT2
  float* R4   = R3 + NCHW;                // fused: yB   | legacy: yA(=yB)
  ushort_t* hiP = (ushort_t*)(R4 + NCHW); // fused only: bf16 hi plane (HWC)
  ushort_t* loP = hiP + NCHW;             //             bf16 lo plane (HWC)

  hipMemsetAsync(stats, 0, 33 * STSLOT * sizeof(float), stream);
  hipMemsetAsync(zpg, 0, 128, stream);

  transpose_w_kernel<<<32, 256, 0, stream>>>(conv1_w, T1, 1, 64, 1, 81);

  prep_wfrag<<<dim3(144, 16), 256, 0, stream>>>(rb_w1,   WF,            4, 64, 36864, WFL);
  prep_wfrag<<<dim3(144, 16), 256, 0, stream>>>(rb_w2,   WF + 16 * WFL, 4, 64, 36864, WFL);
  prep_wfrag<<<dim3(144, 1),  256, 0, stream>>>(conv2_w, WF + 32 * WFL, 4, 64, 36864, WFL);
  prep_wfrag<<<dim3(72, 1),   256, 0, stream>>>(dc2_ow,  WF + 33 * WFL, 2, 27, 15552, WFL);
  prep_wfrag<<<dim3(72, 1),   256, 0, stream>>>(dc3_ow,  WF + 34 * WFL, 2, 27, 15552, WFL);
  prep_wfrag<<<dim3(72, 1),   256, 0, stream>>>(dc4_ow,  WF + 35 * WFL, 2, 27, 15552, WFL);
  prep_wfrag<<<dim3(144, 1),  256, 0, stream>>>(dc2_w,   WF + 36 * WFL, 4, 64, 36864, WFL);
  prep_wfrag<<<dim3(144, 1),  256, 0, stream>>>(dc3_w,   WF + 37 * WFL, 4, 64, 36864, WFL);
  prep_wfrag<<<dim3(36, 1),   256, 0, stream>>>(dc4_w,   WF + 38 * WFL, 1, 1, 576, WFL);

  prep_kernel<<<(NPIX + 255) / 256, 256, 0, stream>>>(LowDEM, Point_Ele, Slope, Distance,
                                                      Level, conv0_w, conv0_b, x0);

  dim3 grid16(16, 16, 2);   // conv9x9
  dim3 gmf(16, 64, 2);      // dcn_mfma / legacy conv (16x4 pixel tiles)
  dim3 gmf8(16, 32, 2);     // chain conv / ofs conv (16x8 pixel tiles)

  conv9x9_kernel<<<grid16, 256, 0, stream>>>(x0, T1, conv1_b, bufX,
                                             fused ? (uint32_t*)hiP : nullptr,
                                             fused ? (uint32_t*)loP : nullptr);

  if (fused) {
    float* yA = R3;
    float* yB = R4;
    // R18: all-HWC chain — 16x8-tile DMA convs + streaming bn/split.
    for (int i = 0; i < 16; i++) {
      mfma_conv3_dma<<<gmf8, 256, 0, stream>>>(hiP, loP, WF + (size_t)i * WFL, zpg,
                                               stats + (size_t)(2 * i) * STSLOT, bufT);
      bn_split_hwc<1><<<2048, 256, 0, stream>>>(
          bufT, stats + (size_t)(2 * i) * STSLOT, rb_g1 + i * 64, rb_be1 + i * 64,
          nullptr, nullptr, (uint32_t*)hiP, (uint32_t*)loP);
      mfma_conv3_dma<<<gmf8, 256, 0, stream>>>(hiP, loP, WF + (size_t)(16 + i) * WFL, zpg,
                                               stats + (size_t)(2 * i + 1) * STSLOT, bufT);
      const float* skp = (i == 0) ? bufX : ((i & 1) ? yA : yB);   // y_i
      float* yo = (i & 1) ? yB : yA;                              // y_{i+1}
      bn_split_hwc<2><<<2048, 256, 0, stream>>>(
          bufT, stats + (size_t)(2 * i + 1) * STSLOT, rb_g2 + i * 64, rb_be2 + i * 64,
          skp, yo, (uint32_t*)hiP, (uint32_t*)loP);
    }
    mfma_conv3_dma<<<gmf8, 256, 0, stream>>>(hiP, loP, WF + (size_t)32 * WFL, zpg,
                                             stats + (size_t)32 * STSLOT, bufT);

    float* xT    = R4;          // y16 fp32 dead (its planes fed conv2)
    float* d2out = R3;          // yA dead after i=15
    float* d3out = (float*)hiP; // plane region dead after ofs dc2 below
    // x = bn(conv2_out) + X -> xT (HWC) + x planes (for dc2's offset conv)
    bn_add_hwc<<<2048, 256, 0, stream>>>(bufT, stats + 32 * STSLOT, bn2_g, bn2_be,
                                         bufX, xT, (uint32_t*)hiP, (uint32_t*)loP);
    // dc2: DMA offset conv from x planes (R20 bisect target)
    ofs_conv_dma<<<gmf8, 256, 0, stream>>>(hiP, loP, WF + (size_t)33 * WFL, zpg,
                                           dc2_ob, bufT);
    dcn_mfma<4, 0><<<gmf, 256, 0, stream>>>(xT, bufT, WF + (size_t)36 * WFL, dc2_b,
                                            nullptr, nullptr, d2out);
    // dc3: VALU-staged offset conv from d2out fp32 HWC (proven path)
    mfma_conv3<2, 0, 0, 27, 1, 0, 1><<<gmf, 256, 0, stream>>>(
        d2out, nullptr, WF + (size_t)34 * WFL, dc3_ob, nullptr, nullptr, nullptr,
        nullptr, nullptr, bufT);
    dcn_mfma<4, 0><<<gmf, 256, 0, stream>>>(d2out, bufT, WF + (size_t)37 * WFL, dc3_b,
                                            nullptr, nullptr, d3out);
    // dc4 + conv4 -> d_out
    mfma_conv3<2, 0, 0, 27, 1, 0, 1><<<gmf, 256, 0, stream>>>(
        d3out, nullptr, WF + (size_t)35 * WFL, dc4_ob, nullptr, nullptr, nullptr,
        nullptr, nullptr, bufT);
    dcn_mfma<1, 1><<<gmf, 256, 0, stream>>>(d3out, bufT, WF + (size_t)38 * WFL, dc4_b,
                                            conv4_w, conv4_b, (float*)d_out);
  } else {
    float* bufT2 = R3;
    float* bufY  = R4;
    for (int i = 0; i < 16; i++) {
      const float* src = (i == 0) ? bufX : bufY;
      mfma_conv3<4, 0, 1, 64, 0, 0, 0><<<gmf, 256, 0, stream>>>(
          src, nullptr, WF + (size_t)i * WFL, nullptr, nullptr, nullptr, nullptr,
          stats + (2 * i) * STSLOT, nullptr, bufT);
      mfma_conv3<4, 1, 1, 64, 0, 0, 0><<<gmf, 256, 0, stream>>>(
          bufT, nullptr, WF + (size_t)(16 + i) * WFL, nullptr, stats + (2 * i) * STSLOT,
          rb_g1 + i * 64, rb_be1 + i * 64, stats + (2 * i + 1) * STSLOT, nullptr, bufT2);
      bn_apply_add_kernel<<<2048, 256, 0, stream>>>(bufT2, stats + (2 * i + 1) * STSLOT,
                                                    rb_g2 + i * 64, rb_be2 + i * 64, src, bufY);
    }
    mfma_conv3<4, 0, 1, 64, 0, 0, 0><<<gmf, 256, 0, stream>>>(
        bufY, nullptr, WF + (size_t)32 * WFL, nullptr, nullptr, nullptr, nullptr,
        stats + 32 * STSLOT, nullptr, bufT);
    float* xT    = R4;
    float* d2out = R3;
    float* d3out = R4;
    bn_tx_kernel<<<2048, 256, 0, stream>>>(bufT, stats + 32 * STSLOT, bn2_g, bn2_be,
                                           bufX, bufX, xT);
    mfma_conv3<2, 0, 0, 27, 1, 0, 0><<<gmf, 256, 0, stream>>>(
        bufX, nullptr, WF + (size_t)33 * WFL, dc2_ob, nullptr, nullptr, nullptr,
        nullptr, nullptr, bufT);
    dcn_mfma<4, 0><<<gmf, 256, 0, stream>>>(xT, bufT, WF + (size_t)36 * WFL, dc2_b,
                                            nullptr, nullptr, d2out);
    mfma_conv3<2, 0, 0, 27, 1, 0, 1><<<gmf, 256, 0, stream>>>(
        d2out, nullptr, WF + (size_t)34 * WFL, dc3_ob, nullptr, nullptr, nullptr,
        nullptr, nullptr, bufT);
    dcn_mfma<4, 0><<<gmf, 256, 0, stream>>>(d2out, bufT, WF + (size_t)37 * WFL, dc3_b,
                                            nullptr, nullptr, d3out);
    mfma_conv3<2, 0, 0, 27, 1, 0, 1><<<gmf, 256, 0, stream>>>(
        d3out, nullptr, WF + (size_t)35 * WFL, dc4_ob, nullptr, nullptr, nullptr,
        nullptr, nullptr, bufT);
    dcn_mfma<1, 1><<<gmf, 256, 0, stream>>>(d3out, bufT, WF + (size_t)38 * WFL, dc4_b,
                                            conv4_w, conv4_b, (float*)d_out);
  }
}

// Round 7
// 2317.267 us; speedup vs baseline: 1.0872x; 1.0872x over previous
//
#include <hip/hip_runtime.h>
#include <cmath>

typedef unsigned short ushort_t;
typedef __attribute__((ext_vector_type(8))) short bf16x8;
typedef __attribute__((ext_vector_type(4))) float f32x4;

// Problem constants (B=2, C=64, H=W=256)
static constexpr int Bn   = 2;
static constexpr int Hn   = 256;
static constexpr int Wn   = 256;
static constexpr int HW   = Hn * Wn;          // 65536
static constexpr int CHW  = 64 * HW;          // 4194304
static constexpr int NCHW = Bn * CHW;         // 8388608
static constexpr int NPIX = Bn * HW;          // 131072
static constexpr float EPSv = 1e-5f;
static constexpr float INV_N = 1.0f / 131072.0f;   // BN count = B*H*W
static constexpr int NSLOT = 64;              // stats slot replication (anti-contention)
static constexpr int STSLOT = NSLOT * 128;    // floats per layer stats region
static constexpr int WFL = 73728;             // ushorts per weight-fragment layer slot

// bf16 round-to-nearest-even (no NaN inputs in this net)
__device__ inline uint32_t bf16_rne(float f) {
  uint32_t u = __float_as_uint(f);
  return (u + 0x7FFFu + ((u >> 16) & 1u)) >> 16;
}
__device__ inline void split_hl(float v, uint32_t& h, uint32_t& l) {
  h = bf16_rne(v);
  l = bf16_rne(v - __uint_as_float(h << 16)) & 0xFFFFu;
}
__device__ inline bf16x8 lds_ld16(const ushort_t* p) {   // 2x ds_read_b64
  union { bf16x8 v; uint2 u[2]; } r;
  r.u[0] = *(const uint2*)p;
  r.u[1] = *(const uint2*)(p + 4);
  return r.v;
}

// async global->LDS, 16B per lane: LDS dest = wave-uniform base + lane*16,
// global src is per-lane (carries the XOR swizzle + OOB zero-page redirect).
typedef __attribute__((address_space(1))) const void glb_void;
typedef __attribute__((address_space(3))) void lds_void;
__device__ inline void gld_lds16(const void* g, void* l) {
  __builtin_amdgcn_global_load_lds((glb_void*)g, (lds_void*)l, 16, 0, 0);
}

// ---------------------------------------------------------------------------
__global__ void transpose_w_kernel(const float* __restrict__ in, float* __restrict__ out,
                                   int NB, int OC, int IC, int K) {
  int total = NB * OC * IC * K;
  for (int i = blockIdx.x * blockDim.x + threadIdx.x; i < total; i += gridDim.x * blockDim.x) {
    int k  = i % K;
    int t  = i / K;
    int ic = t % IC; t /= IC;
    int oc = t % OC;
    int nb = t / OC;
    out[(((size_t)nb * IC + ic) * K + k) * OC + oc] = in[i];
  }
}

// ---------------------------------------------------------------------------
// Weight fragment prep: w[oc][ic][3][3] f32 -> MFMA B-frag order, bf16 hi/lo.
__global__ void prep_wfrag(const float* __restrict__ w, ushort_t* __restrict__ out,
                           int NGp, int ocreal, int wlstride, int olstride) {
  int layer = blockIdx.y;
  int elems = 9 * 2 * NGp * 64 * 8;
  int idx = blockIdx.x * 256 + threadIdx.x;
  if (idx >= elems) return;
  int j = idx & 7, lane = (idx >> 3) & 63;
  int rest = idx >> 9;
  int g = rest % NGp; rest /= NGp;
  int ih = rest & 1, tap = rest >> 1;
  int oc = g * 16 + (lane & 15);
  int ic = ih * 32 + (lane >> 4) * 8 + j;
  float v = 0.0f;
  if (oc < ocreal) v = w[(size_t)layer * wlstride + (oc * 64 + ic) * 9 + tap];
  uint32_t hi, lo;
  split_hl(v, hi, lo);
  out[(size_t)layer * olstride + idx] = (ushort_t)hi;
  out[(size_t)layer * olstride + elems + idx] = (ushort_t)lo;
}

// ---------------------------------------------------------------------------
__global__ void prep_kernel(const float* __restrict__ LowDEM, const float* __restrict__ Point_Ele,
                            const float* __restrict__ Slope, const float* __restrict__ Distance,
                            const float* __restrict__ Level, const float* __restrict__ w0,
                            const float* __restrict__ b0, float* __restrict__ x0) {
  int i = blockIdx.x * blockDim.x + threadIdx.x;
  if (i >= NPIX) return;
  float lv  = Level[i];
  float err = w0[0] * Slope[i] + w0[1] * Distance[i] + w0[2] * lv + b0[0];
  float lm  = (lv != 0.0f) ? 1.0f : 0.0f;
  x0[i] = LowDEM[i] * (1.0f - lm) + Point_Ele[i] + err * lm;
}

// ---------------------------------------------------------------------------
// conv9x9: when hiP != nullptr (fused path) writes X in HWC fp32 layout AND
// the bf16 hi/lo HWC planes; else planar NCHW (legacy).
__global__ __launch_bounds__(256, 2)
void conv9x9_kernel(const float* __restrict__ in, const float* __restrict__ wT,
                    const float* __restrict__ bias, float* __restrict__ out,
                    uint32_t* __restrict__ hiP, uint32_t* __restrict__ loP) {
  const int tx = threadIdx.x & 15, ty = threadIdx.x >> 4;
  const int w0 = blockIdx.x * 16, h0 = blockIdx.y * 16, b = blockIdx.z;
  __shared__ float lds[24 * 24];
  for (int idx = threadIdx.x; idx < 576; idx += 256) {
    int yy = idx / 24, xx = idx - yy * 24;
    int gy = h0 + yy - 4, gx = w0 + xx - 4;
    float v = 0.0f;
    if ((unsigned)gy < 256u && (unsigned)gx < 256u) v = in[b * HW + gy * 256 + gx];
    lds[idx] = v;
  }
  __syncthreads();
  float acc[64];
#pragma unroll
  for (int o = 0; o < 64; o++) acc[o] = 0.0f;
#pragma unroll 1
  for (int i = 0; i < 9; i++) {
#pragma unroll
    for (int j = 0; j < 9; j++) {
      float v = lds[(ty + i) * 24 + tx + j];
      const float* wp = wT + (i * 9 + j) * 64;   // uniform -> s_load
#pragma unroll
      for (int o = 0; o < 64; o++) acc[o] = fmaf(v, wp[o], acc[o]);
    }
  }
  const int p = (h0 + ty) * 256 + (w0 + tx);
  if (hiP) {
    float* op = out + ((size_t)b * HW + p) * 64;      // HWC fp32
#pragma unroll
    for (int o4 = 0; o4 < 16; o4++) {
      float4 v;
      v.x = acc[o4 * 4 + 0] + bias[o4 * 4 + 0];
      v.y = acc[o4 * 4 + 1] + bias[o4 * 4 + 1];
      v.z = acc[o4 * 4 + 2] + bias[o4 * 4 + 2];
      v.w = acc[o4 * 4 + 3] + bias[o4 * 4 + 3];
      *(float4*)(op + o4 * 4) = v;
    }
    uint32_t* hb = hiP + ((size_t)b * HW + p) * 32;
    uint32_t* lb = loP + ((size_t)b * HW + p) * 32;
#pragma unroll
    for (int o2 = 0; o2 < 32; o2++) {
      float v0 = acc[o2 * 2] + bias[o2 * 2];
      float v1 = acc[o2 * 2 + 1] + bias[o2 * 2 + 1];
      uint32_t h0v, l0v, h1v, l1v;
      split_hl(v0, h0v, l0v);
      split_hl(v1, h1v, l1v);
      hb[o2] = h0v | (h1v << 16);
      lb[o2] = l0v | (l1v << 16);
    }
  } else {
    float* op = out + (size_t)b * CHW + p;            // planar (legacy)
#pragma unroll
    for (int o = 0; o < 64; o++) op[o * HW] = acc[o] + bias[o];
  }
}

// ---------------------------------------------------------------------------
// OLD-STYLE MFMA conv3x3 (VALU-transform staging). Used for dc3/dc4 offset
// convs (INHWC) and the legacy (small-ws) path.
// MODE 0 plain / 1 relu(bn) / 2 bn+skip (WRITEY: materialize y). INHWC:
// pixel-major input.
// ---------------------------------------------------------------------------
template <int NG, int MODE, int STATS, int OCLIM, int HASBIAS, int WRITEY, int INHWC>
__global__ __launch_bounds__(256, 3)
void mfma_conv3(const float* __restrict__ in, const float* __restrict__ skip,
                const ushort_t* __restrict__ wf,
                const float* __restrict__ bias, const float* __restrict__ stats_in,
                const float* __restrict__ gg, const float* __restrict__ be,
                float* __restrict__ stats_out, float* __restrict__ yout,
                float* __restrict__ out) {
  const int tid  = threadIdx.x;
  const int lane = tid & 63, wid = tid >> 6;
  const int m = lane & 15, quad = lane >> 4;
  const int x0 = blockIdx.x * 16, y0 = blockIdx.y * 4, b = blockIdx.z;
  constexpr int WT = 2 * NG * 64 * 8;          // ushorts per tap per plane
  __shared__ __align__(16) ushort_t xh[108 * 68];   // hi plane, [spat][ch]
  __shared__ __align__(16) ushort_t xl[108 * 68];   // lo plane
  __shared__ float s_sc[MODE ? 64 : 1], s_sh[MODE ? 64 : 1];
  __shared__ float red[STATS ? 2 * 4 * 64 : 1];
  if (MODE) {
    if (tid < 64) {
      float sum = 0.0f, sq = 0.0f;
      for (int sl = 0; sl < NSLOT; sl++) {
        sum += stats_in[sl * 128 + tid];
        sq  += stats_in[sl * 128 + 64 + tid];
      }
      float mn = sum * INV_N, var = sq * INV_N - mn * mn;
      float s = gg[tid] * rsqrtf(var + EPSv);
      s_sc[tid] = s;
      s_sh[tid] = be[tid] - mn * s;
    }
    __syncthreads();
  }
  const float* inb = in + (size_t)b * CHW;
  const float* skb = MODE == 2 ? skip + (size_t)b * CHW : nullptr;
  float* ytb = WRITEY ? yout + (size_t)b * CHW : nullptr;
  uint32_t* xh32 = (uint32_t*)xh;              // row stride 34 dwords
  uint32_t* xl32 = (uint32_t*)xl;
#pragma unroll
  for (int t = 0; t < 14; t++) {
    int idx = t * 256 + tid;                   // 3456 = 108 spat * 32 ic-pairs
    if (idx < 3456) {
      int r, icp;
      if (INHWC) { icp = idx & 31; r = idx >> 5; }   // tid-contig ic -> coalesced HWC
      else       { r = idx % 108; icp = idx / 108; } // tid-contig px -> coalesced NCHW
      int row = r / 18, col = r - row * 18;
      int gy = y0 - 1 + row, gx = x0 - 1 + col;
      float v0 = 0.0f, v1 = 0.0f;
      if ((unsigned)gy < 256u && (unsigned)gx < 256u) {
        int ic = icp * 2;
        if (INHWC) {
          float2 vv = *(const float2*)&inb[(size_t)(gy * 256 + gx) * 64 + ic];
          v0 = vv.x; v1 = vv.y;
        } else {
          v0 = inb[ic * HW + gy * 256 + gx];
          v1 = inb[(ic + 1) * HW + gy * 256 + gx];
        }
        if (MODE == 1) {
          v0 = fmaxf(fmaf(v0, s_sc[ic], s_sh[ic]), 0.0f);
          v1 = fmaxf(fmaf(v1, s_sc[ic + 1], s_sh[ic + 1]), 0.0f);
        }
        if (MODE == 2) {
          v0 = fmaf(v0, s_sc[ic], s_sh[ic]) + skb[ic * HW + gy * 256 + gx];
          v1 = fmaf(v1, s_sc[ic + 1], s_sh[ic + 1]) + skb[(ic + 1) * HW + gy * 256 + gx];
          if (WRITEY && row >= 1 && row <= 4 && col >= 1 && col <= 16) {
            ytb[ic * HW + gy * 256 + gx] = v0;
            ytb[(ic + 1) * HW + gy * 256 + gx] = v1;
          }
        }
      }
      uint32_t h0, l0, h1, l1;
      split_hl(v0, h0, l0);
      split_hl(v1, h1, l1);
      xh32[r * 34 + icp] = h0 | (h1 << 16);
      xl32[r * 34 + icp] = l0 | (l1 << 16);
    }
  }
  __syncthreads();                             // the ONLY barrier before epilogue
  f32x4 acc[NG];
#pragma unroll
  for (int g = 0; g < NG; g++) acc[g] = (f32x4){0.0f, 0.0f, 0.0f, 0.0f};

  const bf16x8* wfh = (const bf16x8*)wf;                 // hi plane, frag-ordered
  const bf16x8* wfl = (const bf16x8*)(wf + 9 * WT);      // lo plane

#pragma unroll 1
  for (int tap = 0; tap < 9; tap++) {
    bf16x8 bh[2][NG], bl[2][NG];
#pragma unroll
    for (int ih = 0; ih < 2; ih++)
#pragma unroll
      for (int g = 0; g < NG; g++) {
        int fi = ((tap * 2 + ih) * NG + g) * 64 + lane;
        bh[ih][g] = wfh[fi];
        bl[ih][g] = wfl[fi];
      }
    const int dy = tap / 3 - 1, dx = tap % 3 - 1;
    const int spat = (wid + dy + 1) * 18 + (m + dx + 1);
#pragma unroll
    for (int ih = 0; ih < 2; ih++) {
      const int base = spat * 68 + ih * 32 + quad * 8;
      bf16x8 ah = lds_ld16(xh + base);
      bf16x8 al = lds_ld16(xl + base);
#pragma unroll
      for (int g = 0; g < NG; g++) {
        acc[g] = __builtin_amdgcn_mfma_f32_16x16x32_bf16(ah, bh[ih][g], acc[g], 0, 0, 0);
        acc[g] = __builtin_amdgcn_mfma_f32_16x16x32_bf16(al, bh[ih][g], acc[g], 0, 0, 0);
        acc[g] = __builtin_amdgcn_mfma_f32_16x16x32_bf16(ah, bl[ih][g], acc[g], 0, 0, 0);
      }
    }
  }
  // epilogue: D[row=quad*4+r][col=lane&15] -> pixel (y0+wid, x0+quad*4+r), oc=g*16+m
  const int py = y0 + wid;
  float* ob = out + (size_t)b * OCLIM * HW + py * 256 + x0 + quad * 4;
#pragma unroll
  for (int g = 0; g < NG; g++) {
    int oc = g * 16 + m;
    if (oc < OCLIM) {
      float bv = HASBIAS ? bias[oc] : 0.0f;
#pragma unroll
      for (int r = 0; r < 4; r++) ob[oc * HW + r] = acc[g][r] + bv;
    }
    if (STATS) {
      float s  = acc[g][0] + acc[g][1] + acc[g][2] + acc[g][3];
      float s2 = acc[g][0] * acc[g][0] + acc[g][1] * acc[g][1] +
                 acc[g][2] * acc[g][2] + acc[g][3] * acc[g][3];
      s  += __shfl_xor(s, 16, 64);  s  += __shfl_xor(s, 32, 64);
      s2 += __shfl_xor(s2, 16, 64); s2 += __shfl_xor(s2, 32, 64);
      if (lane < 16) {
        red[(0 * 4 + wid) * 64 + g * 16 + lane] = s;
        red[(1 * 4 + wid) * 64 + g * 16 + lane] = s2;
      }
    }
  }
  if (STATS) {
    __syncthreads();
    if (tid < 128) {
      int oc = tid & 63, which = tid >> 6;
      float tot = red[(which * 4 + 0) * 64 + oc] + red[(which * 4 + 1) * 64 + oc] +
                  red[(which * 4 + 2) * 64 + oc] + red[(which * 4 + 3) * 64 + oc];
      int slot = (blockIdx.y * 16 + blockIdx.x) & (NSLOT - 1);
      atomicAdd(&stats_out[slot * 128 + which * 64 + oc], tot);
    }
  }
}

// ---------------------------------------------------------------------------
// R18 chain conv: DMA staging + 16x8 tile (2 rows / wave, 2 M-tiles).
// Each wave reads the ENTIRE 147 KB weight tensor; halving blocks halves
// weight L2 traffic. LDS 46 KB -> 3 blocks/CU. (R18: 46 -> 35 us, WIN.)
// ---------------------------------------------------------------------------
__global__ __launch_bounds__(256, 3)
void mfma_conv3_dma(const ushort_t* __restrict__ hiP, const ushort_t* __restrict__ loP,
                    const ushort_t* __restrict__ wf, const float* __restrict__ zeroPg,
                    float* __restrict__ stats_out, float* __restrict__ out) {
  const int tid  = threadIdx.x;
  const int lane = tid & 63, wid = tid >> 6;
  const int m = lane & 15, quad = lane >> 4;
  const int x0 = blockIdx.x * 16, y0 = blockIdx.y * 8, b = blockIdx.z;
  // 180 spats (18 cols x 10 rows) * 8 chunks(16B) per plane; hi then lo.
  __shared__ __align__(16) ushort_t xs[2880 * 8];   // 46080 B
  __shared__ float red[2 * 4 * 64];
  const size_t bimg = (size_t)b * HW;
  for (int g = wid; g < 45; g += 4) {
    int q  = g * 64 + lane;                 // 0..2879
    int pl = q >= 1440;
    int r  = q - (pl ? 1440 : 0);
    int s  = r >> 3, jl = r & 7;
    int js = jl ^ (s & 7);
    int row = s / 18, col = s - row * 18;
    int gy = y0 - 1 + row, gx = x0 - 1 + col;
    const ushort_t* src = (const ushort_t*)zeroPg;
    if ((unsigned)gy < 256u && (unsigned)gx < 256u)
      src = (pl ? loP : hiP) + ((bimg + (size_t)(gy * 256 + gx)) << 6) + (js << 3);
    gld_lds16(src, (void*)&xs[(size_t)g * 512]);
  }
  __syncthreads();                           // compiler drains vmcnt here

  f32x4 acc[2][4];
#pragma unroll
  for (int t = 0; t < 2; t++)
#pragma unroll
    for (int g = 0; g < 4; g++) acc[t][g] = (f32x4){0.0f, 0.0f, 0.0f, 0.0f};
  const bf16x8* wfh = (const bf16x8*)wf;
  const bf16x8* wfl8 = (const bf16x8*)(wf + 9 * 4096);   // WT = 2*4*64*8 = 4096

#pragma unroll 1
  for (int tap = 0; tap < 9; tap++) {
    bf16x8 bh[2][4], bl[2][4];
#pragma unroll
    for (int ih = 0; ih < 2; ih++)
#pragma unroll
      for (int g = 0; g < 4; g++) {
        int fi = ((tap * 2 + ih) * 4 + g) * 64 + lane;
        bh[ih][g] = wfh[fi];
        bl[ih][g] = wfl8[fi];
      }
    const int dy = tap / 3 - 1, dxx = tap % 3 - 1;
    const int scol = m + dxx + 1;
#pragma unroll
    for (int t = 0; t < 2; t++) {
      const int s  = (wid * 2 + t + dy + 1) * 18 + scol;
      const int s7 = s & 7;
#pragma unroll
      for (int ih = 0; ih < 2; ih++) {
        const int ch = s * 8 + ((ih * 4 + quad) ^ s7);   // swizzled chunk
        bf16x8 ah = *(const bf16x8*)&xs[ch * 8];
        bf16x8 al = *(const bf16x8*)&xs[ch * 8 + 11520]; // lo plane (+1440 chunks)
#pragma unroll
        for (int g = 0; g < 4; g++) {
          acc[t][g] = __builtin_amdgcn_mfma_f32_16x16x32_bf16(ah, bh[ih][g], acc[t][g], 0, 0, 0);
          acc[t][g] = __builtin_amdgcn_mfma_f32_16x16x32_bf16(al, bh[ih][g], acc[t][g], 0, 0, 0);
          acc[t][g] = __builtin_amdgcn_mfma_f32_16x16x32_bf16(ah, bl[ih][g], acc[t][g], 0, 0, 0);
        }
      }
    }
  }
  // HWC epilogue: rows y0+wid*2+t, pixel col x0+quad*4+r, oc = g*16+m
#pragma unroll
  for (int g = 0; g < 4; g++) {
    int oc = g * 16 + m;
    float s = 0.0f, s2 = 0.0f;
#pragma unroll
    for (int t = 0; t < 2; t++) {
      const int py = y0 + wid * 2 + t;
      float* ob = out + ((size_t)b * HW + (size_t)py * 256 + x0) * 64;
#pragma unroll
      for (int r = 0; r < 4; r++) {
        float v = acc[t][g][r];
        ob[(quad * 4 + r) * 64 + oc] = v;
        s += v;
        s2 += v * v;
      }
    }
    s  += __shfl_xor(s, 16, 64);  s  += __shfl_xor(s, 32, 64);
    s2 += __shfl_xor(s2, 16, 64); s2 += __shfl_xor(s2, 32, 64);
    if (lane < 16) {
      red[(0 * 4 + wid) * 64 + g * 16 + lane] = s;
      red[(1 * 4 + wid) * 64 + g * 16 + lane] = s2;
    }
  }
  __syncthreads();
  if (tid < 128) {
    int oc = tid & 63, which = tid >> 6;
    float tot = red[(which * 4 + 0) * 64 + oc] + red[(which * 4 + 1) * 64 + oc] +
                red[(which * 4 + 2) * 64 + oc] + red[(which * 4 + 3) * 64 + oc];
    int slot = (blockIdx.y * 16 + blockIdx.x) & (NSLOT - 1);
    atomicAdd(&stats_out[slot * 128 + which * 64 + oc], tot);
  }
}

// ---------------------------------------------------------------------------
// R20 offset conv (dc2): DMA staging from bf16 hi/lo planes (16x8, same
// geometry as chain conv), NG=2, planar-27 epilogue with bias.
// ---------------------------------------------------------------------------
__global__ __launch_bounds__(256, 3)
void ofs_conv_dma(const ushort_t* __restrict__ hiP, const ushort_t* __restrict__ loP,
                  const ushort_t* __restrict__ wf, const float* __restrict__ zeroPg,
                  const float* __restrict__ bias, float* __restrict__ out) {
  const int tid  = threadIdx.x;
  const int lane = tid & 63, wid = tid >> 6;
  const int m = lane & 15, quad = lane >> 4;
  const int x0 = blockIdx.x * 16, y0 = blockIdx.y * 8, b = blockIdx.z;
  __shared__ __align__(16) ushort_t xs[2880 * 8];   // 46080 B
  const size_t bimg = (size_t)b * HW;
  for (int g = wid; g < 45; g += 4) {
    int q  = g * 64 + lane;
    int pl = q >= 1440;
    int r  = q - (pl ? 1440 : 0);
    int s  = r >> 3, jl = r & 7;
    int js = jl ^ (s & 7);
    int row = s / 18, col = s - row * 18;
    int gy = y0 - 1 + row, gx = x0 - 1 + col;
    const ushort_t* src = (const ushort_t*)zeroPg;
    if ((unsigned)gy < 256u && (unsigned)gx < 256u)
      src = (pl ? loP : hiP) + ((bimg + (size_t)(gy * 256 + gx)) << 6) + (js << 3);
    gld_lds16(src, (void*)&xs[(size_t)g * 512]);
  }
  __syncthreads();

  f32x4 acc[2][2];
#pragma unroll
  for (int t = 0; t < 2; t++)
#pragma unroll
    for (int g = 0; g < 2; g++) acc[t][g] = (f32x4){0.0f, 0.0f, 0.0f, 0.0f};
  const bf16x8* wfh = (const bf16x8*)wf;
  const bf16x8* wfl8 = (const bf16x8*)(wf + 9 * 2048);   // WT = 2*2*64*8 = 2048

#pragma unroll 1
  for (int tap = 0; tap < 9; tap++) {
    bf16x8 bh[2][2], bl[2][2];
#pragma unroll
    for (int ih = 0; ih < 2; ih++)
#pragma unroll
      for (int g = 0; g < 2; g++) {
        int fi = ((tap * 2 + ih) * 2 + g) * 64 + lane;
        bh[ih][g] = wfh[fi];
        bl[ih][g] = wfl8[fi];
      }
    const int dy = tap / 3 - 1, dxx = tap % 3 - 1;
    const int scol = m + dxx + 1;
#pragma unroll
    for (int t = 0; t < 2; t++) {
      const int s  = (wid * 2 + t + dy + 1) * 18 + scol;
      const int s7 = s & 7;
#pragma unroll
      for (int ih = 0; ih < 2; ih++) {
        const int ch = s * 8 + ((ih * 4 + quad) ^ s7);
        bf16x8 ah = *(const bf16x8*)&xs[ch * 8];
        bf16x8 al = *(const bf16x8*)&xs[ch * 8 + 11520];
#pragma unroll
        for (int g = 0; g < 2; g++) {
          acc[t][g] = __builtin_amdgcn_mfma_f32_16x16x32_bf16(ah, bh[ih][g], acc[t][g], 0, 0, 0);
          acc[t][g] = __builtin_amdgcn_mfma_f32_16x16x32_bf16(al, bh[ih][g], acc[t][g], 0, 0, 0);
          acc[t][g] = __builtin_amdgcn_mfma_f32_16x16x32_bf16(ah, bl[ih][g], acc[t][g], 0, 0, 0);
        }
      }
    }
  }
  // planar epilogue (om layout [B][27][HW] kept for dcn's coalesced om reads)
#pragma unroll
  for (int g = 0; g < 2; g++) {
    int oc = g * 16 + m;
    if (oc < 27) {
      float bv = bias[oc];
#pragma unroll
      for (int t = 0; t < 2; t++) {
        const int py = y0 + wid * 2 + t;
        float* ob = out + (size_t)b * 27 * HW + (size_t)oc * HW + py * 256 + x0 + quad * 4;
#pragma unroll
        for (int r = 0; r < 4; r++) ob[r] = acc[t][g][r] + bv;
      }
    }
  }
}

// ---------------------------------------------------------------------------
// R17 transform: all-HWC streaming. Finalize BN of raw conv out t (HWC) and
// materialize bf16 hi/lo HWC planes. TMODE 1: relu(bn(t)) -> planes only.
// TMODE 2: y = bn(t)+skip -> y fp32 HWC + planes. Parallel stats preamble.
// ---------------------------------------------------------------------------
template <int TMODE>
__global__ __launch_bounds__(256, 8)
void bn_split_hwc(const float* __restrict__ t, const float* __restrict__ stats,
                  const float* __restrict__ g, const float* __restrict__ be,
                  const float* __restrict__ skip, float* __restrict__ yout,
                  uint32_t* __restrict__ hiP, uint32_t* __restrict__ loP) {
  __shared__ float part[2][4][64];
  __shared__ float s_sc[64], s_sh[64];
  const int tid = threadIdx.x;
  {
    int c = tid & 63, q = tid >> 6;
    float sum = 0.0f, sq = 0.0f;
    for (int sl = q * 16; sl < q * 16 + 16; sl++) {
      sum += stats[sl * 128 + c];
      sq  += stats[sl * 128 + 64 + c];
    }
    part[0][q][c] = sum;
    part[1][q][c] = sq;
  }
  __syncthreads();
  if (tid < 64) {
    int c = tid;
    float sum = part[0][0][c] + part[0][1][c] + part[0][2][c] + part[0][3][c];
    float sq  = part[1][0][c] + part[1][1][c] + part[1][2][c] + part[1][3][c];
    float mn  = sum * INV_N;
    float var = sq * INV_N - mn * mn;
    float s   = g[c] * rsqrtf(var + EPSv);
    s_sc[c] = s;
    s_sh[c] = be[c] - mn * s;
  }
  __syncthreads();
  const int blk = blockIdx.x;            // 2048 = NPIX/64
  const int b  = blk >> 10;
  const int p0 = (blk & 1023) * 64;
  const size_t base = ((size_t)b * HW + p0) * 64;   // floats (HWC)
  uint32_t* hb = hiP + ((size_t)b * HW + p0) * 32;
  uint32_t* lb = loP + ((size_t)b * HW + p0) * 32;
#pragma unroll
  for (int i = 0; i < 8; i++) {
    int idx = i * 256 + tid;             // 0..2047 = 64 px * 32 ch-pairs
    int p = idx >> 5, c2 = idx & 31;
    size_t off = base + (size_t)p * 64 + c2 * 2;
    float2 v = *(const float2*)&t[off];
    float v0 = fmaf(v.x, s_sc[c2 * 2],     s_sh[c2 * 2]);
    float v1 = fmaf(v.y, s_sc[c2 * 2 + 1], s_sh[c2 * 2 + 1]);
    if (TMODE == 1) {
      v0 = fmaxf(v0, 0.0f);
      v1 = fmaxf(v1, 0.0f);
    } else {
      float2 k = *(const float2*)&skip[off];
      v0 += k.x; v1 += k.y;
      float2 y2; y2.x = v0; y2.y = v1;
      *(float2*)&yout[off] = y2;
    }
    uint32_t h0v, l0v, h1v, l1v;
    split_hl(v0, h0v, l0v);
    split_hl(v1, h1v, l1v);
    hb[p * 32 + c2] = h0v | (h1v << 16);
    lb[p * 32 + c2] = l0v | (l1v << 16);
  }
}

// ---------------------------------------------------------------------------
// R20: x = bn(t)+skip, all-HWC streaming; also emits x's bf16 hi/lo planes
// (feeds the DMA offset conv for dc2).
// ---------------------------------------------------------------------------
__global__ __launch_bounds__(256, 8)
void bn_add_hwc(const float* __restrict__ t, const float* __restrict__ stats,
                const float* __restrict__ g, const float* __restrict__ be,
                const float* __restrict__ skip, float* __restrict__ xout,
                uint32_t* __restrict__ hiP, uint32_t* __restrict__ loP) {
  __shared__ float part[2][4][64];
  __shared__ float s_sc[64], s_sh[64];
  const int tid = threadIdx.x;
  {
    int c = tid & 63, q = tid >> 6;
    float sum = 0.0f, sq = 0.0f;
    for (int sl = q * 16; sl < q * 16 + 16; sl++) {
      sum += stats[sl * 128 + c];
      sq  += stats[sl * 128 + 64 + c];
    }
    part[0][q][c] = sum;
    part[1][q][c] = sq;
  }
  __syncthreads();
  if (tid < 64) {
    int c = tid;
    float sum = part[0][0][c] + part[0][1][c] + part[0][2][c] + part[0][3][c];
    float sq  = part[1][0][c] + part[1][1][c] + part[1][2][c] + part[1][3][c];
    float mn  = sum * INV_N;
    float var = sq * INV_N - mn * mn;
    float s   = g[c] * rsqrtf(var + EPSv);
    s_sc[c] = s;
    s_sh[c] = be[c] - mn * s;
  }
  __syncthreads();
  const int blk = blockIdx.x;            // 2048
  const int b  = blk >> 10;
  const int p0 = (blk & 1023) * 64;
  const size_t base4 = (((size_t)b * HW + p0) * 64) >> 2;   // float4 units
  const float4* t4 = (const float4*)t;
  const float4* k4 = (const float4*)skip;
  float4* x4 = (float4*)xout;
  uint32_t* hb = hiP + ((size_t)b * HW + p0) * 32;
  uint32_t* lb = loP + ((size_t)b * HW + p0) * 32;
#pragma unroll
  for (int i = 0; i < 4; i++) {
    int idx = i * 256 + tid;             // 0..1023 = 64 px * 16 ch-quads
    int c = (idx & 15) * 4;
    int p = idx >> 4;
    float4 v = t4[base4 + idx], k = k4[base4 + idx], r;
    r.x = fmaf(v.x, s_sc[c],     s_sh[c])     + k.x;
    r.y = fmaf(v.y, s_sc[c + 1], s_sh[c + 1]) + k.y;
    r.z = fmaf(v.z, s_sc[c + 2], s_sh[c + 2]) + k.z;
    r.w = fmaf(v.w, s_sc[c + 3], s_sh[c + 3]) + k.w;
    x4[base4 + idx] = r;
    uint32_t h0v, l0v, h1v, l1v, h2v, l2v, h3v, l3v;
    split_hl(r.x, h0v, l0v); split_hl(r.y, h1v, l1v);
    split_hl(r.z, h2v, l2v); split_hl(r.w, h3v, l3v);
    uint2 hv = make_uint2(h0v | (h1v << 16), h2v | (h3v << 16));
    uint2 lv = make_uint2(l0v | (l1v << 16), l2v | (l3v << 16));
    *(uint2*)&hb[p * 32 + (c >> 1)] = hv;
    *(uint2*)&lb[p * 32 + (c >> 1)] = lv;
  }
}

// ---------------------------------------------------------------------------
// Legacy path only: y = BN(t)*g+be + skip (float4).
// ---------------------------------------------------------------------------
__global__ void bn_apply_add_kernel(const float* __restrict__ t, const float* __restrict__ stats,
                                    const float* __restrict__ g, const float* __restrict__ be,
                                    const float* __restrict__ skip, float* __restrict__ out) {
  __shared__ float s_sc[64], s_sh[64];
  if (threadIdx.x < 64) {
    int c = threadIdx.x;
    float sum = 0.0f, sq = 0.0f;
    for (int sl = 0; sl < NSLOT; sl++) {
      sum += stats[sl * 128 + c];
      sq  += stats[sl * 128 + 64 + c];
    }
    float m   = sum * INV_N;
    float var = sq * INV_N - m * m;
    float s   = g[c] * rsqrtf(var + EPSv);
    s_sc[c] = s;
    s_sh[c] = be[c] - m * s;
  }
  __syncthreads();
  const float4* t4 = (const float4*)t;
  const float4* k4 = (const float4*)skip;
  float4* o4 = (float4*)out;
  const int n4 = NCHW / 4;
  for (int i = blockIdx.x * blockDim.x + threadIdx.x; i < n4; i += gridDim.x * blockDim.x) {
    int c = (i >> 14) & 63;
    float s = s_sc[c], h = s_sh[c];
    float4 v = t4[i], kk = k4[i], r;
    r.x = fmaf(v.x, s, h) + kk.x;
    r.y = fmaf(v.y, s, h) + kk.y;
    r.z = fmaf(v.z, s, h) + kk.z;
    r.w = fmaf(v.w, s, h) + kk.w;
    o4[i] = r;
  }
}

// ---------------------------------------------------------------------------
// Legacy path only: fused x = bn(t)+skip -> planar out AND HWC mirror.
// ---------------------------------------------------------------------------
__global__ __launch_bounds__(256, 4)
void bn_tx_kernel(const float* __restrict__ t, const float* __restrict__ stats,
                  const float* __restrict__ g, const float* __restrict__ be,
                  const float* __restrict__ skip, float* __restrict__ outP,
                  float* __restrict__ outHWC) {
  __shared__ float tile[64][65];
  __shared__ float s_sc[64], s_sh[64];
  if (threadIdx.x < 64) {
    int c = threadIdx.x;
    float sum = 0.0f, sq = 0.0f;
    for (int sl = 0; sl < NSLOT; sl++) {
      sum += stats[sl * 128 + c];
      sq  += stats[sl * 128 + 64 + c];
    }
    float m   = sum * INV_N;
    float var = sq * INV_N - m * m;
    float s   = g[c] * rsqrtf(var + EPSv);
    s_sc[c] = s;
    s_sh[c] = be[c] - m * s;
  }
  __syncthreads();
  const int blk = blockIdx.x;            // 2048 = NPIX/64
  const int b = blk >> 10;
  const int p0 = (blk & 1023) * 64;
  const float* tb = t + (size_t)b * CHW;
  const float* kb = skip + (size_t)b * CHW;
  float* oP = outP + (size_t)b * CHW;
  float* oH = outHWC + (size_t)b * CHW;
#pragma unroll
  for (int i = 0; i < 16; i++) {
    int idx = i * 256 + threadIdx.x;
    int c = idx >> 6, p = idx & 63;
    float v = fmaf(tb[c * HW + p0 + p], s_sc[c], s_sh[c]) + kb[c * HW + p0 + p];
    oP[c * HW + p0 + p] = v;
    tile[c][p] = v;
  }
  __syncthreads();
#pragma unroll
  for (int i = 0; i < 16; i++) {
    int idx = i * 256 + threadIdx.x;
    int p = idx >> 6, c = idx & 63;
    oH[(size_t)(p0 + p) * 64 + c] = tile[c][p];
  }
}

// ---------------------------------------------------------------------------
// Deformable conv on MFMA, HWC input. R21: R18 schedule (double-buffered LDS,
// gather(tap+1) before MFMAs, 1 barrier/tap — measured-best structure) with a
// remapped gather: quad-per-pixel (gp = tid>>2, c4 = tid&3). For each corner
// the 4 lanes of a pixel read contiguous 64B (one cache line) -> 16 L1
// transactions per load instr instead of 64 (old: 64 lanes = 64 scattered
// pixels). LDS write conflicts drop 16-way -> 4-way. Per-channel math is
// expression-identical; LDS layout & read side unchanged.
// R16 reg-only REGRESSED; R19 cross-iteration pipeline FAILED correctness.
// FINAL: fuse dc4 bias + conv4.
// ---------------------------------------------------------------------------
template <int NG, int FINAL>
__global__ __launch_bounds__(256, 4)
void dcn_mfma(const float* __restrict__ xhwc, const float* __restrict__ om,
              const ushort_t* __restrict__ wf, const float* __restrict__ bias,
              const float* __restrict__ c4w, const float* __restrict__ c4b,
              float* __restrict__ out) {
  const int tid  = threadIdx.x;
  const int lane = tid & 63, wid = tid >> 6;
  const int m = lane & 15, quad = lane >> 4;
  const int x0 = blockIdx.x * 16, y0 = blockIdx.y * 4, b = blockIdx.z;
  constexpr int WT = 2 * NG * 64 * 8;
  __shared__ __align__(16) ushort_t sh[2][64 * 64];   // hi plane per buffer, 8 KB
  __shared__ __align__(16) ushort_t sl[2][64 * 64];   // lo plane
  const int gp = tid >> 2, c4 = tid & 3;       // gather role: pixel, 16B-chunk lane
  const int gpy = y0 + (gp >> 4), gxx = x0 + (gp & 15);
  const int psw = gp & 3;                      // pixel swizzle bits
  const float* xb  = xhwc + (size_t)b * CHW;
  const float* omb = om + (size_t)b * 27 * HW + gpy * 256 + gxx;

  auto gather = [&](int tap, int buf) {
    float dyv = omb[tap * HW];
    float dxv = omb[(9 + tap) * HW];
    float mo  = omb[(18 + tap) * HW];
    float mk  = 1.0f / (1.0f + __expf(-mo));
    float ys = fminf(fmaxf((float)(gpy + tap / 3 - 1) + dyv, -2.0f), 258.0f);
    float xs = fminf(fmaxf((float)(gxx + tap % 3 - 1) + dxv, -2.0f), 258.0f);
    float y0f = floorf(ys), x0f = floorf(xs);
    float wy = ys - y0f, wx = xs - x0f;
    int yi = (int)y0f, xi = (int)x0f;
    float vy0 = ((unsigned)yi       < 256u) ? 1.0f : 0.0f;
    float vy1 = ((unsigned)(yi + 1) < 256u) ? 1.0f : 0.0f;
    float vx0 = ((unsigned)xi       < 256u) ? 1.0f : 0.0f;
    float vx1 = ((unsigned)(xi + 1) < 256u) ? 1.0f : 0.0f;
    int cy0 = min(max(yi, 0), 255), cy1 = min(max(yi + 1, 0), 255);
    int cx0 = min(max(xi, 0), 255), cx1 = min(max(xi + 1, 0), 255);
    float W00 = (1.0f - wy) * (1.0f - wx) * mk * vy0 * vx0;
    float W01 = (1.0f - wy) * wx * mk * vy0 * vx1;
    float W10 = wy * (1.0f - wx) * mk * vy1 * vx0;
    float W11 = wy * wx * mk * vy1 * vx1;
    const float* p00 = xb + (size_t)(cy0 * 256 + cx0) * 64;
    const float* p01 = xb + (size_t)(cy0 * 256 + cx1) * 64;
    const float* p10 = xb + (size_t)(cy1 * 256 + cx0) * 64;
    const float* p11 = xb + (size_t)(cy1 * 256 + cx1) * 64;
#pragma unroll
    for (int j = 0; j < 4; j++) {
      const int k = c4 + 4 * j;                // 4-ch chunk index 0..15
      float4 a  = *(const float4*)(p00 + k * 4);
      float4 b2 = *(const float4*)(p01 + k * 4);
      float4 c2 = *(const float4*)(p10 + k * 4);
      float4 d2 = *(const float4*)(p11 + k * 4);
      float s0 = W00 * a.x + W01 * b2.x + W10 * c2.x + W11 * d2.x;
      float s1 = W00 * a.y + W01 * b2.y + W10 * c2.y + W11 * d2.y;
      float s2 = W00 * a.z + W01 * b2.z + W10 * c2.z + W11 * d2.z;
      float s3 = W00 * a.w + W01 * b2.w + W10 * c2.w + W11 * d2.w;
      uint32_t h0, l0, h1, l1, h2, l2, h3, l3;
      split_hl(s0, h0, l0); split_hl(s1, h1, l1);
      split_hl(s2, h2, l2); split_hl(s3, h3, l3);
      // chunk k lives at group (k>>2)=j, sub (k&3)=c4 -> same layout as before
      int wi = gp * 64 + ((j ^ psw) * 16) + c4 * 4;   // 8B-aligned
      *(uint2*)&sh[buf][wi] = make_uint2(h0 | (h1 << 16), h2 | (h3 << 16));
      *(uint2*)&sl[buf][wi] = make_uint2(l0 | (l1 << 16), l2 | (l3 << 16));
    }
  };

  f32x4 acc[NG];
#pragma unroll
  for (int g = 0; g < NG; g++) acc[g] = (f32x4){0.0f, 0.0f, 0.0f, 0.0f};
  const bf16x8* wfh = (const bf16x8*)wf;
  const bf16x8* wfl = (const bf16x8*)(wf + 9 * WT);
  const int px = wid * 16 + m;                 // this lane's A-row pixel

  gather(0, 0);
  __syncthreads();
#pragma unroll 1
  for (int tap = 0; tap < 9; tap++) {
    const int cur = tap & 1;
    if (tap < 8) gather(tap + 1, cur ^ 1);     // overlaps MFMAs below
#pragma unroll
    for (int ih = 0; ih < 2; ih++) {
      const int c = ih * 2 + (quad >> 1), h = quad & 1;
      const int ri = px * 64 + ((c ^ (px & 3)) * 16) + h * 8;   // 16B-aligned
      bf16x8 ah = *(const bf16x8*)&sh[cur][ri];
      bf16x8 al = *(const bf16x8*)&sl[cur][ri];
#pragma unroll
      for (int g = 0; g < NG; g++) {
        int fi = ((tap * 2 + ih) * NG + g) * 64 + lane;
        bf16x8 bh = wfh[fi], bl = wfl[fi];
        acc[g] = __builtin_amdgcn_mfma_f32_16x16x32_bf16(ah, bh, acc[g], 0, 0, 0);
        acc[g] = __builtin_amdgcn_mfma_f32_16x16x32_bf16(al, bh, acc[g], 0, 0, 0);
        acc[g] = __builtin_amdgcn_mfma_f32_16x16x32_bf16(ah, bl, acc[g], 0, 0, 0);
      }
    }
    __syncthreads();   // writes to buf^1 and reads of cur both done
  }
  const int py = y0 + wid;
  if (FINAL) {
    if (m == 0) {
      float* op = out + (size_t)b * HW + py * 256 + x0 + quad * 4;
#pragma unroll
      for (int r = 0; r < 4; r++) op[r] = c4w[0] * (acc[0][r] + bias[0]) + c4b[0];
    }
  } else {
    float* ob = out + (size_t)b * CHW + ((size_t)py * 256 + x0 + quad * 4) * 64 + m;
#pragma unroll
    for (int g = 0; g < NG; g++)
#pragma unroll
      for (int r = 0; r < 4; r++)
        ob[r * 64 + g * 16] = fmaxf(acc[g][r] + bias[g * 16 + m], 0.0f);
  }
}

// ---------------------------------------------------------------------------
extern "C" void kernel_launch(void* const* d_in, const int* in_sizes, int n_in,
                              void* d_out, int out_size, void* d_ws, size_t ws_size,
                              hipStream_t stream) {
  const float* LowDEM    = (const float*)d_in[0];
  const float* Point_Ele = (const float*)d_in[1];
  const float* Slope     = (const float*)d_in[2];
  const float* Distance  = (const float*)d_in[3];
  const float* Level     = (const float*)d_in[4];
  const float* conv0_w   = (const float*)d_in[5];
  const float* conv0_b   = (const float*)d_in[6];
  const float* conv1_w   = (const float*)d_in[7];
  const float* conv1_b   = (const float*)d_in[8];
  const float* rb_w1     = (const float*)d_in[9];
  const float* rb_g1     = (const float*)d_in[11];
  const float* rb_be1    = (const float*)d_in[12];
  const float* rb_w2     = (const float*)d_in[13];
  const float* rb_g2     = (const float*)d_in[15];
  const float* rb_be2    = (const float*)d_in[16];
  const float* conv2_w   = (const float*)d_in[17];
  const float* bn2_g     = (const float*)d_in[19];
  const float* bn2_be    = (const float*)d_in[20];
  const float* dc2_w     = (const float*)d_in[21];
  const float* dc2_b     = (const float*)d_in[22];
  const float* dc2_ow    = (const float*)d_in[23];
  const float* dc2_ob    = (const float*)d_in[24];
  const float* dc3_w     = (const float*)d_in[25];
  const float* dc3_b     = (const float*)d_in[26];
  const float* dc3_ow    = (const float*)d_in[27];
  const float* dc3_ob    = (const float*)d_in[28];
  const float* dc4_w     = (const float*)d_in[29];
  const float* dc4_b     = (const float*)d_in[30];
  const float* dc4_ow    = (const float*)d_in[31];
  const float* dc4_ob    = (const float*)d_in[32];
  const float* conv4_w   = (const float*)d_in[33];
  const float* conv4_b   = (const float*)d_in[34];

  // small region first, then big buffers
  float* x0   = (float*)d_ws;             // 131072
  float* T1   = x0 + NPIX;                // 5184
  ushort_t* WF = (ushort_t*)(T1 + 5184);  // 39 * WFL ushorts
  float* stats = (float*)(WF + 39 * WFL); // 33 * STSLOT floats
  float* zpg   = stats + 33 * STSLOT;     // 32 floats: DMA zero page
  float* big   = zpg + 32;
  size_t used_small = (size_t)((char*)big - (char*)d_ws);
  bool fused = ws_size >= used_small + 5ull * NCHW * sizeof(float);

  float* bufX = big;                      // X (conv9x9 out; skip for bn2)
  float* bufT = bufX + NCHW;              // raw conv out / offset-conv out
  float* R3   = bufT + NCHW;              // fused: yA   | legacy: bufT2
  float* R4   = R3 + NCHW;                // fused: yB   | legacy: yA(=yB)
  ushort_t* hiP = (ushort_t*)(R4 + NCHW); // fused only: bf16 hi plane (HWC)
  ushort_t* loP = hiP + NCHW;             //             bf16 lo plane (HWC)

  hipMemsetAsync(stats, 0, 33 * STSLOT * sizeof(float), stream);
  hipMemsetAsync(zpg, 0, 128, stream);

  transpose_w_kernel<<<32, 256, 0, stream>>>(conv1_w, T1, 1, 64, 1, 81);

  prep_wfrag<<<dim3(144, 16), 256, 0, stream>>>(rb_w1,   WF,            4, 64, 36864, WFL);
  prep_wfrag<<<dim3(144, 16), 256, 0, stream>>>(rb_w2,   WF + 16 * WFL, 4, 64, 36864, WFL);
  prep_wfrag<<<dim3(144, 1),  256, 0, stream>>>(conv2_w, WF + 32 * WFL, 4, 64, 36864, WFL);
  prep_wfrag<<<dim3(72, 1),   256, 0, stream>>>(dc2_ow,  WF + 33 * WFL, 2, 27, 15552, WFL);
  prep_wfrag<<<dim3(72, 1),   256, 0, stream>>>(dc3_ow,  WF + 34 * WFL, 2, 27, 15552, WFL);
  prep_wfrag<<<dim3(72, 1),   256, 0, stream>>>(dc4_ow,  WF + 35 * WFL, 2, 27, 15552, WFL);
  prep_wfrag<<<dim3(144, 1),  256, 0, stream>>>(dc2_w,   WF + 36 * WFL, 4, 64, 36864, WFL);
  prep_wfrag<<<dim3(144, 1),  256, 0, stream>>>(dc3_w,   WF + 37 * WFL, 4, 64, 36864, WFL);
  prep_wfrag<<<dim3(36, 1),   256, 0, stream>>>(dc4_w,   WF + 38 * WFL, 1, 1, 576, WFL);

  prep_kernel<<<(NPIX + 255) / 256, 256, 0, stream>>>(LowDEM, Point_Ele, Slope, Distance,
                                                      Level, conv0_w, conv0_b, x0);

  dim3 grid16(16, 16, 2);   // conv9x9
  dim3 gmf(16, 64, 2);      // dcn_mfma / legacy conv (16x4 pixel tiles)
  dim3 gmf8(16, 32, 2);     // chain conv / ofs conv (16x8 pixel tiles)

  conv9x9_kernel<<<grid16, 256, 0, stream>>>(x0, T1, conv1_b, bufX,
                                             fused ? (uint32_t*)hiP : nullptr,
                                             fused ? (uint32_t*)loP : nullptr);

  if (fused) {
    float* yA = R3;
    float* yB = R4;
    // R18: all-HWC chain — 16x8-tile DMA convs + streaming bn/split.
    for (int i = 0; i < 16; i++) {
      mfma_conv3_dma<<<gmf8, 256, 0, stream>>>(hiP, loP, WF + (size_t)i * WFL, zpg,
                                               stats + (size_t)(2 * i) * STSLOT, bufT);
      bn_split_hwc<1><<<2048, 256, 0, stream>>>(
          bufT, stats + (size_t)(2 * i) * STSLOT, rb_g1 + i * 64, rb_be1 + i * 64,
          nullptr, nullptr, (uint32_t*)hiP, (uint32_t*)loP);
      mfma_conv3_dma<<<gmf8, 256, 0, stream>>>(hiP, loP, WF + (size_t)(16 + i) * WFL, zpg,
                                               stats + (size_t)(2 * i + 1) * STSLOT, bufT);
      const float* skp = (i == 0) ? bufX : ((i & 1) ? yA : yB);   // y_i
      float* yo = (i & 1) ? yB : yA;                              // y_{i+1}
      bn_split_hwc<2><<<2048, 256, 0, stream>>>(
          bufT, stats + (size_t)(2 * i + 1) * STSLOT, rb_g2 + i * 64, rb_be2 + i * 64,
          skp, yo, (uint32_t*)hiP, (uint32_t*)loP);
    }
    mfma_conv3_dma<<<gmf8, 256, 0, stream>>>(hiP, loP, WF + (size_t)32 * WFL, zpg,
                                             stats + (size_t)32 * STSLOT, bufT);

    float* xT    = R4;          // y16 fp32 dead (its planes fed conv2)
    float* d2out = R3;          // yA dead after i=15
    float* d3out = (float*)hiP; // plane region dead after ofs dc2 below
    // x = bn(conv2_out) + X -> xT (HWC) + x planes (for dc2's offset conv)
    bn_add_hwc<<<2048, 256, 0, stream>>>(bufT, stats + 32 * STSLOT, bn2_g, bn2_be,
                                         bufX, xT, (uint32_t*)hiP, (uint32_t*)loP);
    // dc2: DMA offset conv from x planes
    ofs_conv_dma<<<gmf8, 256, 0, stream>>>(hiP, loP, WF + (size_t)33 * WFL, zpg,
                                           dc2_ob, bufT);
    dcn_mfma<4, 0><<<gmf, 256, 0, stream>>>(xT, bufT, WF + (size_t)36 * WFL, dc2_b,
                                            nullptr, nullptr, d2out);
    // dc3: VALU-staged offset conv from d2out fp32 HWC (proven path)
    mfma_conv3<2, 0, 0, 27, 1, 0, 1><<<gmf, 256, 0, stream>>>(
        d2out, nullptr, WF + (size_t)34 * WFL, dc3_ob, nullptr, nullptr, nullptr,
        nullptr, nullptr, bufT);
    dcn_mfma<4, 0><<<gmf, 256, 0, stream>>>(d2out, bufT, WF + (size_t)37 * WFL, dc3_b,
                                            nullptr, nullptr, d3out);
    // dc4 + conv4 -> d_out
    mfma_conv3<2, 0, 0, 27, 1, 0, 1><<<gmf, 256, 0, stream>>>(
        d3out, nullptr, WF + (size_t)35 * WFL, dc4_ob, nullptr, nullptr, nullptr,
        nullptr, nullptr, bufT);
    dcn_mfma<1, 1><<<gmf, 256, 0, stream>>>(d3out, bufT, WF + (size_t)38 * WFL, dc4_b,
                                            conv4_w, conv4_b, (float*)d_out);
  } else {
    float* bufT2 = R3;
    float* bufY  = R4;
    for (int i = 0; i < 16; i++) {
      const float* src = (i == 0) ? bufX : bufY;
      mfma_conv3<4, 0, 1, 64, 0, 0, 0><<<gmf, 256, 0, stream>>>(
          src, nullptr, WF + (size_t)i * WFL, nullptr, nullptr, nullptr, nullptr,
          stats + (2 * i) * STSLOT, nullptr, bufT);
      mfma_conv3<4, 1, 1, 64, 0, 0, 0><<<gmf, 256, 0, stream>>>(
          bufT, nullptr, WF + (size_t)(16 + i) * WFL, nullptr, stats + (2 * i) * STSLOT,
          rb_g1 + i * 64, rb_be1 + i * 64, stats + (2 * i + 1) * STSLOT, nullptr, bufT2);
      bn_apply_add_kernel<<<2048, 256, 0, stream>>>(bufT2, stats + (2 * i + 1) * STSLOT,
                                                    rb_g2 + i * 64, rb_be2 + i * 64, src, bufY);
    }
    mfma_conv3<4, 0, 1, 64, 0, 0, 0><<<gmf, 256, 0, stream>>>(
        bufY, nullptr, WF + (size_t)32 * WFL, nullptr, nullptr, nullptr, nullptr,
        stats + 32 * STSLOT, nullptr, bufT);
    float* xT    = R4;
    float* d2out = R3;
    float* d3out = R4;
    bn_tx_kernel<<<2048, 256, 0, stream>>>(bufT, stats + 32 * STSLOT, bn2_g, bn2_be,
                                           bufX, bufX, xT);
    mfma_conv3<2, 0, 0, 27, 1, 0, 0><<<gmf, 256, 0, stream>>>(
        bufX, nullptr, WF + (size_t)33 * WFL, dc2_ob, nullptr, nullptr, nullptr,
        nullptr, nullptr, bufT);
    dcn_mfma<4, 0><<<gmf, 256, 0, stream>>>(xT, bufT, WF + (size_t)36 * WFL, dc2_b,
                                            nullptr, nullptr, d2out);
    mfma_conv3<2, 0, 0, 27, 1, 0, 1><<<gmf, 256, 0, stream>>>(
        d2out, nullptr, WF + (size_t)34 * WFL, dc3_ob, nullptr, nullptr, nullptr,
        nullptr, nullptr, bufT);
    dcn_mfma<4, 0><<<gmf, 256, 0, stream>>>(d2out, bufT, WF + (size_t)37 * WFL, dc3_b,
                                            nullptr, nullptr, d3out);
    mfma_conv3<2, 0, 0, 27, 1, 0, 1><<<gmf, 256, 0, stream>>>(
        d3out, nullptr, WF + (size_t)35 * WFL, dc4_ob, nullptr, nullptr, nullptr,
        nullptr, nullptr, bufT);
    dcn_mfma<1, 1><<<gmf, 256, 0, stream>>>(d3out, bufT, WF + (size_t)38 * WFL, dc4_b,
                                            conv4_w, conv4_b, (float*)d_out);
  }
}

// Round 8
// 2185.136 us; speedup vs baseline: 1.1529x; 1.0605x over previous
//
#include <hip/hip_runtime.h>
#include <cmath>

typedef unsigned short ushort_t;
typedef __attribute__((ext_vector_type(8))) short bf16x8;
typedef __attribute__((ext_vector_type(4))) float f32x4;

// Problem constants (B=2, C=64, H=W=256)
static constexpr int Bn   = 2;
static constexpr int Hn   = 256;
static constexpr int Wn   = 256;
static constexpr int HW   = Hn * Wn;          // 65536
static constexpr int CHW  = 64 * HW;          // 4194304
static constexpr int NCHW = Bn * CHW;         // 8388608
static constexpr int NPIX = Bn * HW;          // 131072
static constexpr float EPSv = 1e-5f;
static constexpr float INV_N = 1.0f / 131072.0f;   // BN count = B*H*W
static constexpr int NSLOT = 64;              // stats slot replication (anti-contention)
static constexpr int STSLOT = NSLOT * 128;    // floats per layer stats region
static constexpr int WFL = 73728;             // ushorts per weight-fragment layer slot

// bf16 round-to-nearest-even (no NaN inputs in this net)
__device__ inline uint32_t bf16_rne(float f) {
  uint32_t u = __float_as_uint(f);
  return (u + 0x7FFFu + ((u >> 16) & 1u)) >> 16;
}
__device__ inline void split_hl(float v, uint32_t& h, uint32_t& l) {
  h = bf16_rne(v);
  l = bf16_rne(v - __uint_as_float(h << 16)) & 0xFFFFu;
}
__device__ inline bf16x8 lds_ld16(const ushort_t* p) {   // 2x ds_read_b64
  union { bf16x8 v; uint2 u[2]; } r;
  r.u[0] = *(const uint2*)p;
  r.u[1] = *(const uint2*)(p + 4);
  return r.v;
}

// async global->LDS, 16B per lane: LDS dest = wave-uniform base + lane*16,
// global src is per-lane (carries the XOR swizzle + OOB zero-page redirect).
typedef __attribute__((address_space(1))) const void glb_void;
typedef __attribute__((address_space(3))) void lds_void;
__device__ inline void gld_lds16(const void* g, void* l) {
  __builtin_amdgcn_global_load_lds((glb_void*)g, (lds_void*)l, 16, 0, 0);
}

// ---------------------------------------------------------------------------
__global__ void transpose_w_kernel(const float* __restrict__ in, float* __restrict__ out,
                                   int NB, int OC, int IC, int K) {
  int total = NB * OC * IC * K;
  for (int i = blockIdx.x * blockDim.x + threadIdx.x; i < total; i += gridDim.x * blockDim.x) {
    int k  = i % K;
    int t  = i / K;
    int ic = t % IC; t /= IC;
    int oc = t % OC;
    int nb = t / OC;
    out[(((size_t)nb * IC + ic) * K + k) * OC + oc] = in[i];
  }
}

// ---------------------------------------------------------------------------
// Weight fragment prep: w[oc][ic][3][3] f32 -> MFMA B-frag order, bf16 hi/lo.
__global__ void prep_wfrag(const float* __restrict__ w, ushort_t* __restrict__ out,
                           int NGp, int ocreal, int wlstride, int olstride) {
  int layer = blockIdx.y;
  int elems = 9 * 2 * NGp * 64 * 8;
  int idx = blockIdx.x * 256 + threadIdx.x;
  if (idx >= elems) return;
  int j = idx & 7, lane = (idx >> 3) & 63;
  int rest = idx >> 9;
  int g = rest % NGp; rest /= NGp;
  int ih = rest & 1, tap = rest >> 1;
  int oc = g * 16 + (lane & 15);
  int ic = ih * 32 + (lane >> 4) * 8 + j;
  float v = 0.0f;
  if (oc < ocreal) v = w[(size_t)layer * wlstride + (oc * 64 + ic) * 9 + tap];
  uint32_t hi, lo;
  split_hl(v, hi, lo);
  out[(size_t)layer * olstride + idx] = (ushort_t)hi;
  out[(size_t)layer * olstride + elems + idx] = (ushort_t)lo;
}

// ---------------------------------------------------------------------------
__global__ void prep_kernel(const float* __restrict__ LowDEM, const float* __restrict__ Point_Ele,
                            const float* __restrict__ Slope, const float* __restrict__ Distance,
                            const float* __restrict__ Level, const float* __restrict__ w0,
                            const float* __restrict__ b0, float* __restrict__ x0) {
  int i = blockIdx.x * blockDim.x + threadIdx.x;
  if (i >= NPIX) return;
  float lv  = Level[i];
  float err = w0[0] * Slope[i] + w0[1] * Distance[i] + w0[2] * lv + b0[0];
  float lm  = (lv != 0.0f) ? 1.0f : 0.0f;
  x0[i] = LowDEM[i] * (1.0f - lm) + Point_Ele[i] + err * lm;
}

// ---------------------------------------------------------------------------
// conv9x9: when hiP != nullptr (fused path) writes X in HWC fp32 layout AND
// the bf16 hi/lo HWC planes; else planar NCHW (legacy).
__global__ __launch_bounds__(256, 2)
void conv9x9_kernel(const float* __restrict__ in, const float* __restrict__ wT,
                    const float* __restrict__ bias, float* __restrict__ out,
                    uint32_t* __restrict__ hiP, uint32_t* __restrict__ loP) {
  const int tx = threadIdx.x & 15, ty = threadIdx.x >> 4;
  const int w0 = blockIdx.x * 16, h0 = blockIdx.y * 16, b = blockIdx.z;
  __shared__ float lds[24 * 24];
  for (int idx = threadIdx.x; idx < 576; idx += 256) {
    int yy = idx / 24, xx = idx - yy * 24;
    int gy = h0 + yy - 4, gx = w0 + xx - 4;
    float v = 0.0f;
    if ((unsigned)gy < 256u && (unsigned)gx < 256u) v = in[b * HW + gy * 256 + gx];
    lds[idx] = v;
  }
  __syncthreads();
  float acc[64];
#pragma unroll
  for (int o = 0; o < 64; o++) acc[o] = 0.0f;
#pragma unroll 1
  for (int i = 0; i < 9; i++) {
#pragma unroll
    for (int j = 0; j < 9; j++) {
      float v = lds[(ty + i) * 24 + tx + j];
      const float* wp = wT + (i * 9 + j) * 64;   // uniform -> s_load
#pragma unroll
      for (int o = 0; o < 64; o++) acc[o] = fmaf(v, wp[o], acc[o]);
    }
  }
  const int p = (h0 + ty) * 256 + (w0 + tx);
  if (hiP) {
    float* op = out + ((size_t)b * HW + p) * 64;      // HWC fp32
#pragma unroll
    for (int o4 = 0; o4 < 16; o4++) {
      float4 v;
      v.x = acc[o4 * 4 + 0] + bias[o4 * 4 + 0];
      v.y = acc[o4 * 4 + 1] + bias[o4 * 4 + 1];
      v.z = acc[o4 * 4 + 2] + bias[o4 * 4 + 2];
      v.w = acc[o4 * 4 + 3] + bias[o4 * 4 + 3];
      *(float4*)(op + o4 * 4) = v;
    }
    uint32_t* hb = hiP + ((size_t)b * HW + p) * 32;
    uint32_t* lb = loP + ((size_t)b * HW + p) * 32;
#pragma unroll
    for (int o2 = 0; o2 < 32; o2++) {
      float v0 = acc[o2 * 2] + bias[o2 * 2];
      float v1 = acc[o2 * 2 + 1] + bias[o2 * 2 + 1];
      uint32_t h0v, l0v, h1v, l1v;
      split_hl(v0, h0v, l0v);
      split_hl(v1, h1v, l1v);
      hb[o2] = h0v | (h1v << 16);
      lb[o2] = l0v | (l1v << 16);
    }
  } else {
    float* op = out + (size_t)b * CHW + p;            // planar (legacy)
#pragma unroll
    for (int o = 0; o < 64; o++) op[o * HW] = acc[o] + bias[o];
  }
}

// ---------------------------------------------------------------------------
// OLD-STYLE MFMA conv3x3 (VALU-transform staging). Used for dc3/dc4 offset
// convs (INHWC) and the legacy (small-ws) path.
// MODE 0 plain / 1 relu(bn) / 2 bn+skip (WRITEY: materialize y). INHWC:
// pixel-major input.
// ---------------------------------------------------------------------------
template <int NG, int MODE, int STATS, int OCLIM, int HASBIAS, int WRITEY, int INHWC>
__global__ __launch_bounds__(256, 3)
void mfma_conv3(const float* __restrict__ in, const float* __restrict__ skip,
                const ushort_t* __restrict__ wf,
                const float* __restrict__ bias, const float* __restrict__ stats_in,
                const float* __restrict__ gg, const float* __restrict__ be,
                float* __restrict__ stats_out, float* __restrict__ yout,
                float* __restrict__ out) {
  const int tid  = threadIdx.x;
  const int lane = tid & 63, wid = tid >> 6;
  const int m = lane & 15, quad = lane >> 4;
  const int x0 = blockIdx.x * 16, y0 = blockIdx.y * 4, b = blockIdx.z;
  constexpr int WT = 2 * NG * 64 * 8;          // ushorts per tap per plane
  __shared__ __align__(16) ushort_t xh[108 * 68];   // hi plane, [spat][ch]
  __shared__ __align__(16) ushort_t xl[108 * 68];   // lo plane
  __shared__ float s_sc[MODE ? 64 : 1], s_sh[MODE ? 64 : 1];
  __shared__ float red[STATS ? 2 * 4 * 64 : 1];
  if (MODE) {
    if (tid < 64) {
      float sum = 0.0f, sq = 0.0f;
      for (int sl = 0; sl < NSLOT; sl++) {
        sum += stats_in[sl * 128 + tid];
        sq  += stats_in[sl * 128 + 64 + tid];
      }
      float mn = sum * INV_N, var = sq * INV_N - mn * mn;
      float s = gg[tid] * rsqrtf(var + EPSv);
      s_sc[tid] = s;
      s_sh[tid] = be[tid] - mn * s;
    }
    __syncthreads();
  }
  const float* inb = in + (size_t)b * CHW;
  const float* skb = MODE == 2 ? skip + (size_t)b * CHW : nullptr;
  float* ytb = WRITEY ? yout + (size_t)b * CHW : nullptr;
  uint32_t* xh32 = (uint32_t*)xh;              // row stride 34 dwords
  uint32_t* xl32 = (uint32_t*)xl;
#pragma unroll
  for (int t = 0; t < 14; t++) {
    int idx = t * 256 + tid;                   // 3456 = 108 spat * 32 ic-pairs
    if (idx < 3456) {
      int r, icp;
      if (INHWC) { icp = idx & 31; r = idx >> 5; }   // tid-contig ic -> coalesced HWC
      else       { r = idx % 108; icp = idx / 108; } // tid-contig px -> coalesced NCHW
      int row = r / 18, col = r - row * 18;
      int gy = y0 - 1 + row, gx = x0 - 1 + col;
      float v0 = 0.0f, v1 = 0.0f;
      if ((unsigned)gy < 256u && (unsigned)gx < 256u) {
        int ic = icp * 2;
        if (INHWC) {
          float2 vv = *(const float2*)&inb[(size_t)(gy * 256 + gx) * 64 + ic];
          v0 = vv.x; v1 = vv.y;
        } else {
          v0 = inb[ic * HW + gy * 256 + gx];
          v1 = inb[(ic + 1) * HW + gy * 256 + gx];
        }
        if (MODE == 1) {
          v0 = fmaxf(fmaf(v0, s_sc[ic], s_sh[ic]), 0.0f);
          v1 = fmaxf(fmaf(v1, s_sc[ic + 1], s_sh[ic + 1]), 0.0f);
        }
        if (MODE == 2) {
          v0 = fmaf(v0, s_sc[ic], s_sh[ic]) + skb[ic * HW + gy * 256 + gx];
          v1 = fmaf(v1, s_sc[ic + 1], s_sh[ic + 1]) + skb[(ic + 1) * HW + gy * 256 + gx];
          if (WRITEY && row >= 1 && row <= 4 && col >= 1 && col <= 16) {
            ytb[ic * HW + gy * 256 + gx] = v0;
            ytb[(ic + 1) * HW + gy * 256 + gx] = v1;
          }
        }
      }
      uint32_t h0, l0, h1, l1;
      split_hl(v0, h0, l0);
      split_hl(v1, h1, l1);
      xh32[r * 34 + icp] = h0 | (h1 << 16);
      xl32[r * 34 + icp] = l0 | (l1 << 16);
    }
  }
  __syncthreads();                             // the ONLY barrier before epilogue
  f32x4 acc[NG];
#pragma unroll
  for (int g = 0; g < NG; g++) acc[g] = (f32x4){0.0f, 0.0f, 0.0f, 0.0f};

  const bf16x8* wfh = (const bf16x8*)wf;                 // hi plane, frag-ordered
  const bf16x8* wfl = (const bf16x8*)(wf + 9 * WT);      // lo plane

#pragma unroll 1
  for (int tap = 0; tap < 9; tap++) {
    bf16x8 bh[2][NG], bl[2][NG];
#pragma unroll
    for (int ih = 0; ih < 2; ih++)
#pragma unroll
      for (int g = 0; g < NG; g++) {
        int fi = ((tap * 2 + ih) * NG + g) * 64 + lane;
        bh[ih][g] = wfh[fi];
        bl[ih][g] = wfl[fi];
      }
    const int dy = tap / 3 - 1, dx = tap % 3 - 1;
    const int spat = (wid + dy + 1) * 18 + (m + dx + 1);
#pragma unroll
    for (int ih = 0; ih < 2; ih++) {
      const int base = spat * 68 + ih * 32 + quad * 8;
      bf16x8 ah = lds_ld16(xh + base);
      bf16x8 al = lds_ld16(xl + base);
#pragma unroll
      for (int g = 0; g < NG; g++) {
        acc[g] = __builtin_amdgcn_mfma_f32_16x16x32_bf16(ah, bh[ih][g], acc[g], 0, 0, 0);
        acc[g] = __builtin_amdgcn_mfma_f32_16x16x32_bf16(al, bh[ih][g], acc[g], 0, 0, 0);
        acc[g] = __builtin_amdgcn_mfma_f32_16x16x32_bf16(ah, bl[ih][g], acc[g], 0, 0, 0);
      }
    }
  }
  // epilogue: D[row=quad*4+r][col=lane&15] -> pixel (y0+wid, x0+quad*4+r), oc=g*16+m
  const int py = y0 + wid;
  float* ob = out + (size_t)b * OCLIM * HW + py * 256 + x0 + quad * 4;
#pragma unroll
  for (int g = 0; g < NG; g++) {
    int oc = g * 16 + m;
    if (oc < OCLIM) {
      float bv = HASBIAS ? bias[oc] : 0.0f;
#pragma unroll
      for (int r = 0; r < 4; r++) ob[oc * HW + r] = acc[g][r] + bv;
    }
    if (STATS) {
      float s  = acc[g][0] + acc[g][1] + acc[g][2] + acc[g][3];
      float s2 = acc[g][0] * acc[g][0] + acc[g][1] * acc[g][1] +
                 acc[g][2] * acc[g][2] + acc[g][3] * acc[g][3];
      s  += __shfl_xor(s, 16, 64);  s  += __shfl_xor(s, 32, 64);
      s2 += __shfl_xor(s2, 16, 64); s2 += __shfl_xor(s2, 32, 64);
      if (lane < 16) {
        red[(0 * 4 + wid) * 64 + g * 16 + lane] = s;
        red[(1 * 4 + wid) * 64 + g * 16 + lane] = s2;
      }
    }
  }
  if (STATS) {
    __syncthreads();
    if (tid < 128) {
      int oc = tid & 63, which = tid >> 6;
      float tot = red[(which * 4 + 0) * 64 + oc] + red[(which * 4 + 1) * 64 + oc] +
                  red[(which * 4 + 2) * 64 + oc] + red[(which * 4 + 3) * 64 + oc];
      int slot = (blockIdx.y * 16 + blockIdx.x) & (NSLOT - 1);
      atomicAdd(&stats_out[slot * 128 + which * 64 + oc], tot);
    }
  }
}

// ---------------------------------------------------------------------------
// R22 chain conv: DMA staging + 16x8 tile, oc-group-per-wave work split.
// Every wave previously read ALL 4 oc-groups' B-frags (147 KB/wave -> 600 MB
// L2/dispatch). Now wave wid owns group wid for ALL 8 rows: B-traffic/wave
// 147 -> 36.8 KB (L2 600 -> 150 MB); A-frags come from shared LDS (4x more
// ds_reads, cheap); MFMA count/wave unchanged; per-output MFMA sequence
// bit-identical. Bonus: each wave holds complete block sums for its 16 oc ->
// no red buffer, no 2nd barrier.
// ---------------------------------------------------------------------------
__global__ __launch_bounds__(256, 3)
void mfma_conv3_dma(const ushort_t* __restrict__ hiP, const ushort_t* __restrict__ loP,
                    const ushort_t* __restrict__ wf, const float* __restrict__ zeroPg,
                    float* __restrict__ stats_out, float* __restrict__ out) {
  const int tid  = threadIdx.x;
  const int lane = tid & 63, wid = tid >> 6;
  const int m = lane & 15, quad = lane >> 4;
  const int x0 = blockIdx.x * 16, y0 = blockIdx.y * 8, b = blockIdx.z;
  // 180 spats (18 cols x 10 rows) * 8 chunks(16B) per plane; hi then lo.
  __shared__ __align__(16) ushort_t xs[2880 * 8];   // 46080 B
  const size_t bimg = (size_t)b * HW;
  for (int g = wid; g < 45; g += 4) {
    int q  = g * 64 + lane;                 // 0..2879
    int pl = q >= 1440;
    int r  = q - (pl ? 1440 : 0);
    int s  = r >> 3, jl = r & 7;
    int js = jl ^ (s & 7);
    int row = s / 18, col = s - row * 18;
    int gy = y0 - 1 + row, gx = x0 - 1 + col;
    const ushort_t* src = (const ushort_t*)zeroPg;
    if ((unsigned)gy < 256u && (unsigned)gx < 256u)
      src = (pl ? loP : hiP) + ((bimg + (size_t)(gy * 256 + gx)) << 6) + (js << 3);
    gld_lds16(src, (void*)&xs[(size_t)g * 512]);
  }
  __syncthreads();                           // compiler drains vmcnt here

  f32x4 acc[8];                              // 8 row-tiles, oc group = wid
#pragma unroll
  for (int t = 0; t < 8; t++) acc[t] = (f32x4){0.0f, 0.0f, 0.0f, 0.0f};
  const bf16x8* wfh = (const bf16x8*)wf;
  const bf16x8* wfl8 = (const bf16x8*)(wf + 9 * 4096);   // WT = 2*4*64*8 = 4096

#pragma unroll 1
  for (int tap = 0; tap < 9; tap++) {
    bf16x8 bh[2], bl[2];
#pragma unroll
    for (int ih = 0; ih < 2; ih++) {
      int fi = ((tap * 2 + ih) * 4 + wid) * 64 + lane;
      bh[ih] = wfh[fi];
      bl[ih] = wfl8[fi];
    }
    const int dy = tap / 3 - 1, dxx = tap % 3 - 1;
    const int scol = m + dxx + 1;
#pragma unroll
    for (int t = 0; t < 8; t++) {
      const int s  = (t + dy + 1) * 18 + scol;
      const int s7 = s & 7;
#pragma unroll
      for (int ih = 0; ih < 2; ih++) {
        const int ch = s * 8 + ((ih * 4 + quad) ^ s7);   // swizzled chunk
        bf16x8 ah = *(const bf16x8*)&xs[ch * 8];
        bf16x8 al = *(const bf16x8*)&xs[ch * 8 + 11520]; // lo plane (+1440 chunks)
        acc[t] = __builtin_amdgcn_mfma_f32_16x16x32_bf16(ah, bh[ih], acc[t], 0, 0, 0);
        acc[t] = __builtin_amdgcn_mfma_f32_16x16x32_bf16(al, bh[ih], acc[t], 0, 0, 0);
        acc[t] = __builtin_amdgcn_mfma_f32_16x16x32_bf16(ah, bl[ih], acc[t], 0, 0, 0);
      }
    }
  }
  // HWC epilogue: row y0+t, pixel col x0+quad*4+r, oc = wid*16+m
  const int oc = wid * 16 + m;
  float s = 0.0f, s2 = 0.0f;
#pragma unroll
  for (int t = 0; t < 8; t++) {
    const int py = y0 + t;
    float* ob = out + ((size_t)b * HW + (size_t)py * 256 + x0) * 64;
#pragma unroll
    for (int r = 0; r < 4; r++) {
      float v = acc[t][r];
      ob[(quad * 4 + r) * 64 + oc] = v;
      s += v;
      s2 += v * v;
    }
  }
  // quad lanes share oc -> reduce over quad; wave covers all 128 px.
  s  += __shfl_xor(s, 16, 64);  s  += __shfl_xor(s, 32, 64);
  s2 += __shfl_xor(s2, 16, 64); s2 += __shfl_xor(s2, 32, 64);
  if (lane < 16) {
    int slot = (blockIdx.y * 16 + blockIdx.x) & (NSLOT - 1);
    atomicAdd(&stats_out[slot * 128 + oc], s);
    atomicAdd(&stats_out[slot * 128 + 64 + oc], s2);
  }
}

// ---------------------------------------------------------------------------
// R20 offset conv (dc2): DMA staging from bf16 hi/lo planes (16x8, same
// geometry as chain conv), NG=2, planar-27 epilogue with bias.
// ---------------------------------------------------------------------------
__global__ __launch_bounds__(256, 3)
void ofs_conv_dma(const ushort_t* __restrict__ hiP, const ushort_t* __restrict__ loP,
                  const ushort_t* __restrict__ wf, const float* __restrict__ zeroPg,
                  const float* __restrict__ bias, float* __restrict__ out) {
  const int tid  = threadIdx.x;
  const int lane = tid & 63, wid = tid >> 6;
  const int m = lane & 15, quad = lane >> 4;
  const int x0 = blockIdx.x * 16, y0 = blockIdx.y * 8, b = blockIdx.z;
  __shared__ __align__(16) ushort_t xs[2880 * 8];   // 46080 B
  const size_t bimg = (size_t)b * HW;
  for (int g = wid; g < 45; g += 4) {
    int q  = g * 64 + lane;
    int pl = q >= 1440;
    int r  = q - (pl ? 1440 : 0);
    int s  = r >> 3, jl = r & 7;
    int js = jl ^ (s & 7);
    int row = s / 18, col = s - row * 18;
    int gy = y0 - 1 + row, gx = x0 - 1 + col;
    const ushort_t* src = (const ushort_t*)zeroPg;
    if ((unsigned)gy < 256u && (unsigned)gx < 256u)
      src = (pl ? loP : hiP) + ((bimg + (size_t)(gy * 256 + gx)) << 6) + (js << 3);
    gld_lds16(src, (void*)&xs[(size_t)g * 512]);
  }
  __syncthreads();

  f32x4 acc[2][2];
#pragma unroll
  for (int t = 0; t < 2; t++)
#pragma unroll
    for (int g = 0; g < 2; g++) acc[t][g] = (f32x4){0.0f, 0.0f, 0.0f, 0.0f};
  const bf16x8* wfh = (const bf16x8*)wf;
  const bf16x8* wfl8 = (const bf16x8*)(wf + 9 * 2048);   // WT = 2*2*64*8 = 2048

#pragma unroll 1
  for (int tap = 0; tap < 9; tap++) {
    bf16x8 bh[2][2], bl[2][2];
#pragma unroll
    for (int ih = 0; ih < 2; ih++)
#pragma unroll
      for (int g = 0; g < 2; g++) {
        int fi = ((tap * 2 + ih) * 2 + g) * 64 + lane;
        bh[ih][g] = wfh[fi];
        bl[ih][g] = wfl8[fi];
      }
    const int dy = tap / 3 - 1, dxx = tap % 3 - 1;
    const int scol = m + dxx + 1;
#pragma unroll
    for (int t = 0; t < 2; t++) {
      const int s  = (wid * 2 + t + dy + 1) * 18 + scol;
      const int s7 = s & 7;
#pragma unroll
      for (int ih = 0; ih < 2; ih++) {
        const int ch = s * 8 + ((ih * 4 + quad) ^ s7);
        bf16x8 ah = *(const bf16x8*)&xs[ch * 8];
        bf16x8 al = *(const bf16x8*)&xs[ch * 8 + 11520];
#pragma unroll
        for (int g = 0; g < 2; g++) {
          acc[t][g] = __builtin_amdgcn_mfma_f32_16x16x32_bf16(ah, bh[ih][g], acc[t][g], 0, 0, 0);
          acc[t][g] = __builtin_amdgcn_mfma_f32_16x16x32_bf16(al, bh[ih][g], acc[t][g], 0, 0, 0);
          acc[t][g] = __builtin_amdgcn_mfma_f32_16x16x32_bf16(ah, bl[ih][g], acc[t][g], 0, 0, 0);
        }
      }
    }
  }
  // planar epilogue (om layout [B][27][HW] kept for dcn's coalesced om reads)
#pragma unroll
  for (int g = 0; g < 2; g++) {
    int oc = g * 16 + m;
    if (oc < 27) {
      float bv = bias[oc];
#pragma unroll
      for (int t = 0; t < 2; t++) {
        const int py = y0 + wid * 2 + t;
        float* ob = out + (size_t)b * 27 * HW + (size_t)oc * HW + py * 256 + x0 + quad * 4;
#pragma unroll
        for (int r = 0; r < 4; r++) ob[r] = acc[t][g][r] + bv;
      }
    }
  }
}

// ---------------------------------------------------------------------------
// R17 transform: all-HWC streaming. Finalize BN of raw conv out t (HWC) and
// materialize bf16 hi/lo HWC planes. TMODE 1: relu(bn(t)) -> planes only.
// TMODE 2: y = bn(t)+skip -> y fp32 HWC + planes. Parallel stats preamble.
// ---------------------------------------------------------------------------
template <int TMODE>
__global__ __launch_bounds__(256, 8)
void bn_split_hwc(const float* __restrict__ t, const float* __restrict__ stats,
                  const float* __restrict__ g, const float* __restrict__ be,
                  const float* __restrict__ skip, float* __restrict__ yout,
                  uint32_t* __restrict__ hiP, uint32_t* __restrict__ loP) {
  __shared__ float part[2][4][64];
  __shared__ float s_sc[64], s_sh[64];
  const int tid = threadIdx.x;
  {
    int c = tid & 63, q = tid >> 6;
    float sum = 0.0f, sq = 0.0f;
    for (int sl = q * 16; sl < q * 16 + 16; sl++) {
      sum += stats[sl * 128 + c];
      sq  += stats[sl * 128 + 64 + c];
    }
    part[0][q][c] = sum;
    part[1][q][c] = sq;
  }
  __syncthreads();
  if (tid < 64) {
    int c = tid;
    float sum = part[0][0][c] + part[0][1][c] + part[0][2][c] + part[0][3][c];
    float sq  = part[1][0][c] + part[1][1][c] + part[1][2][c] + part[1][3][c];
    float mn  = sum * INV_N;
    float var = sq * INV_N - mn * mn;
    float s   = g[c] * rsqrtf(var + EPSv);
    s_sc[c] = s;
    s_sh[c] = be[c] - mn * s;
  }
  __syncthreads();
  const int blk = blockIdx.x;            // 2048 = NPIX/64
  const int b  = blk >> 10;
  const int p0 = (blk & 1023) * 64;
  const size_t base = ((size_t)b * HW + p0) * 64;   // floats (HWC)
  uint32_t* hb = hiP + ((size_t)b * HW + p0) * 32;
  uint32_t* lb = loP + ((size_t)b * HW + p0) * 32;
#pragma unroll
  for (int i = 0; i < 8; i++) {
    int idx = i * 256 + tid;             // 0..2047 = 64 px * 32 ch-pairs
    int p = idx >> 5, c2 = idx & 31;
    size_t off = base + (size_t)p * 64 + c2 * 2;
    float2 v = *(const float2*)&t[off];
    float v0 = fmaf(v.x, s_sc[c2 * 2],     s_sh[c2 * 2]);
    float v1 = fmaf(v.y, s_sc[c2 * 2 + 1], s_sh[c2 * 2 + 1]);
    if (TMODE == 1) {
      v0 = fmaxf(v0, 0.0f);
      v1 = fmaxf(v1, 0.0f);
    } else {
      float2 k = *(const float2*)&skip[off];
      v0 += k.x; v1 += k.y;
      float2 y2; y2.x = v0; y2.y = v1;
      *(float2*)&yout[off] = y2;
    }
    uint32_t h0v, l0v, h1v, l1v;
    split_hl(v0, h0v, l0v);
    split_hl(v1, h1v, l1v);
    hb[p * 32 + c2] = h0v | (h1v << 16);
    lb[p * 32 + c2] = l0v | (l1v << 16);
  }
}

// ---------------------------------------------------------------------------
// R20: x = bn(t)+skip, all-HWC streaming; also emits x's bf16 hi/lo planes
// (feeds the DMA offset conv for dc2).
// ---------------------------------------------------------------------------
__global__ __launch_bounds__(256, 8)
void bn_add_hwc(const float* __restrict__ t, const float* __restrict__ stats,
                const float* __restrict__ g, const float* __restrict__ be,
                const float* __restrict__ skip, float* __restrict__ xout,
                uint32_t* __restrict__ hiP, uint32_t* __restrict__ loP) {
  __shared__ float part[2][4][64];
  __shared__ float s_sc[64], s_sh[64];
  const int tid = threadIdx.x;
  {
    int c = tid & 63, q = tid >> 6;
    float sum = 0.0f, sq = 0.0f;
    for (int sl = q * 16; sl < q * 16 + 16; sl++) {
      sum += stats[sl * 128 + c];
      sq  += stats[sl * 128 + 64 + c];
    }
    part[0][q][c] = sum;
    part[1][q][c] = sq;
  }
  __syncthreads();
  if (tid < 64) {
    int c = tid;
    float sum = part[0][0][c] + part[0][1][c] + part[0][2][c] + part[0][3][c];
    float sq  = part[1][0][c] + part[1][1][c] + part[1][2][c] + part[1][3][c];
    float mn  = sum * INV_N;
    float var = sq * INV_N - mn * mn;
    float s   = g[c] * rsqrtf(var + EPSv);
    s_sc[c] = s;
    s_sh[c] = be[c] - mn * s;
  }
  __syncthreads();
  const int blk = blockIdx.x;            // 2048
  const int b  = blk >> 10;
  const int p0 = (blk & 1023) * 64;
  const size_t base4 = (((size_t)b * HW + p0) * 64) >> 2;   // float4 units
  const float4* t4 = (const float4*)t;
  const float4* k4 = (const float4*)skip;
  float4* x4 = (float4*)xout;
  uint32_t* hb = hiP + ((size_t)b * HW + p0) * 32;
  uint32_t* lb = loP + ((size_t)b * HW + p0) * 32;
#pragma unroll
  for (int i = 0; i < 4; i++) {
    int idx = i * 256 + tid;             // 0..1023 = 64 px * 16 ch-quads
    int c = (idx & 15) * 4;
    int p = idx >> 4;
    float4 v = t4[base4 + idx], k = k4[base4 + idx], r;
    r.x = fmaf(v.x, s_sc[c],     s_sh[c])     + k.x;
    r.y = fmaf(v.y, s_sc[c + 1], s_sh[c + 1]) + k.y;
    r.z = fmaf(v.z, s_sc[c + 2], s_sh[c + 2]) + k.z;
    r.w = fmaf(v.w, s_sc[c + 3], s_sh[c + 3]) + k.w;
    x4[base4 + idx] = r;
    uint32_t h0v, l0v, h1v, l1v, h2v, l2v, h3v, l3v;
    split_hl(r.x, h0v, l0v); split_hl(r.y, h1v, l1v);
    split_hl(r.z, h2v, l2v); split_hl(r.w, h3v, l3v);
    uint2 hv = make_uint2(h0v | (h1v << 16), h2v | (h3v << 16));
    uint2 lv = make_uint2(l0v | (l1v << 16), l2v | (l3v << 16));
    *(uint2*)&hb[p * 32 + (c >> 1)] = hv;
    *(uint2*)&lb[p * 32 + (c >> 1)] = lv;
  }
}

// ---------------------------------------------------------------------------
// Legacy path only: y = BN(t)*g+be + skip (float4).
// ---------------------------------------------------------------------------
__global__ void bn_apply_add_kernel(const float* __restrict__ t, const float* __restrict__ stats,
                                    const float* __restrict__ g, const float* __restrict__ be,
                                    const float* __restrict__ skip, float* __restrict__ out) {
  __shared__ float s_sc[64], s_sh[64];
  if (threadIdx.x < 64) {
    int c = threadIdx.x;
    float sum = 0.0f, sq = 0.0f;
    for (int sl = 0; sl < NSLOT; sl++) {
      sum += stats[sl * 128 + c];
      sq  += stats[sl * 128 + 64 + c];
    }
    float m   = sum * INV_N;
    float var = sq * INV_N - m * m;
    float s   = g[c] * rsqrtf(var + EPSv);
    s_sc[c] = s;
    s_sh[c] = be[c] - m * s;
  }
  __syncthreads();
  const float4* t4 = (const float4*)t;
  const float4* k4 = (const float4*)skip;
  float4* o4 = (float4*)out;
  const int n4 = NCHW / 4;
  for (int i = blockIdx.x * blockDim.x + threadIdx.x; i < n4; i += gridDim.x * blockDim.x) {
    int c = (i >> 14) & 63;
    float s = s_sc[c], h = s_sh[c];
    float4 v = t4[i], kk = k4[i], r;
    r.x = fmaf(v.x, s, h) + kk.x;
    r.y = fmaf(v.y, s, h) + kk.y;
    r.z = fmaf(v.z, s, h) + kk.z;
    r.w = fmaf(v.w, s, h) + kk.w;
    o4[i] = r;
  }
}

// ---------------------------------------------------------------------------
// Legacy path only: fused x = bn(t)+skip -> planar out AND HWC mirror.
// ---------------------------------------------------------------------------
__global__ __launch_bounds__(256, 4)
void bn_tx_kernel(const float* __restrict__ t, const float* __restrict__ stats,
                  const float* __restrict__ g, const float* __restrict__ be,
                  const float* __restrict__ skip, float* __restrict__ outP,
                  float* __restrict__ outHWC) {
  __shared__ float tile[64][65];
  __shared__ float s_sc[64], s_sh[64];
  if (threadIdx.x < 64) {
    int c = threadIdx.x;
    float sum = 0.0f, sq = 0.0f;
    for (int sl = 0; sl < NSLOT; sl++) {
      sum += stats[sl * 128 + c];
      sq  += stats[sl * 128 + 64 + c];
    }
    float m   = sum * INV_N;
    float var = sq * INV_N - m * m;
    float s   = g[c] * rsqrtf(var + EPSv);
    s_sc[c] = s;
    s_sh[c] = be[c] - m * s;
  }
  __syncthreads();
  const int blk = blockIdx.x;            // 2048 = NPIX/64
  const int b = blk >> 10;
  const int p0 = (blk & 1023) * 64;
  const float* tb = t + (size_t)b * CHW;
  const float* kb = skip + (size_t)b * CHW;
  float* oP = outP + (size_t)b * CHW;
  float* oH = outHWC + (size_t)b * CHW;
#pragma unroll
  for (int i = 0; i < 16; i++) {
    int idx = i * 256 + threadIdx.x;
    int c = idx >> 6, p = idx & 63;
    float v = fmaf(tb[c * HW + p0 + p], s_sc[c], s_sh[c]) + kb[c * HW + p0 + p];
    oP[c * HW + p0 + p] = v;
    tile[c][p] = v;
  }
  __syncthreads();
#pragma unroll
  for (int i = 0; i < 16; i++) {
    int idx = i * 256 + threadIdx.x;
    int p = idx >> 6, c = idx & 63;
    oH[(size_t)(p0 + p) * 64 + c] = tile[c][p];
  }
}

// ---------------------------------------------------------------------------
// Deformable conv on MFMA, HWC input. R21 (measured 90us, WIN): R18 schedule
// (double-buffered LDS, gather(tap+1) before MFMAs, 1 barrier/tap) with
// quad-per-pixel gather (gp = tid>>2, c4 = tid&3): 4 lanes of a pixel read
// contiguous 64B per corner -> 4x fewer L1 transactions; LDS write conflicts
// 16 -> 4-way (3.54M -> 1.18M). R16 reg-only REGRESSED; R19 cross-iteration
// pipeline FAILED correctness. FINAL: fuse dc4 bias + conv4.
// ---------------------------------------------------------------------------
template <int NG, int FINAL>
__global__ __launch_bounds__(256, 4)
void dcn_mfma(const float* __restrict__ xhwc, const float* __restrict__ om,
              const ushort_t* __restrict__ wf, const float* __restrict__ bias,
              const float* __restrict__ c4w, const float* __restrict__ c4b,
              float* __restrict__ out) {
  const int tid  = threadIdx.x;
  const int lane = tid & 63, wid = tid >> 6;
  const int m = lane & 15, quad = lane >> 4;
  const int x0 = blockIdx.x * 16, y0 = blockIdx.y * 4, b = blockIdx.z;
  constexpr int WT = 2 * NG * 64 * 8;
  __shared__ __align__(16) ushort_t sh[2][64 * 64];   // hi plane per buffer, 8 KB
  __shared__ __align__(16) ushort_t sl[2][64 * 64];   // lo plane
  const int gp = tid >> 2, c4 = tid & 3;       // gather role: pixel, 16B-chunk lane
  const int gpy = y0 + (gp >> 4), gxx = x0 + (gp & 15);
  const int psw = gp & 3;                      // pixel swizzle bits
  const float* xb  = xhwc + (size_t)b * CHW;
  const float* omb = om + (size_t)b * 27 * HW + gpy * 256 + gxx;

  auto gather = [&](int tap, int buf) {
    float dyv = omb[tap * HW];
    float dxv = omb[(9 + tap) * HW];
    float mo  = omb[(18 + tap) * HW];
    float mk  = 1.0f / (1.0f + __expf(-mo));
    float ys = fminf(fmaxf((float)(gpy + tap / 3 - 1) + dyv, -2.0f), 258.0f);
    float xs = fminf(fmaxf((float)(gxx + tap % 3 - 1) + dxv, -2.0f), 258.0f);
    float y0f = floorf(ys), x0f = floorf(xs);
    float wy = ys - y0f, wx = xs - x0f;
    int yi = (int)y0f, xi = (int)x0f;
    float vy0 = ((unsigned)yi       < 256u) ? 1.0f : 0.0f;
    float vy1 = ((unsigned)(yi + 1) < 256u) ? 1.0f : 0.0f;
    float vx0 = ((unsigned)xi       < 256u) ? 1.0f : 0.0f;
    float vx1 = ((unsigned)(xi + 1) < 256u) ? 1.0f : 0.0f;
    int cy0 = min(max(yi, 0), 255), cy1 = min(max(yi + 1, 0), 255);
    int cx0 = min(max(xi, 0), 255), cx1 = min(max(xi + 1, 0), 255);
    float W00 = (1.0f - wy) * (1.0f - wx) * mk * vy0 * vx0;
    float W01 = (1.0f - wy) * wx * mk * vy0 * vx1;
    float W10 = wy * (1.0f - wx) * mk * vy1 * vx0;
    float W11 = wy * wx * mk * vy1 * vx1;
    const float* p00 = xb + (size_t)(cy0 * 256 + cx0) * 64;
    const float* p01 = xb + (size_t)(cy0 * 256 + cx1) * 64;
    const float* p10 = xb + (size_t)(cy1 * 256 + cx0) * 64;
    const float* p11 = xb + (size_t)(cy1 * 256 + cx1) * 64;
#pragma unroll
    for (int j = 0; j < 4; j++) {
      const int k = c4 + 4 * j;                // 4-ch chunk index 0..15
      float4 a  = *(const float4*)(p00 + k * 4);
      float4 b2 = *(const float4*)(p01 + k * 4);
      float4 c2 = *(const float4*)(p10 + k * 4);
      float4 d2 = *(const float4*)(p11 + k * 4);
      float s0 = W00 * a.x + W01 * b2.x + W10 * c2.x + W11 * d2.x;
      float s1 = W00 * a.y + W01 * b2.y + W10 * c2.y + W11 * d2.y;
      float s2 = W00 * a.z + W01 * b2.z + W10 * c2.z + W11 * d2.z;
      float s3 = W00 * a.w + W01 * b2.w + W10 * c2.w + W11 * d2.w;
      uint32_t h0, l0, h1, l1, h2, l2, h3, l3;
      split_hl(s0, h0, l0); split_hl(s1, h1, l1);
      split_hl(s2, h2, l2); split_hl(s3, h3, l3);
      // chunk k lives at group (k>>2)=j, sub (k&3)=c4 -> same layout as before
      int wi = gp * 64 + ((j ^ psw) * 16) + c4 * 4;   // 8B-aligned
      *(uint2*)&sh[buf][wi] = make_uint2(h0 | (h1 << 16), h2 | (h3 << 16));
      *(uint2*)&sl[buf][wi] = make_uint2(l0 | (l1 << 16), l2 | (l3 << 16));
    }
  };

  f32x4 acc[NG];
#pragma unroll
  for (int g = 0; g < NG; g++) acc[g] = (f32x4){0.0f, 0.0f, 0.0f, 0.0f};
  const bf16x8* wfh = (const bf16x8*)wf;
  const bf16x8* wfl = (const bf16x8*)(wf + 9 * WT);
  const int px = wid * 16 + m;                 // this lane's A-row pixel

  gather(0, 0);
  __syncthreads();
#pragma unroll 1
  for (int tap = 0; tap < 9; tap++) {
    const int cur = tap & 1;
    if (tap < 8) gather(tap + 1, cur ^ 1);     // overlaps MFMAs below
#pragma unroll
    for (int ih = 0; ih < 2; ih++) {
      const int c = ih * 2 + (quad >> 1), h = quad & 1;
      const int ri = px * 64 + ((c ^ (px & 3)) * 16) + h * 8;   // 16B-aligned
      bf16x8 ah = *(const bf16x8*)&sh[cur][ri];
      bf16x8 al = *(const bf16x8*)&sl[cur][ri];
#pragma unroll
      for (int g = 0; g < NG; g++) {
        int fi = ((tap * 2 + ih) * NG + g) * 64 + lane;
        bf16x8 bh = wfh[fi], bl = wfl[fi];
        acc[g] = __builtin_amdgcn_mfma_f32_16x16x32_bf16(ah, bh, acc[g], 0, 0, 0);
        acc[g] = __builtin_amdgcn_mfma_f32_16x16x32_bf16(al, bh, acc[g], 0, 0, 0);
        acc[g] = __builtin_amdgcn_mfma_f32_16x16x32_bf16(ah, bl, acc[g], 0, 0, 0);
      }
    }
    __syncthreads();   // writes to buf^1 and reads of cur both done
  }
  const int py = y0 + wid;
  if (FINAL) {
    if (m == 0) {
      float* op = out + (size_t)b * HW + py * 256 + x0 + quad * 4;
#pragma unroll
      for (int r = 0; r < 4; r++) op[r] = c4w[0] * (acc[0][r] + bias[0]) + c4b[0];
    }
  } else {
    float* ob = out + (size_t)b * CHW + ((size_t)py * 256 + x0 + quad * 4) * 64 + m;
#pragma unroll
    for (int g = 0; g < NG; g++)
#pragma unroll
      for (int r = 0; r < 4; r++)
        ob[r * 64 + g * 16] = fmaxf(acc[g][r] + bias[g * 16 + m], 0.0f);
  }
}

// ---------------------------------------------------------------------------
extern "C" void kernel_launch(void* const* d_in, const int* in_sizes, int n_in,
                              void* d_out, int out_size, void* d_ws, size_t ws_size,
                              hipStream_t stream) {
  const float* LowDEM    = (const float*)d_in[0];
  const float* Point_Ele = (const float*)d_in[1];
  const float* Slope     = (const float*)d_in[2];
  const float* Distance  = (const float*)d_in[3];
  const float* Level     = (const float*)d_in[4];
  const float* conv0_w   = (const float*)d_in[5];
  const float* conv0_b   = (const float*)d_in[6];
  const float* conv1_w   = (const float*)d_in[7];
  const float* conv1_b   = (const float*)d_in[8];
  const float* rb_w1     = (const float*)d_in[9];
  const float* rb_g1     = (const float*)d_in[11];
  const float* rb_be1    = (const float*)d_in[12];
  const float* rb_w2     = (const float*)d_in[13];
  const float* rb_g2     = (const float*)d_in[15];
  const float* rb_be2    = (const float*)d_in[16];
  const float* conv2_w   = (const float*)d_in[17];
  const float* bn2_g     = (const float*)d_in[19];
  const float* bn2_be    = (const float*)d_in[20];
  const float* dc2_w     = (const float*)d_in[21];
  const float* dc2_b     = (const float*)d_in[22];
  const float* dc2_ow    = (const float*)d_in[23];
  const float* dc2_ob    = (const float*)d_in[24];
  const float* dc3_w     = (const float*)d_in[25];
  const float* dc3_b     = (const float*)d_in[26];
  const float* dc3_ow    = (const float*)d_in[27];
  const float* dc3_ob    = (const float*)d_in[28];
  const float* dc4_w     = (const float*)d_in[29];
  const float* dc4_b     = (const float*)d_in[30];
  const float* dc4_ow    = (const float*)d_in[31];
  const float* dc4_ob    = (const float*)d_in[32];
  const float* conv4_w   = (const float*)d_in[33];
  const float* conv4_b   = (const float*)d_in[34];

  // small region first, then big buffers
  float* x0   = (float*)d_ws;             // 131072
  float* T1   = x0 + NPIX;                // 5184
  ushort_t* WF = (ushort_t*)(T1 + 5184);  // 39 * WFL ushorts
  float* stats = (float*)(WF + 39 * WFL); // 33 * STSLOT floats
  float* zpg   = stats + 33 * STSLOT;     // 32 floats: DMA zero page
  float* big   = zpg + 32;
  size_t used_small = (size_t)((char*)big - (char*)d_ws);
  bool fused = ws_size >= used_small + 5ull * NCHW * sizeof(float);

  float* bufX = big;                      // X (conv9x9 out; skip for bn2)
  float* bufT = bufX + NCHW;              // raw conv out / offset-conv out
  float* R3   = bufT + NCHW;              // fused: yA   | legacy: bufT2
  float* R4   = R3 + NCHW;                // fused: yB   | legacy: yA(=yB)
  ushort_t* hiP = (ushort_t*)(R4 + NCHW); // fused only: bf16 hi plane (HWC)
  ushort_t* loP = hiP + NCHW;             //             bf16 lo plane (HWC)

  hipMemsetAsync(stats, 0, 33 * STSLOT * sizeof(float), stream);
  hipMemsetAsync(zpg, 0, 128, stream);

  transpose_w_kernel<<<32, 256, 0, stream>>>(conv1_w, T1, 1, 64, 1, 81);

  prep_wfrag<<<dim3(144, 16), 256, 0, stream>>>(rb_w1,   WF,            4, 64, 36864, WFL);
  prep_wfrag<<<dim3(144, 16), 256, 0, stream>>>(rb_w2,   WF + 16 * WFL, 4, 64, 36864, WFL);
  prep_wfrag<<<dim3(144, 1),  256, 0, stream>>>(conv2_w, WF + 32 * WFL, 4, 64, 36864, WFL);
  prep_wfrag<<<dim3(72, 1),   256, 0, stream>>>(dc2_ow,  WF + 33 * WFL, 2, 27, 15552, WFL);
  prep_wfrag<<<dim3(72, 1),   256, 0, stream>>>(dc3_ow,  WF + 34 * WFL, 2, 27, 15552, WFL);
  prep_wfrag<<<dim3(72, 1),   256, 0, stream>>>(dc4_ow,  WF + 35 * WFL, 2, 27, 15552, WFL);
  prep_wfrag<<<dim3(144, 1),  256, 0, stream>>>(dc2_w,   WF + 36 * WFL, 4, 64, 36864, WFL);
  prep_wfrag<<<dim3(144, 1),  256, 0, stream>>>(dc3_w,   WF + 37 * WFL, 4, 64, 36864, WFL);
  prep_wfrag<<<dim3(36, 1),   256, 0, stream>>>(dc4_w,   WF + 38 * WFL, 1, 1, 576, WFL);

  prep_kernel<<<(NPIX + 255) / 256, 256, 0, stream>>>(LowDEM, Point_Ele, Slope, Distance,
                                                      Level, conv0_w, conv0_b, x0);

  dim3 grid16(16, 16, 2);   // conv9x9
  dim3 gmf(16, 64, 2);      // dcn_mfma / legacy conv (16x4 pixel tiles)
  dim3 gmf8(16, 32, 2);     // chain conv / ofs conv (16x8 pixel tiles)

  conv9x9_kernel<<<grid16, 256, 0, stream>>>(x0, T1, conv1_b, bufX,
                                             fused ? (uint32_t*)hiP : nullptr,
                                             fused ? (uint32_t*)loP : nullptr);

  if (fused) {
    float* yA = R3;
    float* yB = R4;
    // R22: all-HWC chain — oc-group-per-wave DMA convs + streaming bn/split.
    for (int i = 0; i < 16; i++) {
      mfma_conv3_dma<<<gmf8, 256, 0, stream>>>(hiP, loP, WF + (size_t)i * WFL, zpg,
                                               stats + (size_t)(2 * i) * STSLOT, bufT);
      bn_split_hwc<1><<<2048, 256, 0, stream>>>(
          bufT, stats + (size_t)(2 * i) * STSLOT, rb_g1 + i * 64, rb_be1 + i * 64,
          nullptr, nullptr, (uint32_t*)hiP, (uint32_t*)loP);
      mfma_conv3_dma<<<gmf8, 256, 0, stream>>>(hiP, loP, WF + (size_t)(16 + i) * WFL, zpg,
                                               stats + (size_t)(2 * i + 1) * STSLOT, bufT);
      const float* skp = (i == 0) ? bufX : ((i & 1) ? yA : yB);   // y_i
      float* yo = (i & 1) ? yB : yA;                              // y_{i+1}
      bn_split_hwc<2><<<2048, 256, 0, stream>>>(
          bufT, stats + (size_t)(2 * i + 1) * STSLOT, rb_g2 + i * 64, rb_be2 + i * 64,
          skp, yo, (uint32_t*)hiP, (uint32_t*)loP);
    }
    mfma_conv3_dma<<<gmf8, 256, 0, stream>>>(hiP, loP, WF + (size_t)32 * WFL, zpg,
                                             stats + (size_t)32 * STSLOT, bufT);

    float* xT    = R4;          // y16 fp32 dead (its planes fed conv2)
    float* d2out = R3;          // yA dead after i=15
    float* d3out = (float*)hiP; // plane region dead after ofs dc2 below
    // x = bn(conv2_out) + X -> xT (HWC) + x planes (for dc2's offset conv)
    bn_add_hwc<<<2048, 256, 0, stream>>>(bufT, stats + 32 * STSLOT, bn2_g, bn2_be,
                                         bufX, xT, (uint32_t*)hiP, (uint32_t*)loP);
    // dc2: DMA offset conv from x planes
    ofs_conv_dma<<<gmf8, 256, 0, stream>>>(hiP, loP, WF + (size_t)33 * WFL, zpg,
                                           dc2_ob, bufT);
    dcn_mfma<4, 0><<<gmf, 256, 0, stream>>>(xT, bufT, WF + (size_t)36 * WFL, dc2_b,
                                            nullptr, nullptr, d2out);
    // dc3: VALU-staged offset conv from d2out fp32 HWC (proven path)
    mfma_conv3<2, 0, 0, 27, 1, 0, 1><<<gmf, 256, 0, stream>>>(
        d2out, nullptr, WF + (size_t)34 * WFL, dc3_ob, nullptr, nullptr, nullptr,
        nullptr, nullptr, bufT);
    dcn_mfma<4, 0><<<gmf, 256, 0, stream>>>(d2out, bufT, WF + (size_t)37 * WFL, dc3_b,
                                            nullptr, nullptr, d3out);
    // dc4 + conv4 -> d_out
    mfma_conv3<2, 0, 0, 27, 1, 0, 1><<<gmf, 256, 0, stream>>>(
        d3out, nullptr, WF + (size_t)35 * WFL, dc4_ob, nullptr, nullptr, nullptr,
        nullptr, nullptr, bufT);
    dcn_mfma<1, 1><<<gmf, 256, 0, stream>>>(d3out, bufT, WF + (size_t)38 * WFL, dc4_b,
                                            conv4_w, conv4_b, (float*)d_out);
  } else {
    float* bufT2 = R3;
    float* bufY  = R4;
    for (int i = 0; i < 16; i++) {
      const float* src = (i == 0) ? bufX : bufY;
      mfma_conv3<4, 0, 1, 64, 0, 0, 0><<<gmf, 256, 0, stream>>>(
          src, nullptr, WF + (size_t)i * WFL, nullptr, nullptr, nullptr, nullptr,
          stats + (2 * i) * STSLOT, nullptr, bufT);
      mfma_conv3<4, 1, 1, 64, 0, 0, 0><<<gmf, 256, 0, stream>>>(
          bufT, nullptr, WF + (size_t)(16 + i) * WFL, nullptr, stats + (2 * i) * STSLOT,
          rb_g1 + i * 64, rb_be1 + i * 64, stats + (2 * i + 1) * STSLOT, nullptr, bufT2);
      bn_apply_add_kernel<<<2048, 256, 0, stream>>>(bufT2, stats + (2 * i + 1) * STSLOT,
                                                    rb_g2 + i * 64, rb_be2 + i * 64, src, bufY);
    }
    mfma_conv3<4, 0, 1, 64, 0, 0, 0><<<gmf, 256, 0, stream>>>(
        bufY, nullptr, WF + (size_t)32 * WFL, nullptr, nullptr, nullptr, nullptr,
        stats + 32 * STSLOT, nullptr, bufT);
    float* xT    = R4;
    float* d2out = R3;
    float* d3out = R4;
    bn_tx_kernel<<<2048, 256, 0, stream>>>(bufT, stats + 32 * STSLOT, bn2_g, bn2_be,
                                           bufX, bufX, xT);
    mfma_conv3<2, 0, 0, 27, 1, 0, 0><<<gmf, 256, 0, stream>>>(
        bufX, nullptr, WF + (size_t)33 * WFL, dc2_ob, nullptr, nullptr, nullptr,
        nullptr, nullptr, bufT);
    dcn_mfma<4, 0><<<gmf, 256, 0, stream>>>(xT, bufT, WF + (size_t)36 * WFL, dc2_b,
                                            nullptr, nullptr, d2out);
    mfma_conv3<2, 0, 0, 27, 1, 0, 1><<<gmf, 256, 0, stream>>>(
        d2out, nullptr, WF + (size_t)34 * WFL, dc3_ob, nullptr, nullptr, nullptr,
        nullptr, nullptr, bufT);
    dcn_mfma<4, 0><<<gmf, 256, 0, stream>>>(d2out, bufT, WF + (size_t)37 * WFL, dc3_b,
                                            nullptr, nullptr, d3out);
    mfma_conv3<2, 0, 0, 27, 1, 0, 1><<<gmf, 256, 0, stream>>>(
        d3out, nullptr, WF + (size_t)35 * WFL, dc4_ob, nullptr, nullptr, nullptr,
        nullptr, nullptr, bufT);
    dcn_mfma<1, 1><<<gmf, 256, 0, stream>>>(d3out, bufT, WF + (size_t)38 * WFL, dc4_b,
                                            conv4_w, conv4_b, (float*)d_out);
  }
}

// Round 9
// 2025.897 us; speedup vs baseline: 1.2435x; 1.0786x over previous
//
#include <hip/hip_runtime.h>
#include <cmath>

typedef unsigned short ushort_t;
typedef __attribute__((ext_vector_type(8))) short bf16x8;
typedef __attribute__((ext_vector_type(4))) float f32x4;

// Problem constants (B=2, C=64, H=W=256)
static constexpr int Bn   = 2;
static constexpr int Hn   = 256;
static constexpr int Wn   = 256;
static constexpr int HW   = Hn * Wn;          // 65536
static constexpr int CHW  = 64 * HW;          // 4194304
static constexpr int NCHW = Bn * CHW;         // 8388608
static constexpr int NPIX = Bn * HW;          // 131072
static constexpr float EPSv = 1e-5f;
static constexpr float INV_N = 1.0f / 131072.0f;   // BN count = B*H*W
static constexpr int NSLOT = 64;              // stats slot replication (anti-contention)
static constexpr int STSLOT = NSLOT * 128;    // floats per layer stats region
static constexpr int WFL = 73728;             // ushorts per weight-fragment layer slot

// bf16 round-to-nearest-even (no NaN inputs in this net)
__device__ inline uint32_t bf16_rne(float f) {
  uint32_t u = __float_as_uint(f);
  return (u + 0x7FFFu + ((u >> 16) & 1u)) >> 16;
}
__device__ inline void split_hl(float v, uint32_t& h, uint32_t& l) {
  h = bf16_rne(v);
  l = bf16_rne(v - __uint_as_float(h << 16)) & 0xFFFFu;
}
__device__ inline bf16x8 lds_ld16(const ushort_t* p) {   // 2x ds_read_b64
  union { bf16x8 v; uint2 u[2]; } r;
  r.u[0] = *(const uint2*)p;
  r.u[1] = *(const uint2*)(p + 4);
  return r.v;
}

// async global->LDS, 16B per lane: LDS dest = wave-uniform base + lane*16,
// global src is per-lane (carries the XOR swizzle + OOB zero-page redirect).
typedef __attribute__((address_space(1))) const void glb_void;
typedef __attribute__((address_space(3))) void lds_void;
__device__ inline void gld_lds16(const void* g, void* l) {
  __builtin_amdgcn_global_load_lds((glb_void*)g, (lds_void*)l, 16, 0, 0);
}

// ---------------------------------------------------------------------------
__global__ void transpose_w_kernel(const float* __restrict__ in, float* __restrict__ out,
                                   int NB, int OC, int IC, int K) {
  int total = NB * OC * IC * K;
  for (int i = blockIdx.x * blockDim.x + threadIdx.x; i < total; i += gridDim.x * blockDim.x) {
    int k  = i % K;
    int t  = i / K;
    int ic = t % IC; t /= IC;
    int oc = t % OC;
    int nb = t / OC;
    out[(((size_t)nb * IC + ic) * K + k) * OC + oc] = in[i];
  }
}

// ---------------------------------------------------------------------------
// Weight fragment prep: w[oc][ic][3][3] f32 -> MFMA B-frag order, bf16 hi/lo.
__global__ void prep_wfrag(const float* __restrict__ w, ushort_t* __restrict__ out,
                           int NGp, int ocreal, int wlstride, int olstride) {
  int layer = blockIdx.y;
  int elems = 9 * 2 * NGp * 64 * 8;
  int idx = blockIdx.x * 256 + threadIdx.x;
  if (idx >= elems) return;
  int j = idx & 7, lane = (idx >> 3) & 63;
  int rest = idx >> 9;
  int g = rest % NGp; rest /= NGp;
  int ih = rest & 1, tap = rest >> 1;
  int oc = g * 16 + (lane & 15);
  int ic = ih * 32 + (lane >> 4) * 8 + j;
  float v = 0.0f;
  if (oc < ocreal) v = w[(size_t)layer * wlstride + (oc * 64 + ic) * 9 + tap];
  uint32_t hi, lo;
  split_hl(v, hi, lo);
  out[(size_t)layer * olstride + idx] = (ushort_t)hi;
  out[(size_t)layer * olstride + elems + idx] = (ushort_t)lo;
}

// ---------------------------------------------------------------------------
__global__ void prep_kernel(const float* __restrict__ LowDEM, const float* __restrict__ Point_Ele,
                            const float* __restrict__ Slope, const float* __restrict__ Distance,
                            const float* __restrict__ Level, const float* __restrict__ w0,
                            const float* __restrict__ b0, float* __restrict__ x0) {
  int i = blockIdx.x * blockDim.x + threadIdx.x;
  if (i >= NPIX) return;
  float lv  = Level[i];
  float err = w0[0] * Slope[i] + w0[1] * Distance[i] + w0[2] * lv + b0[0];
  float lm  = (lv != 0.0f) ? 1.0f : 0.0f;
  x0[i] = LowDEM[i] * (1.0f - lm) + Point_Ele[i] + err * lm;
}

// ---------------------------------------------------------------------------
// conv9x9: when hiP != nullptr (fused path) writes X in HWC fp32 layout AND
// the bf16 hi/lo HWC planes; else planar NCHW (legacy).
__global__ __launch_bounds__(256, 2)
void conv9x9_kernel(const float* __restrict__ in, const float* __restrict__ wT,
                    const float* __restrict__ bias, float* __restrict__ out,
                    uint32_t* __restrict__ hiP, uint32_t* __restrict__ loP) {
  const int tx = threadIdx.x & 15, ty = threadIdx.x >> 4;
  const int w0 = blockIdx.x * 16, h0 = blockIdx.y * 16, b = blockIdx.z;
  __shared__ float lds[24 * 24];
  for (int idx = threadIdx.x; idx < 576; idx += 256) {
    int yy = idx / 24, xx = idx - yy * 24;
    int gy = h0 + yy - 4, gx = w0 + xx - 4;
    float v = 0.0f;
    if ((unsigned)gy < 256u && (unsigned)gx < 256u) v = in[b * HW + gy * 256 + gx];
    lds[idx] = v;
  }
  __syncthreads();
  float acc[64];
#pragma unroll
  for (int o = 0; o < 64; o++) acc[o] = 0.0f;
#pragma unroll 1
  for (int i = 0; i < 9; i++) {
#pragma unroll
    for (int j = 0; j < 9; j++) {
      float v = lds[(ty + i) * 24 + tx + j];
      const float* wp = wT + (i * 9 + j) * 64;   // uniform -> s_load
#pragma unroll
      for (int o = 0; o < 64; o++) acc[o] = fmaf(v, wp[o], acc[o]);
    }
  }
  const int p = (h0 + ty) * 256 + (w0 + tx);
  if (hiP) {
    float* op = out + ((size_t)b * HW + p) * 64;      // HWC fp32
#pragma unroll
    for (int o4 = 0; o4 < 16; o4++) {
      float4 v;
      v.x = acc[o4 * 4 + 0] + bias[o4 * 4 + 0];
      v.y = acc[o4 * 4 + 1] + bias[o4 * 4 + 1];
      v.z = acc[o4 * 4 + 2] + bias[o4 * 4 + 2];
      v.w = acc[o4 * 4 + 3] + bias[o4 * 4 + 3];
      *(float4*)(op + o4 * 4) = v;
    }
    uint32_t* hb = hiP + ((size_t)b * HW + p) * 32;
    uint32_t* lb = loP + ((size_t)b * HW + p) * 32;
#pragma unroll
    for (int o2 = 0; o2 < 32; o2++) {
      float v0 = acc[o2 * 2] + bias[o2 * 2];
      float v1 = acc[o2 * 2 + 1] + bias[o2 * 2 + 1];
      uint32_t h0v, l0v, h1v, l1v;
      split_hl(v0, h0v, l0v);
      split_hl(v1, h1v, l1v);
      hb[o2] = h0v | (h1v << 16);
      lb[o2] = l0v | (l1v << 16);
    }
  } else {
    float* op = out + (size_t)b * CHW + p;            // planar (legacy)
#pragma unroll
    for (int o = 0; o < 64; o++) op[o * HW] = acc[o] + bias[o];
  }
}

// ---------------------------------------------------------------------------
// OLD-STYLE MFMA conv3x3 (VALU-transform staging). Legacy (small-ws) path.
// MODE 0 plain / 1 relu(bn) / 2 bn+skip (WRITEY: materialize y). INHWC:
// pixel-major input.
// ---------------------------------------------------------------------------
template <int NG, int MODE, int STATS, int OCLIM, int HASBIAS, int WRITEY, int INHWC>
__global__ __launch_bounds__(256, 3)
void mfma_conv3(const float* __restrict__ in, const float* __restrict__ skip,
                const ushort_t* __restrict__ wf,
                const float* __restrict__ bias, const float* __restrict__ stats_in,
                const float* __restrict__ gg, const float* __restrict__ be,
                float* __restrict__ stats_out, float* __restrict__ yout,
                float* __restrict__ out) {
  const int tid  = threadIdx.x;
  const int lane = tid & 63, wid = tid >> 6;
  const int m = lane & 15, quad = lane >> 4;
  const int x0 = blockIdx.x * 16, y0 = blockIdx.y * 4, b = blockIdx.z;
  constexpr int WT = 2 * NG * 64 * 8;          // ushorts per tap per plane
  __shared__ __align__(16) ushort_t xh[108 * 68];   // hi plane, [spat][ch]
  __shared__ __align__(16) ushort_t xl[108 * 68];   // lo plane
  __shared__ float s_sc[MODE ? 64 : 1], s_sh[MODE ? 64 : 1];
  __shared__ float red[STATS ? 2 * 4 * 64 : 1];
  if (MODE) {
    if (tid < 64) {
      float sum = 0.0f, sq = 0.0f;
      for (int sl = 0; sl < NSLOT; sl++) {
        sum += stats_in[sl * 128 + tid];
        sq  += stats_in[sl * 128 + 64 + tid];
      }
      float mn = sum * INV_N, var = sq * INV_N - mn * mn;
      float s = gg[tid] * rsqrtf(var + EPSv);
      s_sc[tid] = s;
      s_sh[tid] = be[tid] - mn * s;
    }
    __syncthreads();
  }
  const float* inb = in + (size_t)b * CHW;
  const float* skb = MODE == 2 ? skip + (size_t)b * CHW : nullptr;
  float* ytb = WRITEY ? yout + (size_t)b * CHW : nullptr;
  uint32_t* xh32 = (uint32_t*)xh;              // row stride 34 dwords
  uint32_t* xl32 = (uint32_t*)xl;
#pragma unroll
  for (int t = 0; t < 14; t++) {
    int idx = t * 256 + tid;                   // 3456 = 108 spat * 32 ic-pairs
    if (idx < 3456) {
      int r, icp;
      if (INHWC) { icp = idx & 31; r = idx >> 5; }   // tid-contig ic -> coalesced HWC
      else       { r = idx % 108; icp = idx / 108; } // tid-contig px -> coalesced NCHW
      int row = r / 18, col = r - row * 18;
      int gy = y0 - 1 + row, gx = x0 - 1 + col;
      float v0 = 0.0f, v1 = 0.0f;
      if ((unsigned)gy < 256u && (unsigned)gx < 256u) {
        int ic = icp * 2;
        if (INHWC) {
          float2 vv = *(const float2*)&inb[(size_t)(gy * 256 + gx) * 64 + ic];
          v0 = vv.x; v1 = vv.y;
        } else {
          v0 = inb[ic * HW + gy * 256 + gx];
          v1 = inb[(ic + 1) * HW + gy * 256 + gx];
        }
        if (MODE == 1) {
          v0 = fmaxf(fmaf(v0, s_sc[ic], s_sh[ic]), 0.0f);
          v1 = fmaxf(fmaf(v1, s_sc[ic + 1], s_sh[ic + 1]), 0.0f);
        }
        if (MODE == 2) {
          v0 = fmaf(v0, s_sc[ic], s_sh[ic]) + skb[ic * HW + gy * 256 + gx];
          v1 = fmaf(v1, s_sc[ic + 1], s_sh[ic + 1]) + skb[(ic + 1) * HW + gy * 256 + gx];
          if (WRITEY && row >= 1 && row <= 4 && col >= 1 && col <= 16) {
            ytb[ic * HW + gy * 256 + gx] = v0;
            ytb[(ic + 1) * HW + gy * 256 + gx] = v1;
          }
        }
      }
      uint32_t h0, l0, h1, l1;
      split_hl(v0, h0, l0);
      split_hl(v1, h1, l1);
      xh32[r * 34 + icp] = h0 | (h1 << 16);
      xl32[r * 34 + icp] = l0 | (l1 << 16);
    }
  }
  __syncthreads();                             // the ONLY barrier before epilogue
  f32x4 acc[NG];
#pragma unroll
  for (int g = 0; g < NG; g++) acc[g] = (f32x4){0.0f, 0.0f, 0.0f, 0.0f};

  const bf16x8* wfh = (const bf16x8*)wf;                 // hi plane, frag-ordered
  const bf16x8* wfl = (const bf16x8*)(wf + 9 * WT);      // lo plane

#pragma unroll 1
  for (int tap = 0; tap < 9; tap++) {
    bf16x8 bh[2][NG], bl[2][NG];
#pragma unroll
    for (int ih = 0; ih < 2; ih++)
#pragma unroll
      for (int g = 0; g < NG; g++) {
        int fi = ((tap * 2 + ih) * NG + g) * 64 + lane;
        bh[ih][g] = wfh[fi];
        bl[ih][g] = wfl[fi];
      }
    const int dy = tap / 3 - 1, dx = tap % 3 - 1;
    const int spat = (wid + dy + 1) * 18 + (m + dx + 1);
#pragma unroll
    for (int ih = 0; ih < 2; ih++) {
      const int base = spat * 68 + ih * 32 + quad * 8;
      bf16x8 ah = lds_ld16(xh + base);
      bf16x8 al = lds_ld16(xl + base);
#pragma unroll
      for (int g = 0; g < NG; g++) {
        acc[g] = __builtin_amdgcn_mfma_f32_16x16x32_bf16(ah, bh[ih][g], acc[g], 0, 0, 0);
        acc[g] = __builtin_amdgcn_mfma_f32_16x16x32_bf16(al, bh[ih][g], acc[g], 0, 0, 0);
        acc[g] = __builtin_amdgcn_mfma_f32_16x16x32_bf16(ah, bl[ih][g], acc[g], 0, 0, 0);
      }
    }
  }
  // epilogue: D[row=quad*4+r][col=lane&15] -> pixel (y0+wid, x0+quad*4+r), oc=g*16+m
  const int py = y0 + wid;
  float* ob = out + (size_t)b * OCLIM * HW + py * 256 + x0 + quad * 4;
#pragma unroll
  for (int g = 0; g < NG; g++) {
    int oc = g * 16 + m;
    if (oc < OCLIM) {
      float bv = HASBIAS ? bias[oc] : 0.0f;
#pragma unroll
      for (int r = 0; r < 4; r++) ob[oc * HW + r] = acc[g][r] + bv;
    }
    if (STATS) {
      float s  = acc[g][0] + acc[g][1] + acc[g][2] + acc[g][3];
      float s2 = acc[g][0] * acc[g][0] + acc[g][1] * acc[g][1] +
                 acc[g][2] * acc[g][2] + acc[g][3] * acc[g][3];
      s  += __shfl_xor(s, 16, 64);  s  += __shfl_xor(s, 32, 64);
      s2 += __shfl_xor(s2, 16, 64); s2 += __shfl_xor(s2, 32, 64);
      if (lane < 16) {
        red[(0 * 4 + wid) * 64 + g * 16 + lane] = s;
        red[(1 * 4 + wid) * 64 + g * 16 + lane] = s2;
      }
    }
  }
  if (STATS) {
    __syncthreads();
    if (tid < 128) {
      int oc = tid & 63, which = tid >> 6;
      float tot = red[(which * 4 + 0) * 64 + oc] + red[(which * 4 + 1) * 64 + oc] +
                  red[(which * 4 + 2) * 64 + oc] + red[(which * 4 + 3) * 64 + oc];
      int slot = (blockIdx.y * 16 + blockIdx.x) & (NSLOT - 1);
      atomicAdd(&stats_out[slot * 128 + which * 64 + oc], tot);
    }
  }
}

// ---------------------------------------------------------------------------
// R23 chain conv: DMA staging + 16x8 tile, 2-oc-group x 4-row wave split.
// R22 (1 group x 8 rows) made A-frag ds_reads 4x (32/wave/tap) -> LDS-read
// bound (13.8k LDS cyc vs 8.6k MFMA cyc per block). 2x4 split: 16 ds_reads
// /wave/tap (6.9k cyc, under MFMA) at 2x weight traffic vs R22 (300 MB, ~8.6us
// L2 — still 2x better than R18's 600). Per-output MFMA order unchanged.
// Stats: direct atomicAdd per wave per group (no red buffer / 2nd barrier).
// ---------------------------------------------------------------------------
__global__ __launch_bounds__(256, 3)
void mfma_conv3_dma(const ushort_t* __restrict__ hiP, const ushort_t* __restrict__ loP,
                    const ushort_t* __restrict__ wf, const float* __restrict__ zeroPg,
                    float* __restrict__ stats_out, float* __restrict__ out) {
  const int tid  = threadIdx.x;
  const int lane = tid & 63, wid = tid >> 6;
  const int m = lane & 15, quad = lane >> 4;
  const int x0 = blockIdx.x * 16, y0 = blockIdx.y * 8, b = blockIdx.z;
  // 180 spats (18 cols x 10 rows) * 8 chunks(16B) per plane; hi then lo.
  __shared__ __align__(16) ushort_t xs[2880 * 8];   // 46080 B
  const size_t bimg = (size_t)b * HW;
  for (int g = wid; g < 45; g += 4) {
    int q  = g * 64 + lane;                 // 0..2879
    int pl = q >= 1440;
    int r  = q - (pl ? 1440 : 0);
    int s  = r >> 3, jl = r & 7;
    int js = jl ^ (s & 7);
    int row = s / 18, col = s - row * 18;
    int gy = y0 - 1 + row, gx = x0 - 1 + col;
    const ushort_t* src = (const ushort_t*)zeroPg;
    if ((unsigned)gy < 256u && (unsigned)gx < 256u)
      src = (pl ? loP : hiP) + ((bimg + (size_t)(gy * 256 + gx)) << 6) + (js << 3);
    gld_lds16(src, (void*)&xs[(size_t)g * 512]);
  }
  __syncthreads();                           // compiler drains vmcnt here

  const int gsel = wid >> 1;                 // oc-group pair: groups gsel*2+{0,1}
  const int rsel = (wid & 1) * 4;            // row base: 0 or 4
  f32x4 acc[4][2];
#pragma unroll
  for (int t = 0; t < 4; t++)
#pragma unroll
    for (int g = 0; g < 2; g++) acc[t][g] = (f32x4){0.0f, 0.0f, 0.0f, 0.0f};
  const bf16x8* wfh = (const bf16x8*)wf;
  const bf16x8* wfl8 = (const bf16x8*)(wf + 9 * 4096);   // WT = 2*4*64*8 = 4096

#pragma unroll 1
  for (int tap = 0; tap < 9; tap++) {
    bf16x8 bh[2][2], bl[2][2];
#pragma unroll
    for (int ih = 0; ih < 2; ih++)
#pragma unroll
      for (int g = 0; g < 2; g++) {
        int fi = ((tap * 2 + ih) * 4 + gsel * 2 + g) * 64 + lane;
        bh[ih][g] = wfh[fi];
        bl[ih][g] = wfl8[fi];
      }
    const int dy = tap / 3 - 1, dxx = tap % 3 - 1;
    const int scol = m + dxx + 1;
#pragma unroll
    for (int t = 0; t < 4; t++) {
      const int s  = (rsel + t + dy + 1) * 18 + scol;
      const int s7 = s & 7;
#pragma unroll
      for (int ih = 0; ih < 2; ih++) {
        const int ch = s * 8 + ((ih * 4 + quad) ^ s7);   // swizzled chunk
        bf16x8 ah = *(const bf16x8*)&xs[ch * 8];
        bf16x8 al = *(const bf16x8*)&xs[ch * 8 + 11520]; // lo plane (+1440 chunks)
#pragma unroll
        for (int g = 0; g < 2; g++) {
          acc[t][g] = __builtin_amdgcn_mfma_f32_16x16x32_bf16(ah, bh[ih][g], acc[t][g], 0, 0, 0);
          acc[t][g] = __builtin_amdgcn_mfma_f32_16x16x32_bf16(al, bh[ih][g], acc[t][g], 0, 0, 0);
          acc[t][g] = __builtin_amdgcn_mfma_f32_16x16x32_bf16(ah, bl[ih][g], acc[t][g], 0, 0, 0);
        }
      }
    }
  }
  // HWC epilogue: row y0+rsel+t, pixel col x0+quad*4+r, oc = gsel*32+g*16+m
  const int slot = (blockIdx.y * 16 + blockIdx.x) & (NSLOT - 1);
#pragma unroll
  for (int g = 0; g < 2; g++) {
    const int oc = gsel * 32 + g * 16 + m;
    float s = 0.0f, s2 = 0.0f;
#pragma unroll
    for (int t = 0; t < 4; t++) {
      const int py = y0 + rsel + t;
      float* ob = out + ((size_t)b * HW + (size_t)py * 256 + x0) * 64;
#pragma unroll
      for (int r = 0; r < 4; r++) {
        float v = acc[t][g][r];
        ob[(quad * 4 + r) * 64 + oc] = v;
        s += v;
        s2 += v * v;
      }
    }
    s  += __shfl_xor(s, 16, 64);  s  += __shfl_xor(s, 32, 64);
    s2 += __shfl_xor(s2, 16, 64); s2 += __shfl_xor(s2, 32, 64);
    if (lane < 16) {
      atomicAdd(&stats_out[slot * 128 + oc], s);
      atomicAdd(&stats_out[slot * 128 + 64 + oc], s2);
    }
  }
}

// ---------------------------------------------------------------------------
// Offset conv (dc2/dc3/dc4): DMA staging from bf16 hi/lo planes (16x8, same
// geometry as chain conv), NG=2, planar-27 epilogue with bias.
// ---------------------------------------------------------------------------
__global__ __launch_bounds__(256, 3)
void ofs_conv_dma(const ushort_t* __restrict__ hiP, const ushort_t* __restrict__ loP,
                  const ushort_t* __restrict__ wf, const float* __restrict__ zeroPg,
                  const float* __restrict__ bias, float* __restrict__ out) {
  const int tid  = threadIdx.x;
  const int lane = tid & 63, wid = tid >> 6;
  const int m = lane & 15, quad = lane >> 4;
  const int x0 = blockIdx.x * 16, y0 = blockIdx.y * 8, b = blockIdx.z;
  __shared__ __align__(16) ushort_t xs[2880 * 8];   // 46080 B
  const size_t bimg = (size_t)b * HW;
  for (int g = wid; g < 45; g += 4) {
    int q  = g * 64 + lane;
    int pl = q >= 1440;
    int r  = q - (pl ? 1440 : 0);
    int s  = r >> 3, jl = r & 7;
    int js = jl ^ (s & 7);
    int row = s / 18, col = s - row * 18;
    int gy = y0 - 1 + row, gx = x0 - 1 + col;
    const ushort_t* src = (const ushort_t*)zeroPg;
    if ((unsigned)gy < 256u && (unsigned)gx < 256u)
      src = (pl ? loP : hiP) + ((bimg + (size_t)(gy * 256 + gx)) << 6) + (js << 3);
    gld_lds16(src, (void*)&xs[(size_t)g * 512]);
  }
  __syncthreads();

  f32x4 acc[2][2];
#pragma unroll
  for (int t = 0; t < 2; t++)
#pragma unroll
    for (int g = 0; g < 2; g++) acc[t][g] = (f32x4){0.0f, 0.0f, 0.0f, 0.0f};
  const bf16x8* wfh = (const bf16x8*)wf;
  const bf16x8* wfl8 = (const bf16x8*)(wf + 9 * 2048);   // WT = 2*2*64*8 = 2048

#pragma unroll 1
  for (int tap = 0; tap < 9; tap++) {
    bf16x8 bh[2][2], bl[2][2];
#pragma unroll
    for (int ih = 0; ih < 2; ih++)
#pragma unroll
      for (int g = 0; g < 2; g++) {
        int fi = ((tap * 2 + ih) * 2 + g) * 64 + lane;
        bh[ih][g] = wfh[fi];
        bl[ih][g] = wfl8[fi];
      }
    const int dy = tap / 3 - 1, dxx = tap % 3 - 1;
    const int scol = m + dxx + 1;
#pragma unroll
    for (int t = 0; t < 2; t++) {
      const int s  = (wid * 2 + t + dy + 1) * 18 + scol;
      const int s7 = s & 7;
#pragma unroll
      for (int ih = 0; ih < 2; ih++) {
        const int ch = s * 8 + ((ih * 4 + quad) ^ s7);
        bf16x8 ah = *(const bf16x8*)&xs[ch * 8];
        bf16x8 al = *(const bf16x8*)&xs[ch * 8 + 11520];
#pragma unroll
        for (int g = 0; g < 2; g++) {
          acc[t][g] = __builtin_amdgcn_mfma_f32_16x16x32_bf16(ah, bh[ih][g], acc[t][g], 0, 0, 0);
          acc[t][g] = __builtin_amdgcn_mfma_f32_16x16x32_bf16(al, bh[ih][g], acc[t][g], 0, 0, 0);
          acc[t][g] = __builtin_amdgcn_mfma_f32_16x16x32_bf16(ah, bl[ih][g], acc[t][g], 0, 0, 0);
        }
      }
    }
  }
  // planar epilogue (om layout [B][27][HW] kept for dcn's coalesced om reads)
#pragma unroll
  for (int g = 0; g < 2; g++) {
    int oc = g * 16 + m;
    if (oc < 27) {
      float bv = bias[oc];
#pragma unroll
      for (int t = 0; t < 2; t++) {
        const int py = y0 + wid * 2 + t;
        float* ob = out + (size_t)b * 27 * HW + (size_t)oc * HW + py * 256 + x0 + quad * 4;
#pragma unroll
        for (int r = 0; r < 4; r++) ob[r] = acc[t][g][r] + bv;
      }
    }
  }
}

// ---------------------------------------------------------------------------
// R17 transform: all-HWC streaming. Finalize BN of raw conv out t (HWC) and
// materialize bf16 hi/lo HWC planes. TMODE 1: relu(bn(t)) -> planes only.
// TMODE 2: y = bn(t)+skip -> y fp32 HWC + planes. Parallel stats preamble.
// ---------------------------------------------------------------------------
template <int TMODE>
__global__ __launch_bounds__(256, 8)
void bn_split_hwc(const float* __restrict__ t, const float* __restrict__ stats,
                  const float* __restrict__ g, const float* __restrict__ be,
                  const float* __restrict__ skip, float* __restrict__ yout,
                  uint32_t* __restrict__ hiP, uint32_t* __restrict__ loP) {
  __shared__ float part[2][4][64];
  __shared__ float s_sc[64], s_sh[64];
  const int tid = threadIdx.x;
  {
    int c = tid & 63, q = tid >> 6;
    float sum = 0.0f, sq = 0.0f;
    for (int sl = q * 16; sl < q * 16 + 16; sl++) {
      sum += stats[sl * 128 + c];
      sq  += stats[sl * 128 + 64 + c];
    }
    part[0][q][c] = sum;
    part[1][q][c] = sq;
  }
  __syncthreads();
  if (tid < 64) {
    int c = tid;
    float sum = part[0][0][c] + part[0][1][c] + part[0][2][c] + part[0][3][c];
    float sq  = part[1][0][c] + part[1][1][c] + part[1][2][c] + part[1][3][c];
    float mn  = sum * INV_N;
    float var = sq * INV_N - mn * mn;
    float s   = g[c] * rsqrtf(var + EPSv);
    s_sc[c] = s;
    s_sh[c] = be[c] - mn * s;
  }
  __syncthreads();
  const int blk = blockIdx.x;            // 2048 = NPIX/64
  const int b  = blk >> 10;
  const int p0 = (blk & 1023) * 64;
  const size_t base = ((size_t)b * HW + p0) * 64;   // floats (HWC)
  uint32_t* hb = hiP + ((size_t)b * HW + p0) * 32;
  uint32_t* lb = loP + ((size_t)b * HW + p0) * 32;
#pragma unroll
  for (int i = 0; i < 8; i++) {
    int idx = i * 256 + tid;             // 0..2047 = 64 px * 32 ch-pairs
    int p = idx >> 5, c2 = idx & 31;
    size_t off = base + (size_t)p * 64 + c2 * 2;
    float2 v = *(const float2*)&t[off];
    float v0 = fmaf(v.x, s_sc[c2 * 2],     s_sh[c2 * 2]);
    float v1 = fmaf(v.y, s_sc[c2 * 2 + 1], s_sh[c2 * 2 + 1]);
    if (TMODE == 1) {
      v0 = fmaxf(v0, 0.0f);
      v1 = fmaxf(v1, 0.0f);
    } else {
      float2 k = *(const float2*)&skip[off];
      v0 += k.x; v1 += k.y;
      float2 y2; y2.x = v0; y2.y = v1;
      *(float2*)&yout[off] = y2;
    }
    uint32_t h0v, l0v, h1v, l1v;
    split_hl(v0, h0v, l0v);
    split_hl(v1, h1v, l1v);
    hb[p * 32 + c2] = h0v | (h1v << 16);
    lb[p * 32 + c2] = l0v | (l1v << 16);
  }
}

// ---------------------------------------------------------------------------
// R20: x = bn(t)+skip, all-HWC streaming; also emits x's bf16 hi/lo planes
// (feeds the DMA offset conv for dc2).
// ---------------------------------------------------------------------------
__global__ __launch_bounds__(256, 8)
void bn_add_hwc(const float* __restrict__ t, const float* __restrict__ stats,
                const float* __restrict__ g, const float* __restrict__ be,
                const float* __restrict__ skip, float* __restrict__ xout,
                uint32_t* __restrict__ hiP, uint32_t* __restrict__ loP) {
  __shared__ float part[2][4][64];
  __shared__ float s_sc[64], s_sh[64];
  const int tid = threadIdx.x;
  {
    int c = tid & 63, q = tid >> 6;
    float sum = 0.0f, sq = 0.0f;
    for (int sl = q * 16; sl < q * 16 + 16; sl++) {
      sum += stats[sl * 128 + c];
      sq  += stats[sl * 128 + 64 + c];
    }
    part[0][q][c] = sum;
    part[1][q][c] = sq;
  }
  __syncthreads();
  if (tid < 64) {
    int c = tid;
    float sum = part[0][0][c] + part[0][1][c] + part[0][2][c] + part[0][3][c];
    float sq  = part[1][0][c] + part[1][1][c] + part[1][2][c] + part[1][3][c];
    float mn  = sum * INV_N;
    float var = sq * INV_N - mn * mn;
    float s   = g[c] * rsqrtf(var + EPSv);
    s_sc[c] = s;
    s_sh[c] = be[c] - mn * s;
  }
  __syncthreads();
  const int blk = blockIdx.x;            // 2048
  const int b  = blk >> 10;
  const int p0 = (blk & 1023) * 64;
  const size_t base4 = (((size_t)b * HW + p0) * 64) >> 2;   // float4 units
  const float4* t4 = (const float4*)t;
  const float4* k4 = (const float4*)skip;
  float4* x4 = (float4*)xout;
  uint32_t* hb = hiP + ((size_t)b * HW + p0) * 32;
  uint32_t* lb = loP + ((size_t)b * HW + p0) * 32;
#pragma unroll
  for (int i = 0; i < 4; i++) {
    int idx = i * 256 + tid;             // 0..1023 = 64 px * 16 ch-quads
    int c = (idx & 15) * 4;
    int p = idx >> 4;
    float4 v = t4[base4 + idx], k = k4[base4 + idx], r;
    r.x = fmaf(v.x, s_sc[c],     s_sh[c])     + k.x;
    r.y = fmaf(v.y, s_sc[c + 1], s_sh[c + 1]) + k.y;
    r.z = fmaf(v.z, s_sc[c + 2], s_sh[c + 2]) + k.z;
    r.w = fmaf(v.w, s_sc[c + 3], s_sh[c + 3]) + k.w;
    x4[base4 + idx] = r;
    uint32_t h0v, l0v, h1v, l1v, h2v, l2v, h3v, l3v;
    split_hl(r.x, h0v, l0v); split_hl(r.y, h1v, l1v);
    split_hl(r.z, h2v, l2v); split_hl(r.w, h3v, l3v);
    uint2 hv = make_uint2(h0v | (h1v << 16), h2v | (h3v << 16));
    uint2 lv = make_uint2(l0v | (l1v << 16), l2v | (l3v << 16));
    *(uint2*)&hb[p * 32 + (c >> 1)] = hv;
    *(uint2*)&lb[p * 32 + (c >> 1)] = lv;
  }
}

// ---------------------------------------------------------------------------
// Legacy path only: y = BN(t)*g+be + skip (float4).
// ---------------------------------------------------------------------------
__global__ void bn_apply_add_kernel(const float* __restrict__ t, const float* __restrict__ stats,
                                    const float* __restrict__ g, const float* __restrict__ be,
                                    const float* __restrict__ skip, float* __restrict__ out) {
  __shared__ float s_sc[64], s_sh[64];
  if (threadIdx.x < 64) {
    int c = threadIdx.x;
    float sum = 0.0f, sq = 0.0f;
    for (int sl = 0; sl < NSLOT; sl++) {
      sum += stats[sl * 128 + c];
      sq  += stats[sl * 128 + 64 + c];
    }
    float m   = sum * INV_N;
    float var = sq * INV_N - m * m;
    float s   = g[c] * rsqrtf(var + EPSv);
    s_sc[c] = s;
    s_sh[c] = be[c] - m * s;
  }
  __syncthreads();
  const float4* t4 = (const float4*)t;
  const float4* k4 = (const float4*)skip;
  float4* o4 = (float4*)out;
  const int n4 = NCHW / 4;
  for (int i = blockIdx.x * blockDim.x + threadIdx.x; i < n4; i += gridDim.x * blockDim.x) {
    int c = (i >> 14) & 63;
    float s = s_sc[c], h = s_sh[c];
    float4 v = t4[i], kk = k4[i], r;
    r.x = fmaf(v.x, s, h) + kk.x;
    r.y = fmaf(v.y, s, h) + kk.y;
    r.z = fmaf(v.z, s, h) + kk.z;
    r.w = fmaf(v.w, s, h) + kk.w;
    o4[i] = r;
  }
}

// ---------------------------------------------------------------------------
// Legacy path only: fused x = bn(t)+skip -> planar out AND HWC mirror.
// ---------------------------------------------------------------------------
__global__ __launch_bounds__(256, 4)
void bn_tx_kernel(const float* __restrict__ t, const float* __restrict__ stats,
                  const float* __restrict__ g, const float* __restrict__ be,
                  const float* __restrict__ skip, float* __restrict__ outP,
                  float* __restrict__ outHWC) {
  __shared__ float tile[64][65];
  __shared__ float s_sc[64], s_sh[64];
  if (threadIdx.x < 64) {
    int c = threadIdx.x;
    float sum = 0.0f, sq = 0.0f;
    for (int sl = 0; sl < NSLOT; sl++) {
      sum += stats[sl * 128 + c];
      sq  += stats[sl * 128 + 64 + c];
    }
    float m   = sum * INV_N;
    float var = sq * INV_N - m * m;
    float s   = g[c] * rsqrtf(var + EPSv);
    s_sc[c] = s;
    s_sh[c] = be[c] - m * s;
  }
  __syncthreads();
  const int blk = blockIdx.x;            // 2048 = NPIX/64
  const int b = blk >> 10;
  const int p0 = (blk & 1023) * 64;
  const float* tb = t + (size_t)b * CHW;
  const float* kb = skip + (size_t)b * CHW;
  float* oP = outP + (size_t)b * CHW;
  float* oH = outHWC + (size_t)b * CHW;
#pragma unroll
  for (int i = 0; i < 16; i++) {
    int idx = i * 256 + threadIdx.x;
    int c = idx >> 6, p = idx & 63;
    float v = fmaf(tb[c * HW + p0 + p], s_sc[c], s_sh[c]) + kb[c * HW + p0 + p];
    oP[c * HW + p0 + p] = v;
    tile[c][p] = v;
  }
  __syncthreads();
#pragma unroll
  for (int i = 0; i < 16; i++) {
    int idx = i * 256 + threadIdx.x;
    int p = idx >> 6, c = idx & 63;
    oH[(size_t)(p0 + p) * 64 + c] = tile[c][p];
  }
}

// ---------------------------------------------------------------------------
// Deformable conv on MFMA, HWC input. R21 (measured 90us, WIN): R18 schedule
// (double-buffered LDS, gather(tap+1) before MFMAs, 1 barrier/tap) with
// quad-per-pixel gather (gp = tid>>2, c4 = tid&3): 4 lanes of a pixel read
// contiguous 64B per corner -> 4x fewer L1 transactions; LDS write conflicts
// 16 -> 4-way (3.54M -> 1.18M). R16 reg-only REGRESSED; R19 cross-iteration
// pipeline FAILED correctness. PLANES: epilogue also emits relu output's bf16
// hi/lo planes (feeds next DMA offset conv). FINAL: fuse dc4 bias + conv4.
// ---------------------------------------------------------------------------
template <int NG, int FINAL, int PLANES>
__global__ __launch_bounds__(256, 4)
void dcn_mfma(const float* __restrict__ xhwc, const float* __restrict__ om,
              const ushort_t* __restrict__ wf, const float* __restrict__ bias,
              const float* __restrict__ c4w, const float* __restrict__ c4b,
              float* __restrict__ out,
              ushort_t* __restrict__ hiO, ushort_t* __restrict__ loO) {
  const int tid  = threadIdx.x;
  const int lane = tid & 63, wid = tid >> 6;
  const int m = lane & 15, quad = lane >> 4;
  const int x0 = blockIdx.x * 16, y0 = blockIdx.y * 4, b = blockIdx.z;
  constexpr int WT = 2 * NG * 64 * 8;
  __shared__ __align__(16) ushort_t sh[2][64 * 64];   // hi plane per buffer, 8 KB
  __shared__ __align__(16) ushort_t sl[2][64 * 64];   // lo plane
  const int gp = tid >> 2, c4 = tid & 3;       // gather role: pixel, 16B-chunk lane
  const int gpy = y0 + (gp >> 4), gxx = x0 + (gp & 15);
  const int psw = gp & 3;                      // pixel swizzle bits
  const float* xb  = xhwc + (size_t)b * CHW;
  const float* omb = om + (size_t)b * 27 * HW + gpy * 256 + gxx;

  auto gather = [&](int tap, int buf) {
    float dyv = omb[tap * HW];
    float dxv = omb[(9 + tap) * HW];
    float mo  = omb[(18 + tap) * HW];
    float mk  = 1.0f / (1.0f + __expf(-mo));
    float ys = fminf(fmaxf((float)(gpy + tap / 3 - 1) + dyv, -2.0f), 258.0f);
    float xs = fminf(fmaxf((float)(gxx + tap % 3 - 1) + dxv, -2.0f), 258.0f);
    float y0f = floorf(ys), x0f = floorf(xs);
    float wy = ys - y0f, wx = xs - x0f;
    int yi = (int)y0f, xi = (int)x0f;
    float vy0 = ((unsigned)yi       < 256u) ? 1.0f : 0.0f;
    float vy1 = ((unsigned)(yi + 1) < 256u) ? 1.0f : 0.0f;
    float vx0 = ((unsigned)xi       < 256u) ? 1.0f : 0.0f;
    float vx1 = ((unsigned)(xi + 1) < 256u) ? 1.0f : 0.0f;
    int cy0 = min(max(yi, 0), 255), cy1 = min(max(yi + 1, 0), 255);
    int cx0 = min(max(xi, 0), 255), cx1 = min(max(xi + 1, 0), 255);
    float W00 = (1.0f - wy) * (1.0f - wx) * mk * vy0 * vx0;
    float W01 = (1.0f - wy) * wx * mk * vy0 * vx1;
    float W10 = wy * (1.0f - wx) * mk * vy1 * vx0;
    float W11 = wy * wx * mk * vy1 * vx1;
    const float* p00 = xb + (size_t)(cy0 * 256 + cx0) * 64;
    const float* p01 = xb + (size_t)(cy0 * 256 + cx1) * 64;
    const float* p10 = xb + (size_t)(cy1 * 256 + cx0) * 64;
    const float* p11 = xb + (size_t)(cy1 * 256 + cx1) * 64;
#pragma unroll
    for (int j = 0; j < 4; j++) {
      const int k = c4 + 4 * j;                // 4-ch chunk index 0..15
      float4 a  = *(const float4*)(p00 + k * 4);
      float4 b2 = *(const float4*)(p01 + k * 4);
      float4 c2 = *(const float4*)(p10 + k * 4);
      float4 d2 = *(const float4*)(p11 + k * 4);
      float s0 = W00 * a.x + W01 * b2.x + W10 * c2.x + W11 * d2.x;
      float s1 = W00 * a.y + W01 * b2.y + W10 * c2.y + W11 * d2.y;
      float s2 = W00 * a.z + W01 * b2.z + W10 * c2.z + W11 * d2.z;
      float s3 = W00 * a.w + W01 * b2.w + W10 * c2.w + W11 * d2.w;
      uint32_t h0, l0, h1, l1, h2, l2, h3, l3;
      split_hl(s0, h0, l0); split_hl(s1, h1, l1);
      split_hl(s2, h2, l2); split_hl(s3, h3, l3);
      // chunk k lives at group (k>>2)=j, sub (k&3)=c4 -> same layout as before
      int wi = gp * 64 + ((j ^ psw) * 16) + c4 * 4;   // 8B-aligned
      *(uint2*)&sh[buf][wi] = make_uint2(h0 | (h1 << 16), h2 | (h3 << 16));
      *(uint2*)&sl[buf][wi] = make_uint2(l0 | (l1 << 16), l2 | (l3 << 16));
    }
  };

  f32x4 acc[NG];
#pragma unroll
  for (int g = 0; g < NG; g++) acc[g] = (f32x4){0.0f, 0.0f, 0.0f, 0.0f};
  const bf16x8* wfh = (const bf16x8*)wf;
  const bf16x8* wfl = (const bf16x8*)(wf + 9 * WT);
  const int px = wid * 16 + m;                 // this lane's A-row pixel

  gather(0, 0);
  __syncthreads();
#pragma unroll 1
  for (int tap = 0; tap < 9; tap++) {
    const int cur = tap & 1;
    if (tap < 8) gather(tap + 1, cur ^ 1);     // overlaps MFMAs below
#pragma unroll
    for (int ih = 0; ih < 2; ih++) {
      const int c = ih * 2 + (quad >> 1), h = quad & 1;
      const int ri = px * 64 + ((c ^ (px & 3)) * 16) + h * 8;   // 16B-aligned
      bf16x8 ah = *(const bf16x8*)&sh[cur][ri];
      bf16x8 al = *(const bf16x8*)&sl[cur][ri];
#pragma unroll
      for (int g = 0; g < NG; g++) {
        int fi = ((tap * 2 + ih) * NG + g) * 64 + lane;
        bf16x8 bh = wfh[fi], bl = wfl[fi];
        acc[g] = __builtin_amdgcn_mfma_f32_16x16x32_bf16(ah, bh, acc[g], 0, 0, 0);
        acc[g] = __builtin_amdgcn_mfma_f32_16x16x32_bf16(al, bh, acc[g], 0, 0, 0);
        acc[g] = __builtin_amdgcn_mfma_f32_16x16x32_bf16(ah, bl, acc[g], 0, 0, 0);
      }
    }
    __syncthreads();   // writes to buf^1 and reads of cur both done
  }
  const int py = y0 + wid;
  if (FINAL) {
    if (m == 0) {
      float* op = out + (size_t)b * HW + py * 256 + x0 + quad * 4;
#pragma unroll
      for (int r = 0; r < 4; r++) op[r] = c4w[0] * (acc[0][r] + bias[0]) + c4b[0];
    }
  } else {
    size_t pbase = ((size_t)b * HW + (size_t)py * 256 + x0 + quad * 4) * 64 + m;
    float* ob = out + pbase;
#pragma unroll
    for (int g = 0; g < NG; g++)
#pragma unroll
      for (int r = 0; r < 4; r++) {
        float v = fmaxf(acc[g][r] + bias[g * 16 + m], 0.0f);
        ob[r * 64 + g * 16] = v;
        if (PLANES) {
          uint32_t h, l;
          split_hl(v, h, l);
          hiO[pbase + r * 64 + g * 16] = (ushort_t)h;
          loO[pbase + r * 64 + g * 16] = (ushort_t)l;
        }
      }
  }
}

// ---------------------------------------------------------------------------
extern "C" void kernel_launch(void* const* d_in, const int* in_sizes, int n_in,
                              void* d_out, int out_size, void* d_ws, size_t ws_size,
                              hipStream_t stream) {
  const float* LowDEM    = (const float*)d_in[0];
  const float* Point_Ele = (const float*)d_in[1];
  const float* Slope     = (const float*)d_in[2];
  const float* Distance  = (const float*)d_in[3];
  const float* Level     = (const float*)d_in[4];
  const float* conv0_w   = (const float*)d_in[5];
  const float* conv0_b   = (const float*)d_in[6];
  const float* conv1_w   = (const float*)d_in[7];
  const float* conv1_b   = (const float*)d_in[8];
  const float* rb_w1     = (const float*)d_in[9];
  const float* rb_g1     = (const float*)d_in[11];
  const float* rb_be1    = (const float*)d_in[12];
  const float* rb_w2     = (const float*)d_in[13];
  const float* rb_g2     = (const float*)d_in[15];
  const float* rb_be2    = (const float*)d_in[16];
  const float* conv2_w   = (const float*)d_in[17];
  const float* bn2_g     = (const float*)d_in[19];
  const float* bn2_be    = (const float*)d_in[20];
  const float* dc2_w     = (const float*)d_in[21];
  const float* dc2_b     = (const float*)d_in[22];
  const float* dc2_ow    = (const float*)d_in[23];
  const float* dc2_ob    = (const float*)d_in[24];
  const float* dc3_w     = (const float*)d_in[25];
  const float* dc3_b     = (const float*)d_in[26];
  const float* dc3_ow    = (const float*)d_in[27];
  const float* dc3_ob    = (const float*)d_in[28];
  const float* dc4_w     = (const float*)d_in[29];
  const float* dc4_b     = (const float*)d_in[30];
  const float* dc4_ow    = (const float*)d_in[31];
  const float* dc4_ob    = (const float*)d_in[32];
  const float* conv4_w   = (const float*)d_in[33];
  const float* conv4_b   = (const float*)d_in[34];

  // small region first, then big buffers
  float* x0   = (float*)d_ws;             // 131072
  float* T1   = x0 + NPIX;                // 5184
  ushort_t* WF = (ushort_t*)(T1 + 5184);  // 39 * WFL ushorts
  float* stats = (float*)(WF + 39 * WFL); // 33 * STSLOT floats
  float* zpg   = stats + 33 * STSLOT;     // 32 floats: DMA zero page
  float* big   = zpg + 32;
  size_t used_small = (size_t)((char*)big - (char*)d_ws);
  bool fused = ws_size >= used_small + 5ull * NCHW * sizeof(float);

  float* bufX = big;                      // X (conv9x9 out; skip for bn2)
  float* bufT = bufX + NCHW;              // raw conv out / offset-conv out
  float* R3   = bufT + NCHW;              // fused: yA   | legacy: bufT2
  float* R4   = R3 + NCHW;                // fused: yB   | legacy: yA(=yB)
  ushort_t* hiP = (ushort_t*)(R4 + NCHW); // fused only: bf16 hi plane (HWC)
  ushort_t* loP = hiP + NCHW;             //             bf16 lo plane (HWC)

  hipMemsetAsync(stats, 0, 33 * STSLOT * sizeof(float), stream);
  hipMemsetAsync(zpg, 0, 128, stream);

  transpose_w_kernel<<<32, 256, 0, stream>>>(conv1_w, T1, 1, 64, 1, 81);

  prep_wfrag<<<dim3(144, 16), 256, 0, stream>>>(rb_w1,   WF,            4, 64, 36864, WFL);
  prep_wfrag<<<dim3(144, 16), 256, 0, stream>>>(rb_w2,   WF + 16 * WFL, 4, 64, 36864, WFL);
  prep_wfrag<<<dim3(144, 1),  256, 0, stream>>>(conv2_w, WF + 32 * WFL, 4, 64, 36864, WFL);
  prep_wfrag<<<dim3(72, 1),   256, 0, stream>>>(dc2_ow,  WF + 33 * WFL, 2, 27, 15552, WFL);
  prep_wfrag<<<dim3(72, 1),   256, 0, stream>>>(dc3_ow,  WF + 34 * WFL, 2, 27, 15552, WFL);
  prep_wfrag<<<dim3(72, 1),   256, 0, stream>>>(dc4_ow,  WF + 35 * WFL, 2, 27, 15552, WFL);
  prep_wfrag<<<dim3(144, 1),  256, 0, stream>>>(dc2_w,   WF + 36 * WFL, 4, 64, 36864, WFL);
  prep_wfrag<<<dim3(144, 1),  256, 0, stream>>>(dc3_w,   WF + 37 * WFL, 4, 64, 36864, WFL);
  prep_wfrag<<<dim3(36, 1),   256, 0, stream>>>(dc4_w,   WF + 38 * WFL, 1, 1, 576, WFL);

  prep_kernel<<<(NPIX + 255) / 256, 256, 0, stream>>>(LowDEM, Point_Ele, Slope, Distance,
                                                      Level, conv0_w, conv0_b, x0);

  dim3 grid16(16, 16, 2);   // conv9x9
  dim3 gmf(16, 64, 2);      // dcn_mfma / legacy conv (16x4 pixel tiles)
  dim3 gmf8(16, 32, 2);     // chain conv / ofs conv (16x8 pixel tiles)

  conv9x9_kernel<<<grid16, 256, 0, stream>>>(x0, T1, conv1_b, bufX,
                                             fused ? (uint32_t*)hiP : nullptr,
                                             fused ? (uint32_t*)loP : nullptr);

  if (fused) {
    float* yA = R3;
    float* yB = R4;
    // R23: all-HWC chain — 2x4-split DMA convs + streaming bn/split.
    for (int i = 0; i < 16; i++) {
      mfma_conv3_dma<<<gmf8, 256, 0, stream>>>(hiP, loP, WF + (size_t)i * WFL, zpg,
                                               stats + (size_t)(2 * i) * STSLOT, bufT);
      bn_split_hwc<1><<<2048, 256, 0, stream>>>(
          bufT, stats + (size_t)(2 * i) * STSLOT, rb_g1 + i * 64, rb_be1 + i * 64,
          nullptr, nullptr, (uint32_t*)hiP, (uint32_t*)loP);
      mfma_conv3_dma<<<gmf8, 256, 0, stream>>>(hiP, loP, WF + (size_t)(16 + i) * WFL, zpg,
                                               stats + (size_t)(2 * i + 1) * STSLOT, bufT);
      const float* skp = (i == 0) ? bufX : ((i & 1) ? yA : yB);   // y_i
      float* yo = (i & 1) ? yB : yA;                              // y_{i+1}
      bn_split_hwc<2><<<2048, 256, 0, stream>>>(
          bufT, stats + (size_t)(2 * i + 1) * STSLOT, rb_g2 + i * 64, rb_be2 + i * 64,
          skp, yo, (uint32_t*)hiP, (uint32_t*)loP);
    }
    mfma_conv3_dma<<<gmf8, 256, 0, stream>>>(hiP, loP, WF + (size_t)32 * WFL, zpg,
                                             stats + (size_t)32 * STSLOT, bufT);

    float* xT    = R4;          // y16 fp32 dead (its planes fed conv2)
    float* d2out = R3;          // yA dead after i=15
    float* d3out = bufX;        // X dead after bn_add_hwc below
    // x = bn(conv2_out) + X -> xT (HWC) + x planes (for dc2's offset conv)
    bn_add_hwc<<<2048, 256, 0, stream>>>(bufT, stats + 32 * STSLOT, bn2_g, bn2_be,
                                         bufX, xT, (uint32_t*)hiP, (uint32_t*)loP);
    // dc2: DMA offset conv from x planes; dcn emits d2out fp32 + planes
    ofs_conv_dma<<<gmf8, 256, 0, stream>>>(hiP, loP, WF + (size_t)33 * WFL, zpg,
                                           dc2_ob, bufT);
    dcn_mfma<4, 0, 1><<<gmf, 256, 0, stream>>>(xT, bufT, WF + (size_t)36 * WFL, dc2_b,
                                               nullptr, nullptr, d2out, hiP, loP);
    // dc3: DMA offset conv from d2out planes; dcn emits d3out fp32 + planes
    ofs_conv_dma<<<gmf8, 256, 0, stream>>>(hiP, loP, WF + (size_t)34 * WFL, zpg,
                                           dc3_ob, bufT);
    dcn_mfma<4, 0, 1><<<gmf, 256, 0, stream>>>(d2out, bufT, WF + (size_t)37 * WFL, dc3_b,
                                               nullptr, nullptr, d3out, hiP, loP);
    // dc4 + conv4 -> d_out (offset conv from d3out planes)
    ofs_conv_dma<<<gmf8, 256, 0, stream>>>(hiP, loP, WF + (size_t)35 * WFL, zpg,
                                           dc4_ob, bufT);
    dcn_mfma<1, 1, 0><<<gmf, 256, 0, stream>>>(d3out, bufT, WF + (size_t)38 * WFL, dc4_b,
                                               conv4_w, conv4_b, (float*)d_out,
                                               nullptr, nullptr);
  } else {
    float* bufT2 = R3;
    float* bufY  = R4;
    for (int i = 0; i < 16; i++) {
      const float* src = (i == 0) ? bufX : bufY;
      mfma_conv3<4, 0, 1, 64, 0, 0, 0><<<gmf, 256, 0, stream>>>(
          src, nullptr, WF + (size_t)i * WFL, nullptr, nullptr, nullptr, nullptr,
          stats + (2 * i) * STSLOT, nullptr, bufT);
      mfma_conv3<4, 1, 1, 64, 0, 0, 0><<<gmf, 256, 0, stream>>>(
          bufT, nullptr, WF + (size_t)(16 + i) * WFL, nullptr, stats + (2 * i) * STSLOT,
          rb_g1 + i * 64, rb_be1 + i * 64, stats + (2 * i + 1) * STSLOT, nullptr, bufT2);
      bn_apply_add_kernel<<<2048, 256, 0, stream>>>(bufT2, stats + (2 * i + 1) * STSLOT,
                                                    rb_g2 + i * 64, rb_be2 + i * 64, src, bufY);
    }
    mfma_conv3<4, 0, 1, 64, 0, 0, 0><<<gmf, 256, 0, stream>>>(
        bufY, nullptr, WF + (size_t)32 * WFL, nullptr, nullptr, nullptr, nullptr,
        stats + 32 * STSLOT, nullptr, bufT);
    float* xT    = R4;
    float* d2out = R3;
    float* d3out = R4;
    bn_tx_kernel<<<2048, 256, 0, stream>>>(bufT, stats + 32 * STSLOT, bn2_g, bn2_be,
                                           bufX, bufX, xT);
    mfma_conv3<2, 0, 0, 27, 1, 0, 0><<<gmf, 256, 0, stream>>>(
        bufX, nullptr, WF + (size_t)33 * WFL, dc2_ob, nullptr, nullptr, nullptr,
        nullptr, nullptr, bufT);
    dcn_mfma<4, 0, 0><<<gmf, 256, 0, stream>>>(xT, bufT, WF + (size_t)36 * WFL, dc2_b,
                                               nullptr, nullptr, d2out, nullptr, nullptr);
    mfma_conv3<2, 0, 0, 27, 1, 0, 1><<<gmf, 256, 0, stream>>>(
        d2out, nullptr, WF + (size_t)34 * WFL, dc3_ob, nullptr, nullptr, nullptr,
        nullptr, nullptr, bufT);
    dcn_mfma<4, 0, 0><<<gmf, 256, 0, stream>>>(d2out, bufT, WF + (size_t)37 * WFL, dc3_b,
                                               nullptr, nullptr, d3out, nullptr, nullptr);
    mfma_conv3<2, 0, 0, 27, 1, 0, 1><<<gmf, 256, 0, stream>>>(
        d3out, nullptr, WF + (size_t)35 * WFL, dc4_ob, nullptr, nullptr, nullptr,
        nullptr, nullptr, bufT);
    dcn_mfma<1, 1, 0><<<gmf, 256, 0, stream>>>(d3out, bufT, WF + (size_t)38 * WFL, dc4_b,
                                               conv4_w, conv4_b, (float*)d_out,
                                               nullptr, nullptr);
  }
}

// Round 10
// 1981.963 us; speedup vs baseline: 1.2711x; 1.0222x over previous
//
#include <hip/hip_runtime.h>
#include <cmath>

typedef unsigned short ushort_t;
typedef __attribute__((ext_vector_type(8))) short bf16x8;
typedef __attribute__((ext_vector_type(4))) float f32x4;

// Problem constants (B=2, C=64, H=W=256)
static constexpr int Bn   = 2;
static constexpr int Hn   = 256;
static constexpr int Wn   = 256;
static constexpr int HW   = Hn * Wn;          // 65536
static constexpr int CHW  = 64 * HW;          // 4194304
static constexpr int NCHW = Bn * CHW;         // 8388608
static constexpr int NPIX = Bn * HW;          // 131072
static constexpr float EPSv = 1e-5f;
static constexpr float INV_N = 1.0f / 131072.0f;   // BN count = B*H*W
static constexpr int NSLOT = 64;              // stats slot replication (anti-contention)
static constexpr int STSLOT = NSLOT * 128;    // floats per layer stats region
static constexpr int WFL = 73728;             // ushorts per weight-fragment layer slot

// bf16 round-to-nearest-even (no NaN inputs in this net)
__device__ inline uint32_t bf16_rne(float f) {
  uint32_t u = __float_as_uint(f);
  return (u + 0x7FFFu + ((u >> 16) & 1u)) >> 16;
}
__device__ inline void split_hl(float v, uint32_t& h, uint32_t& l) {
  h = bf16_rne(v);
  l = bf16_rne(v - __uint_as_float(h << 16)) & 0xFFFFu;
}
// R24: packed two-term bf16 split via v_cvt_pk_bf16_f32 (1 instr converts+packs
// a pair). hi's rounding choice is absorbed by lo, so the 3-MFMA product is
// unchanged to 2^-16 regardless of tie behavior.
__device__ inline void split_pk(float s0, float s1, uint32_t& hpk, uint32_t& lpk) {
  uint32_t h, l;
  asm("v_cvt_pk_bf16_f32 %0, %1, %2" : "=v"(h) : "v"(s0), "v"(s1));
  float h0 = __uint_as_float(h << 16);
  float h1 = __uint_as_float(h & 0xffff0000u);
  asm("v_cvt_pk_bf16_f32 %0, %1, %2" : "=v"(l) : "v"(s0 - h0), "v"(s1 - h1));
  hpk = h; lpk = l;
}
__device__ inline bf16x8 lds_ld16(const ushort_t* p) {   // 2x ds_read_b64
  union { bf16x8 v; uint2 u[2]; } r;
  r.u[0] = *(const uint2*)p;
  r.u[1] = *(const uint2*)(p + 4);
  return r.v;
}

// async global->LDS, 16B per lane: LDS dest = wave-uniform base + lane*16,
// global src is per-lane (carries the XOR swizzle + OOB zero-page redirect).
typedef __attribute__((address_space(1))) const void glb_void;
typedef __attribute__((address_space(3))) void lds_void;
__device__ inline void gld_lds16(const void* g, void* l) {
  __builtin_amdgcn_global_load_lds((glb_void*)g, (lds_void*)l, 16, 0, 0);
}

// ---------------------------------------------------------------------------
__global__ void transpose_w_kernel(const float* __restrict__ in, float* __restrict__ out,
                                   int NB, int OC, int IC, int K) {
  int total = NB * OC * IC * K;
  for (int i = blockIdx.x * blockDim.x + threadIdx.x; i < total; i += gridDim.x * blockDim.x) {
    int k  = i % K;
    int t  = i / K;
    int ic = t % IC; t /= IC;
    int oc = t % OC;
    int nb = t / OC;
    out[(((size_t)nb * IC + ic) * K + k) * OC + oc] = in[i];
  }
}

// ---------------------------------------------------------------------------
// Weight fragment prep: w[oc][ic][3][3] f32 -> MFMA B-frag order, bf16 hi/lo.
__global__ void prep_wfrag(const float* __restrict__ w, ushort_t* __restrict__ out,
                           int NGp, int ocreal, int wlstride, int olstride) {
  int layer = blockIdx.y;
  int elems = 9 * 2 * NGp * 64 * 8;
  int idx = blockIdx.x * 256 + threadIdx.x;
  if (idx >= elems) return;
  int j = idx & 7, lane = (idx >> 3) & 63;
  int rest = idx >> 9;
  int g = rest % NGp; rest /= NGp;
  int ih = rest & 1, tap = rest >> 1;
  int oc = g * 16 + (lane & 15);
  int ic = ih * 32 + (lane >> 4) * 8 + j;
  float v = 0.0f;
  if (oc < ocreal) v = w[(size_t)layer * wlstride + (oc * 64 + ic) * 9 + tap];
  uint32_t hi, lo;
  split_hl(v, hi, lo);
  out[(size_t)layer * olstride + idx] = (ushort_t)hi;
  out[(size_t)layer * olstride + elems + idx] = (ushort_t)lo;
}

// ---------------------------------------------------------------------------
__global__ void prep_kernel(const float* __restrict__ LowDEM, const float* __restrict__ Point_Ele,
                            const float* __restrict__ Slope, const float* __restrict__ Distance,
                            const float* __restrict__ Level, const float* __restrict__ w0,
                            const float* __restrict__ b0, float* __restrict__ x0) {
  int i = blockIdx.x * blockDim.x + threadIdx.x;
  if (i >= NPIX) return;
  float lv  = Level[i];
  float err = w0[0] * Slope[i] + w0[1] * Distance[i] + w0[2] * lv + b0[0];
  float lm  = (lv != 0.0f) ? 1.0f : 0.0f;
  x0[i] = LowDEM[i] * (1.0f - lm) + Point_Ele[i] + err * lm;
}

// ---------------------------------------------------------------------------
// conv9x9: when hiP != nullptr (fused path) writes X in HWC fp32 layout AND
// the bf16 hi/lo HWC planes; else planar NCHW (legacy).
__global__ __launch_bounds__(256, 2)
void conv9x9_kernel(const float* __restrict__ in, const float* __restrict__ wT,
                    const float* __restrict__ bias, float* __restrict__ out,
                    uint32_t* __restrict__ hiP, uint32_t* __restrict__ loP) {
  const int tx = threadIdx.x & 15, ty = threadIdx.x >> 4;
  const int w0 = blockIdx.x * 16, h0 = blockIdx.y * 16, b = blockIdx.z;
  __shared__ float lds[24 * 24];
  for (int idx = threadIdx.x; idx < 576; idx += 256) {
    int yy = idx / 24, xx = idx - yy * 24;
    int gy = h0 + yy - 4, gx = w0 + xx - 4;
    float v = 0.0f;
    if ((unsigned)gy < 256u && (unsigned)gx < 256u) v = in[b * HW + gy * 256 + gx];
    lds[idx] = v;
  }
  __syncthreads();
  float acc[64];
#pragma unroll
  for (int o = 0; o < 64; o++) acc[o] = 0.0f;
#pragma unroll 1
  for (int i = 0; i < 9; i++) {
#pragma unroll
    for (int j = 0; j < 9; j++) {
      float v = lds[(ty + i) * 24 + tx + j];
      const float* wp = wT + (i * 9 + j) * 64;   // uniform -> s_load
#pragma unroll
      for (int o = 0; o < 64; o++) acc[o] = fmaf(v, wp[o], acc[o]);
    }
  }
  const int p = (h0 + ty) * 256 + (w0 + tx);
  if (hiP) {
    float* op = out + ((size_t)b * HW + p) * 64;      // HWC fp32
#pragma unroll
    for (int o4 = 0; o4 < 16; o4++) {
      float4 v;
      v.x = acc[o4 * 4 + 0] + bias[o4 * 4 + 0];
      v.y = acc[o4 * 4 + 1] + bias[o4 * 4 + 1];
      v.z = acc[o4 * 4 + 2] + bias[o4 * 4 + 2];
      v.w = acc[o4 * 4 + 3] + bias[o4 * 4 + 3];
      *(float4*)(op + o4 * 4) = v;
    }
    uint32_t* hb = hiP + ((size_t)b * HW + p) * 32;
    uint32_t* lb = loP + ((size_t)b * HW + p) * 32;
#pragma unroll
    for (int o2 = 0; o2 < 32; o2++) {
      float v0 = acc[o2 * 2] + bias[o2 * 2];
      float v1 = acc[o2 * 2 + 1] + bias[o2 * 2 + 1];
      uint32_t h0v, l0v, h1v, l1v;
      split_hl(v0, h0v, l0v);
      split_hl(v1, h1v, l1v);
      hb[o2] = h0v | (h1v << 16);
      lb[o2] = l0v | (l1v << 16);
    }
  } else {
    float* op = out + (size_t)b * CHW + p;            // planar (legacy)
#pragma unroll
    for (int o = 0; o < 64; o++) op[o * HW] = acc[o] + bias[o];
  }
}

// ---------------------------------------------------------------------------
// OLD-STYLE MFMA conv3x3 (VALU-transform staging). Legacy (small-ws) path.
// MODE 0 plain / 1 relu(bn) / 2 bn+skip (WRITEY: materialize y). INHWC:
// pixel-major input.
// ---------------------------------------------------------------------------
template <int NG, int MODE, int STATS, int OCLIM, int HASBIAS, int WRITEY, int INHWC>
__global__ __launch_bounds__(256, 3)
void mfma_conv3(const float* __restrict__ in, const float* __restrict__ skip,
                const ushort_t* __restrict__ wf,
                const float* __restrict__ bias, const float* __restrict__ stats_in,
                const float* __restrict__ gg, const float* __restrict__ be,
                float* __restrict__ stats_out, float* __restrict__ yout,
                float* __restrict__ out) {
  const int tid  = threadIdx.x;
  const int lane = tid & 63, wid = tid >> 6;
  const int m = lane & 15, quad = lane >> 4;
  const int x0 = blockIdx.x * 16, y0 = blockIdx.y * 4, b = blockIdx.z;
  constexpr int WT = 2 * NG * 64 * 8;          // ushorts per tap per plane
  __shared__ __align__(16) ushort_t xh[108 * 68];   // hi plane, [spat][ch]
  __shared__ __align__(16) ushort_t xl[108 * 68];   // lo plane
  __shared__ float s_sc[MODE ? 64 : 1], s_sh[MODE ? 64 : 1];
  __shared__ float red[STATS ? 2 * 4 * 64 : 1];
  if (MODE) {
    if (tid < 64) {
      float sum = 0.0f, sq = 0.0f;
      for (int sl = 0; sl < NSLOT; sl++) {
        sum += stats_in[sl * 128 + tid];
        sq  += stats_in[sl * 128 + 64 + tid];
      }
      float mn = sum * INV_N, var = sq * INV_N - mn * mn;
      float s = gg[tid] * rsqrtf(var + EPSv);
      s_sc[tid] = s;
      s_sh[tid] = be[tid] - mn * s;
    }
    __syncthreads();
  }
  const float* inb = in + (size_t)b * CHW;
  const float* skb = MODE == 2 ? skip + (size_t)b * CHW : nullptr;
  float* ytb = WRITEY ? yout + (size_t)b * CHW : nullptr;
  uint32_t* xh32 = (uint32_t*)xh;              // row stride 34 dwords
  uint32_t* xl32 = (uint32_t*)xl;
#pragma unroll
  for (int t = 0; t < 14; t++) {
    int idx = t * 256 + tid;                   // 3456 = 108 spat * 32 ic-pairs
    if (idx < 3456) {
      int r, icp;
      if (INHWC) { icp = idx & 31; r = idx >> 5; }   // tid-contig ic -> coalesced HWC
      else       { r = idx % 108; icp = idx / 108; } // tid-contig px -> coalesced NCHW
      int row = r / 18, col = r - row * 18;
      int gy = y0 - 1 + row, gx = x0 - 1 + col;
      float v0 = 0.0f, v1 = 0.0f;
      if ((unsigned)gy < 256u && (unsigned)gx < 256u) {
        int ic = icp * 2;
        if (INHWC) {
          float2 vv = *(const float2*)&inb[(size_t)(gy * 256 + gx) * 64 + ic];
          v0 = vv.x; v1 = vv.y;
        } else {
          v0 = inb[ic * HW + gy * 256 + gx];
          v1 = inb[(ic + 1) * HW + gy * 256 + gx];
        }
        if (MODE == 1) {
          v0 = fmaxf(fmaf(v0, s_sc[ic], s_sh[ic]), 0.0f);
          v1 = fmaxf(fmaf(v1, s_sc[ic + 1], s_sh[ic + 1]), 0.0f);
        }
        if (MODE == 2) {
          v0 = fmaf(v0, s_sc[ic], s_sh[ic]) + skb[ic * HW + gy * 256 + gx];
          v1 = fmaf(v1, s_sc[ic + 1], s_sh[ic + 1]) + skb[(ic + 1) * HW + gy * 256 + gx];
          if (WRITEY && row >= 1 && row <= 4 && col >= 1 && col <= 16) {
            ytb[ic * HW + gy * 256 + gx] = v0;
            ytb[(ic + 1) * HW + gy * 256 + gx] = v1;
          }
        }
      }
      uint32_t h0, l0, h1, l1;
      split_hl(v0, h0, l0);
      split_hl(v1, h1, l1);
      xh32[r * 34 + icp] = h0 | (h1 << 16);
      xl32[r * 34 + icp] = l0 | (l1 << 16);
    }
  }
  __syncthreads();                             // the ONLY barrier before epilogue
  f32x4 acc[NG];
#pragma unroll
  for (int g = 0; g < NG; g++) acc[g] = (f32x4){0.0f, 0.0f, 0.0f, 0.0f};

  const bf16x8* wfh = (const bf16x8*)wf;                 // hi plane, frag-ordered
  const bf16x8* wfl = (const bf16x8*)(wf + 9 * WT);      // lo plane

#pragma unroll 1
  for (int tap = 0; tap < 9; tap++) {
    bf16x8 bh[2][NG], bl[2][NG];
#pragma unroll
    for (int ih = 0; ih < 2; ih++)
#pragma unroll
      for (int g = 0; g < NG; g++) {
        int fi = ((tap * 2 + ih) * NG + g) * 64 + lane;
        bh[ih][g] = wfh[fi];
        bl[ih][g] = wfl[fi];
      }
    const int dy = tap / 3 - 1, dx = tap % 3 - 1;
    const int spat = (wid + dy + 1) * 18 + (m + dx + 1);
#pragma unroll
    for (int ih = 0; ih < 2; ih++) {
      const int base = spat * 68 + ih * 32 + quad * 8;
      bf16x8 ah = lds_ld16(xh + base);
      bf16x8 al = lds_ld16(xl + base);
#pragma unroll
      for (int g = 0; g < NG; g++) {
        acc[g] = __builtin_amdgcn_mfma_f32_16x16x32_bf16(ah, bh[ih][g], acc[g], 0, 0, 0);
        acc[g] = __builtin_amdgcn_mfma_f32_16x16x32_bf16(al, bh[ih][g], acc[g], 0, 0, 0);
        acc[g] = __builtin_amdgcn_mfma_f32_16x16x32_bf16(ah, bl[ih][g], acc[g], 0, 0, 0);
      }
    }
  }
  // epilogue: D[row=quad*4+r][col=lane&15] -> pixel (y0+wid, x0+quad*4+r), oc=g*16+m
  const int py = y0 + wid;
  float* ob = out + (size_t)b * OCLIM * HW + py * 256 + x0 + quad * 4;
#pragma unroll
  for (int g = 0; g < NG; g++) {
    int oc = g * 16 + m;
    if (oc < OCLIM) {
      float bv = HASBIAS ? bias[oc] : 0.0f;
#pragma unroll
      for (int r = 0; r < 4; r++) ob[oc * HW + r] = acc[g][r] + bv;
    }
    if (STATS) {
      float s  = acc[g][0] + acc[g][1] + acc[g][2] + acc[g][3];
      float s2 = acc[g][0] * acc[g][0] + acc[g][1] * acc[g][1] +
                 acc[g][2] * acc[g][2] + acc[g][3] * acc[g][3];
      s  += __shfl_xor(s, 16, 64);  s  += __shfl_xor(s, 32, 64);
      s2 += __shfl_xor(s2, 16, 64); s2 += __shfl_xor(s2, 32, 64);
      if (lane < 16) {
        red[(0 * 4 + wid) * 64 + g * 16 + lane] = s;
        red[(1 * 4 + wid) * 64 + g * 16 + lane] = s2;
      }
    }
  }
  if (STATS) {
    __syncthreads();
    if (tid < 128) {
      int oc = tid & 63, which = tid >> 6;
      float tot = red[(which * 4 + 0) * 64 + oc] + red[(which * 4 + 1) * 64 + oc] +
                  red[(which * 4 + 2) * 64 + oc] + red[(which * 4 + 3) * 64 + oc];
      int slot = (blockIdx.y * 16 + blockIdx.x) & (NSLOT - 1);
      atomicAdd(&stats_out[slot * 128 + which * 64 + oc], tot);
    }
  }
}

// ---------------------------------------------------------------------------
// R23 chain conv: DMA staging + 16x8 tile, 2-oc-group x 4-row wave split.
// (R22's 1x8 was LDS-read bound; 2x4 balances ds_reads vs weight L2.)
// Stats: direct atomicAdd per wave per group (no red buffer / 2nd barrier).
// ---------------------------------------------------------------------------
__global__ __launch_bounds__(256, 3)
void mfma_conv3_dma(const ushort_t* __restrict__ hiP, const ushort_t* __restrict__ loP,
                    const ushort_t* __restrict__ wf, const float* __restrict__ zeroPg,
                    float* __restrict__ stats_out, float* __restrict__ out) {
  const int tid  = threadIdx.x;
  const int lane = tid & 63, wid = tid >> 6;
  const int m = lane & 15, quad = lane >> 4;
  const int x0 = blockIdx.x * 16, y0 = blockIdx.y * 8, b = blockIdx.z;
  // 180 spats (18 cols x 10 rows) * 8 chunks(16B) per plane; hi then lo.
  __shared__ __align__(16) ushort_t xs[2880 * 8];   // 46080 B
  const size_t bimg = (size_t)b * HW;
  for (int g = wid; g < 45; g += 4) {
    int q  = g * 64 + lane;                 // 0..2879
    int pl = q >= 1440;
    int r  = q - (pl ? 1440 : 0);
    int s  = r >> 3, jl = r & 7;
    int js = jl ^ (s & 7);
    int row = s / 18, col = s - row * 18;
    int gy = y0 - 1 + row, gx = x0 - 1 + col;
    const ushort_t* src = (const ushort_t*)zeroPg;
    if ((unsigned)gy < 256u && (unsigned)gx < 256u)
      src = (pl ? loP : hiP) + ((bimg + (size_t)(gy * 256 + gx)) << 6) + (js << 3);
    gld_lds16(src, (void*)&xs[(size_t)g * 512]);
  }
  __syncthreads();                           // compiler drains vmcnt here

  const int gsel = wid >> 1;                 // oc-group pair: groups gsel*2+{0,1}
  const int rsel = (wid & 1) * 4;            // row base: 0 or 4
  f32x4 acc[4][2];
#pragma unroll
  for (int t = 0; t < 4; t++)
#pragma unroll
    for (int g = 0; g < 2; g++) acc[t][g] = (f32x4){0.0f, 0.0f, 0.0f, 0.0f};
  const bf16x8* wfh = (const bf16x8*)wf;
  const bf16x8* wfl8 = (const bf16x8*)(wf + 9 * 4096);   // WT = 2*4*64*8 = 4096

#pragma unroll 1
  for (int tap = 0; tap < 9; tap++) {
    bf16x8 bh[2][2], bl[2][2];
#pragma unroll
    for (int ih = 0; ih < 2; ih++)
#pragma unroll
      for (int g = 0; g < 2; g++) {
        int fi = ((tap * 2 + ih) * 4 + gsel * 2 + g) * 64 + lane;
        bh[ih][g] = wfh[fi];
        bl[ih][g] = wfl8[fi];
      }
    const int dy = tap / 3 - 1, dxx = tap % 3 - 1;
    const int scol = m + dxx + 1;
#pragma unroll
    for (int t = 0; t < 4; t++) {
      const int s  = (rsel + t + dy + 1) * 18 + scol;
      const int s7 = s & 7;
#pragma unroll
      for (int ih = 0; ih < 2; ih++) {
        const int ch = s * 8 + ((ih * 4 + quad) ^ s7);   // swizzled chunk
        bf16x8 ah = *(const bf16x8*)&xs[ch * 8];
        bf16x8 al = *(const bf16x8*)&xs[ch * 8 + 11520]; // lo plane (+1440 chunks)
#pragma unroll
        for (int g = 0; g < 2; g++) {
          acc[t][g] = __builtin_amdgcn_mfma_f32_16x16x32_bf16(ah, bh[ih][g], acc[t][g], 0, 0, 0);
          acc[t][g] = __builtin_amdgcn_mfma_f32_16x16x32_bf16(al, bh[ih][g], acc[t][g], 0, 0, 0);
          acc[t][g] = __builtin_amdgcn_mfma_f32_16x16x32_bf16(ah, bl[ih][g], acc[t][g], 0, 0, 0);
        }
      }
    }
  }
  // HWC epilogue: row y0+rsel+t, pixel col x0+quad*4+r, oc = gsel*32+g*16+m
  const int slot = (blockIdx.y * 16 + blockIdx.x) & (NSLOT - 1);
#pragma unroll
  for (int g = 0; g < 2; g++) {
    const int oc = gsel * 32 + g * 16 + m;
    float s = 0.0f, s2 = 0.0f;
#pragma unroll
    for (int t = 0; t < 4; t++) {
      const int py = y0 + rsel + t;
      float* ob = out + ((size_t)b * HW + (size_t)py * 256 + x0) * 64;
#pragma unroll
      for (int r = 0; r < 4; r++) {
        float v = acc[t][g][r];
        ob[(quad * 4 + r) * 64 + oc] = v;
        s += v;
        s2 += v * v;
      }
    }
    s  += __shfl_xor(s, 16, 64);  s  += __shfl_xor(s, 32, 64);
    s2 += __shfl_xor(s2, 16, 64); s2 += __shfl_xor(s2, 32, 64);
    if (lane < 16) {
      atomicAdd(&stats_out[slot * 128 + oc], s);
      atomicAdd(&stats_out[slot * 128 + 64 + oc], s2);
    }
  }
}

// ---------------------------------------------------------------------------
// Offset conv (dc2/dc3/dc4): DMA staging from bf16 hi/lo planes (16x8, same
// geometry as chain conv), NG=2, planar-27 epilogue with bias.
// ---------------------------------------------------------------------------
__global__ __launch_bounds__(256, 3)
void ofs_conv_dma(const ushort_t* __restrict__ hiP, const ushort_t* __restrict__ loP,
                  const ushort_t* __restrict__ wf, const float* __restrict__ zeroPg,
                  const float* __restrict__ bias, float* __restrict__ out) {
  const int tid  = threadIdx.x;
  const int lane = tid & 63, wid = tid >> 6;
  const int m = lane & 15, quad = lane >> 4;
  const int x0 = blockIdx.x * 16, y0 = blockIdx.y * 8, b = blockIdx.z;
  __shared__ __align__(16) ushort_t xs[2880 * 8];   // 46080 B
  const size_t bimg = (size_t)b * HW;
  for (int g = wid; g < 45; g += 4) {
    int q  = g * 64 + lane;
    int pl = q >= 1440;
    int r  = q - (pl ? 1440 : 0);
    int s  = r >> 3, jl = r & 7;
    int js = jl ^ (s & 7);
    int row = s / 18, col = s - row * 18;
    int gy = y0 - 1 + row, gx = x0 - 1 + col;
    const ushort_t* src = (const ushort_t*)zeroPg;
    if ((unsigned)gy < 256u && (unsigned)gx < 256u)
      src = (pl ? loP : hiP) + ((bimg + (size_t)(gy * 256 + gx)) << 6) + (js << 3);
    gld_lds16(src, (void*)&xs[(size_t)g * 512]);
  }
  __syncthreads();

  f32x4 acc[2][2];
#pragma unroll
  for (int t = 0; t < 2; t++)
#pragma unroll
    for (int g = 0; g < 2; g++) acc[t][g] = (f32x4){0.0f, 0.0f, 0.0f, 0.0f};
  const bf16x8* wfh = (const bf16x8*)wf;
  const bf16x8* wfl8 = (const bf16x8*)(wf + 9 * 2048);   // WT = 2*2*64*8 = 2048

#pragma unroll 1
  for (int tap = 0; tap < 9; tap++) {
    bf16x8 bh[2][2], bl[2][2];
#pragma unroll
    for (int ih = 0; ih < 2; ih++)
#pragma unroll
      for (int g = 0; g < 2; g++) {
        int fi = ((tap * 2 + ih) * 2 + g) * 64 + lane;
        bh[ih][g] = wfh[fi];
        bl[ih][g] = wfl8[fi];
      }
    const int dy = tap / 3 - 1, dxx = tap % 3 - 1;
    const int scol = m + dxx + 1;
#pragma unroll
    for (int t = 0; t < 2; t++) {
      const int s  = (wid * 2 + t + dy + 1) * 18 + scol;
      const int s7 = s & 7;
#pragma unroll
      for (int ih = 0; ih < 2; ih++) {
        const int ch = s * 8 + ((ih * 4 + quad) ^ s7);
        bf16x8 ah = *(const bf16x8*)&xs[ch * 8];
        bf16x8 al = *(const bf16x8*)&xs[ch * 8 + 11520];
#pragma unroll
        for (int g = 0; g < 2; g++) {
          acc[t][g] = __builtin_amdgcn_mfma_f32_16x16x32_bf16(ah, bh[ih][g], acc[t][g], 0, 0, 0);
          acc[t][g] = __builtin_amdgcn_mfma_f32_16x16x32_bf16(al, bh[ih][g], acc[t][g], 0, 0, 0);
          acc[t][g] = __builtin_amdgcn_mfma_f32_16x16x32_bf16(ah, bl[ih][g], acc[t][g], 0, 0, 0);
        }
      }
    }
  }
  // planar epilogue (om layout [B][27][HW] kept for dcn's coalesced om reads)
#pragma unroll
  for (int g = 0; g < 2; g++) {
    int oc = g * 16 + m;
    if (oc < 27) {
      float bv = bias[oc];
#pragma unroll
      for (int t = 0; t < 2; t++) {
        const int py = y0 + wid * 2 + t;
        float* ob = out + (size_t)b * 27 * HW + (size_t)oc * HW + py * 256 + x0 + quad * 4;
#pragma unroll
        for (int r = 0; r < 4; r++) ob[r] = acc[t][g][r] + bv;
      }
    }
  }
}

// ---------------------------------------------------------------------------
// R17 transform: all-HWC streaming. Finalize BN of raw conv out t (HWC) and
// materialize bf16 hi/lo HWC planes. TMODE 1: relu(bn(t)) -> planes only.
// TMODE 2: y = bn(t)+skip -> y fp32 HWC + planes. Parallel stats preamble.
// ---------------------------------------------------------------------------
template <int TMODE>
__global__ __launch_bounds__(256, 8)
void bn_split_hwc(const float* __restrict__ t, const float* __restrict__ stats,
                  const float* __restrict__ g, const float* __restrict__ be,
                  const float* __restrict__ skip, float* __restrict__ yout,
                  uint32_t* __restrict__ hiP, uint32_t* __restrict__ loP) {
  __shared__ float part[2][4][64];
  __shared__ float s_sc[64], s_sh[64];
  const int tid = threadIdx.x;
  {
    int c = tid & 63, q = tid >> 6;
    float sum = 0.0f, sq = 0.0f;
    for (int sl = q * 16; sl < q * 16 + 16; sl++) {
      sum += stats[sl * 128 + c];
      sq  += stats[sl * 128 + 64 + c];
    }
    part[0][q][c] = sum;
    part[1][q][c] = sq;
  }
  __syncthreads();
  if (tid < 64) {
    int c = tid;
    float sum = part[0][0][c] + part[0][1][c] + part[0][2][c] + part[0][3][c];
    float sq  = part[1][0][c] + part[1][1][c] + part[1][2][c] + part[1][3][c];
    float mn  = sum * INV_N;
    float var = sq * INV_N - mn * mn;
    float s   = g[c] * rsqrtf(var + EPSv);
    s_sc[c] = s;
    s_sh[c] = be[c] - mn * s;
  }
  __syncthreads();
  const int blk = blockIdx.x;            // 2048 = NPIX/64
  const int b  = blk >> 10;
  const int p0 = (blk & 1023) * 64;
  const size_t base = ((size_t)b * HW + p0) * 64;   // floats (HWC)
  uint32_t* hb = hiP + ((size_t)b * HW + p0) * 32;
  uint32_t* lb = loP + ((size_t)b * HW + p0) * 32;
#pragma unroll
  for (int i = 0; i < 8; i++) {
    int idx = i * 256 + tid;             // 0..2047 = 64 px * 32 ch-pairs
    int p = idx >> 5, c2 = idx & 31;
    size_t off = base + (size_t)p * 64 + c2 * 2;
    float2 v = *(const float2*)&t[off];
    float v0 = fmaf(v.x, s_sc[c2 * 2],     s_sh[c2 * 2]);
    float v1 = fmaf(v.y, s_sc[c2 * 2 + 1], s_sh[c2 * 2 + 1]);
    if (TMODE == 1) {
      v0 = fmaxf(v0, 0.0f);
      v1 = fmaxf(v1, 0.0f);
    } else {
      float2 k = *(const float2*)&skip[off];
      v0 += k.x; v1 += k.y;
      float2 y2; y2.x = v0; y2.y = v1;
      *(float2*)&yout[off] = y2;
    }
    uint32_t h0v, l0v, h1v, l1v;
    split_hl(v0, h0v, l0v);
    split_hl(v1, h1v, l1v);
    hb[p * 32 + c2] = h0v | (h1v << 16);
    lb[p * 32 + c2] = l0v | (l1v << 16);
  }
}

// ---------------------------------------------------------------------------
// R20: x = bn(t)+skip, all-HWC streaming; also emits x's bf16 hi/lo planes
// (feeds the DMA offset conv for dc2).
// ---------------------------------------------------------------------------
__global__ __launch_bounds__(256, 8)
void bn_add_hwc(const float* __restrict__ t, const float* __restrict__ stats,
                const float* __restrict__ g, const float* __restrict__ be,
                const float* __restrict__ skip, float* __restrict__ xout,
                uint32_t* __restrict__ hiP, uint32_t* __restrict__ loP) {
  __shared__ float part[2][4][64];
  __shared__ float s_sc[64], s_sh[64];
  const int tid = threadIdx.x;
  {
    int c = tid & 63, q = tid >> 6;
    float sum = 0.0f, sq = 0.0f;
    for (int sl = q * 16; sl < q * 16 + 16; sl++) {
      sum += stats[sl * 128 + c];
      sq  += stats[sl * 128 + 64 + c];
    }
    part[0][q][c] = sum;
    part[1][q][c] = sq;
  }
  __syncthreads();
  if (tid < 64) {
    int c = tid;
    float sum = part[0][0][c] + part[0][1][c] + part[0][2][c] + part[0][3][c];
    float sq  = part[1][0][c] + part[1][1][c] + part[1][2][c] + part[1][3][c];
    float mn  = sum * INV_N;
    float var = sq * INV_N - mn * mn;
    float s   = g[c] * rsqrtf(var + EPSv);
    s_sc[c] = s;
    s_sh[c] = be[c] - mn * s;
  }
  __syncthreads();
  const int blk = blockIdx.x;            // 2048
  const int b  = blk >> 10;
  const int p0 = (blk & 1023) * 64;
  const size_t base4 = (((size_t)b * HW + p0) * 64) >> 2;   // float4 units
  const float4* t4 = (const float4*)t;
  const float4* k4 = (const float4*)skip;
  float4* x4 = (float4*)xout;
  uint32_t* hb = hiP + ((size_t)b * HW + p0) * 32;
  uint32_t* lb = loP + ((size_t)b * HW + p0) * 32;
#pragma unroll
  for (int i = 0; i < 4; i++) {
    int idx = i * 256 + tid;             // 0..1023 = 64 px * 16 ch-quads
    int c = (idx & 15) * 4;
    int p = idx >> 4;
    float4 v = t4[base4 + idx], k = k4[base4 + idx], r;
    r.x = fmaf(v.x, s_sc[c],     s_sh[c])     + k.x;
    r.y = fmaf(v.y, s_sc[c + 1], s_sh[c + 1]) + k.y;
    r.z = fmaf(v.z, s_sc[c + 2], s_sh[c + 2]) + k.z;
    r.w = fmaf(v.w, s_sc[c + 3], s_sh[c + 3]) + k.w;
    x4[base4 + idx] = r;
    uint32_t h0v, l0v, h1v, l1v, h2v, l2v, h3v, l3v;
    split_hl(r.x, h0v, l0v); split_hl(r.y, h1v, l1v);
    split_hl(r.z, h2v, l2v); split_hl(r.w, h3v, l3v);
    uint2 hv = make_uint2(h0v | (h1v << 16), h2v | (h3v << 16));
    uint2 lv = make_uint2(l0v | (l1v << 16), l2v | (l3v << 16));
    *(uint2*)&hb[p * 32 + (c >> 1)] = hv;
    *(uint2*)&lb[p * 32 + (c >> 1)] = lv;
  }
}

// ---------------------------------------------------------------------------
// Legacy path only: y = BN(t)*g+be + skip (float4).
// ---------------------------------------------------------------------------
__global__ void bn_apply_add_kernel(const float* __restrict__ t, const float* __restrict__ stats,
                                    const float* __restrict__ g, const float* __restrict__ be,
                                    const float* __restrict__ skip, float* __restrict__ out) {
  __shared__ float s_sc[64], s_sh[64];
  if (threadIdx.x < 64) {
    int c = threadIdx.x;
    float sum = 0.0f, sq = 0.0f;
    for (int sl = 0; sl < NSLOT; sl++) {
      sum += stats[sl * 128 + c];
      sq  += stats[sl * 128 + 64 + c];
    }
    float m   = sum * INV_N;
    float var = sq * INV_N - m * m;
    float s   = g[c] * rsqrtf(var + EPSv);
    s_sc[c] = s;
    s_sh[c] = be[c] - m * s;
  }
  __syncthreads();
  const float4* t4 = (const float4*)t;
  const float4* k4 = (const float4*)skip;
  float4* o4 = (float4*)out;
  const int n4 = NCHW / 4;
  for (int i = blockIdx.x * blockDim.x + threadIdx.x; i < n4; i += gridDim.x * blockDim.x) {
    int c = (i >> 14) & 63;
    float s = s_sc[c], h = s_sh[c];
    float4 v = t4[i], kk = k4[i], r;
    r.x = fmaf(v.x, s, h) + kk.x;
    r.y = fmaf(v.y, s, h) + kk.y;
    r.z = fmaf(v.z, s, h) + kk.z;
    r.w = fmaf(v.w, s, h) + kk.w;
    o4[i] = r;
  }
}

// ---------------------------------------------------------------------------
// Legacy path only: fused x = bn(t)+skip -> planar out AND HWC mirror.
// ---------------------------------------------------------------------------
__global__ __launch_bounds__(256, 4)
void bn_tx_kernel(const float* __restrict__ t, const float* __restrict__ stats,
                  const float* __restrict__ g, const float* __restrict__ be,
                  const float* __restrict__ skip, float* __restrict__ outP,
                  float* __restrict__ outHWC) {
  __shared__ float tile[64][65];
  __shared__ float s_sc[64], s_sh[64];
  if (threadIdx.x < 64) {
    int c = threadIdx.x;
    float sum = 0.0f, sq = 0.0f;
    for (int sl = 0; sl < NSLOT; sl++) {
      sum += stats[sl * 128 + c];
      sq  += stats[sl * 128 + 64 + c];
    }
    float m   = sum * INV_N;
    float var = sq * INV_N - m * m;
    float s   = g[c] * rsqrtf(var + EPSv);
    s_sc[c] = s;
    s_sh[c] = be[c] - m * s;
  }
  __syncthreads();
  const int blk = blockIdx.x;            // 2048 = NPIX/64
  const int b = blk >> 10;
  const int p0 = (blk & 1023) * 64;
  const float* tb = t + (size_t)b * CHW;
  const float* kb = skip + (size_t)b * CHW;
  float* oP = outP + (size_t)b * CHW;
  float* oH = outHWC + (size_t)b * CHW;
#pragma unroll
  for (int i = 0; i < 16; i++) {
    int idx = i * 256 + threadIdx.x;
    int c = idx >> 6, p = idx & 63;
    float v = fmaf(tb[c * HW + p0 + p], s_sc[c], s_sh[c]) + kb[c * HW + p0 + p];
    oP[c * HW + p0 + p] = v;
    tile[c][p] = v;
  }
  __syncthreads();
#pragma unroll
  for (int i = 0; i < 16; i++) {
    int idx = i * 256 + threadIdx.x;
    int p = idx >> 6, c = idx & 63;
    oH[(size_t)(p0 + p) * 64 + c] = tile[c][p];
  }
}

// ---------------------------------------------------------------------------
// Deformable conv on MFMA, HWC input. R21 structure (quad-per-pixel gather,
// double-buffered LDS, 1 barrier/tap). R24: split/pack in the gather uses
// v_cvt_pk_bf16_f32 (1 instr converts+packs a pair) — split math 24 -> 6
// ops/pair; kernel was VALU-bound (50% VALUBusy). PLANES: epilogue also emits
// relu output's bf16 hi/lo planes. FINAL: fuse dc4 bias + conv4.
// ---------------------------------------------------------------------------
template <int NG, int FINAL, int PLANES>
__global__ __launch_bounds__(256, 4)
void dcn_mfma(const float* __restrict__ xhwc, const float* __restrict__ om,
              const ushort_t* __restrict__ wf, const float* __restrict__ bias,
              const float* __restrict__ c4w, const float* __restrict__ c4b,
              float* __restrict__ out,
              ushort_t* __restrict__ hiO, ushort_t* __restrict__ loO) {
  const int tid  = threadIdx.x;
  const int lane = tid & 63, wid = tid >> 6;
  const int m = lane & 15, quad = lane >> 4;
  const int x0 = blockIdx.x * 16, y0 = blockIdx.y * 4, b = blockIdx.z;
  constexpr int WT = 2 * NG * 64 * 8;
  __shared__ __align__(16) ushort_t sh[2][64 * 64];   // hi plane per buffer, 8 KB
  __shared__ __align__(16) ushort_t sl[2][64 * 64];   // lo plane
  const int gp = tid >> 2, c4 = tid & 3;       // gather role: pixel, 16B-chunk lane
  const int gpy = y0 + (gp >> 4), gxx = x0 + (gp & 15);
  const int psw = gp & 3;                      // pixel swizzle bits
  const float* xb  = xhwc + (size_t)b * CHW;
  const float* omb = om + (size_t)b * 27 * HW + gpy * 256 + gxx;

  auto gather = [&](int tap, int buf) {
    float dyv = omb[tap * HW];
    float dxv = omb[(9 + tap) * HW];
    float mo  = omb[(18 + tap) * HW];
    float mk  = 1.0f / (1.0f + __expf(-mo));
    float ys = fminf(fmaxf((float)(gpy + tap / 3 - 1) + dyv, -2.0f), 258.0f);
    float xs = fminf(fmaxf((float)(gxx + tap % 3 - 1) + dxv, -2.0f), 258.0f);
    float y0f = floorf(ys), x0f = floorf(xs);
    float wy = ys - y0f, wx = xs - x0f;
    int yi = (int)y0f, xi = (int)x0f;
    float vy0 = ((unsigned)yi       < 256u) ? 1.0f : 0.0f;
    float vy1 = ((unsigned)(yi + 1) < 256u) ? 1.0f : 0.0f;
    float vx0 = ((unsigned)xi       < 256u) ? 1.0f : 0.0f;
    float vx1 = ((unsigned)(xi + 1) < 256u) ? 1.0f : 0.0f;
    int cy0 = min(max(yi, 0), 255), cy1 = min(max(yi + 1, 0), 255);
    int cx0 = min(max(xi, 0), 255), cx1 = min(max(xi + 1, 0), 255);
    float W00 = (1.0f - wy) * (1.0f - wx) * mk * vy0 * vx0;
    float W01 = (1.0f - wy) * wx * mk * vy0 * vx1;
    float W10 = wy * (1.0f - wx) * mk * vy1 * vx0;
    float W11 = wy * wx * mk * vy1 * vx1;
    const float* p00 = xb + (size_t)(cy0 * 256 + cx0) * 64;
    const float* p01 = xb + (size_t)(cy0 * 256 + cx1) * 64;
    const float* p10 = xb + (size_t)(cy1 * 256 + cx0) * 64;
    const float* p11 = xb + (size_t)(cy1 * 256 + cx1) * 64;
#pragma unroll
    for (int j = 0; j < 4; j++) {
      const int k = c4 + 4 * j;                // 4-ch chunk index 0..15
      float4 a  = *(const float4*)(p00 + k * 4);
      float4 b2 = *(const float4*)(p01 + k * 4);
      float4 c2 = *(const float4*)(p10 + k * 4);
      float4 d2 = *(const float4*)(p11 + k * 4);
      float s0 = W00 * a.x + W01 * b2.x + W10 * c2.x + W11 * d2.x;
      float s1 = W00 * a.y + W01 * b2.y + W10 * c2.y + W11 * d2.y;
      float s2 = W00 * a.z + W01 * b2.z + W10 * c2.z + W11 * d2.z;
      float s3 = W00 * a.w + W01 * b2.w + W10 * c2.w + W11 * d2.w;
      uint32_t h01, l01, h23, l23;
      split_pk(s0, s1, h01, l01);
      split_pk(s2, s3, h23, l23);
      // chunk k lives at group (k>>2)=j, sub (k&3)=c4 -> same layout as before
      int wi = gp * 64 + ((j ^ psw) * 16) + c4 * 4;   // 8B-aligned
      *(uint2*)&sh[buf][wi] = make_uint2(h01, h23);
      *(uint2*)&sl[buf][wi] = make_uint2(l01, l23);
    }
  };

  f32x4 acc[NG];
#pragma unroll
  for (int g = 0; g < NG; g++) acc[g] = (f32x4){0.0f, 0.0f, 0.0f, 0.0f};
  const bf16x8* wfh = (const bf16x8*)wf;
  const bf16x8* wfl = (const bf16x8*)(wf + 9 * WT);
  const int px = wid * 16 + m;                 // this lane's A-row pixel

  gather(0, 0);
  __syncthreads();
#pragma unroll 1
  for (int tap = 0; tap < 9; tap++) {
    const int cur = tap & 1;
    if (tap < 8) gather(tap + 1, cur ^ 1);     // overlaps MFMAs below
#pragma unroll
    for (int ih = 0; ih < 2; ih++) {
      const int c = ih * 2 + (quad >> 1), h = quad & 1;
      const int ri = px * 64 + ((c ^ (px & 3)) * 16) + h * 8;   // 16B-aligned
      bf16x8 ah = *(const bf16x8*)&sh[cur][ri];
      bf16x8 al = *(const bf16x8*)&sl[cur][ri];
#pragma unroll
      for (int g = 0; g < NG; g++) {
        int fi = ((tap * 2 + ih) * NG + g) * 64 + lane;
        bf16x8 bh = wfh[fi], bl = wfl[fi];
        acc[g] = __builtin_amdgcn_mfma_f32_16x16x32_bf16(ah, bh, acc[g], 0, 0, 0);
        acc[g] = __builtin_amdgcn_mfma_f32_16x16x32_bf16(al, bh, acc[g], 0, 0, 0);
        acc[g] = __builtin_amdgcn_mfma_f32_16x16x32_bf16(ah, bl, acc[g], 0, 0, 0);
      }
    }
    __syncthreads();   // writes to buf^1 and reads of cur both done
  }
  const int py = y0 + wid;
  if (FINAL) {
    if (m == 0) {
      float* op = out + (size_t)b * HW + py * 256 + x0 + quad * 4;
#pragma unroll
      for (int r = 0; r < 4; r++) op[r] = c4w[0] * (acc[0][r] + bias[0]) + c4b[0];
    }
  } else {
    size_t pbase = ((size_t)b * HW + (size_t)py * 256 + x0 + quad * 4) * 64 + m;
    float* ob = out + pbase;
#pragma unroll
    for (int g = 0; g < NG; g++)
#pragma unroll
      for (int r = 0; r < 4; r++) {
        float v = fmaxf(acc[g][r] + bias[g * 16 + m], 0.0f);
        ob[r * 64 + g * 16] = v;
        if (PLANES) {
          uint32_t h, l;
          split_hl(v, h, l);
          hiO[pbase + r * 64 + g * 16] = (ushort_t)h;
          loO[pbase + r * 64 + g * 16] = (ushort_t)l;
        }
      }
  }
}

// ---------------------------------------------------------------------------
extern "C" void kernel_launch(void* const* d_in, const int* in_sizes, int n_in,
                              void* d_out, int out_size, void* d_ws, size_t ws_size,
                              hipStream_t stream) {
  const float* LowDEM    = (const float*)d_in[0];
  const float* Point_Ele = (const float*)d_in[1];
  const float* Slope     = (const float*)d_in[2];
  const float* Distance  = (const float*)d_in[3];
  const float* Level     = (const float*)d_in[4];
  const float* conv0_w   = (const float*)d_in[5];
  const float* conv0_b   = (const float*)d_in[6];
  const float* conv1_w   = (const float*)d_in[7];
  const float* conv1_b   = (const float*)d_in[8];
  const float* rb_w1     = (const float*)d_in[9];
  const float* rb_g1     = (const float*)d_in[11];
  const float* rb_be1    = (const float*)d_in[12];
  const float* rb_w2     = (const float*)d_in[13];
  const float* rb_g2     = (const float*)d_in[15];
  const float* rb_be2    = (const float*)d_in[16];
  const float* conv2_w   = (const float*)d_in[17];
  const float* bn2_g     = (const float*)d_in[19];
  const float* bn2_be    = (const float*)d_in[20];
  const float* dc2_w     = (const float*)d_in[21];
  const float* dc2_b     = (const float*)d_in[22];
  const float* dc2_ow    = (const float*)d_in[23];
  const float* dc2_ob    = (const float*)d_in[24];
  const float* dc3_w     = (const float*)d_in[25];
  const float* dc3_b     = (const float*)d_in[26];
  const float* dc3_ow    = (const float*)d_in[27];
  const float* dc3_ob    = (const float*)d_in[28];
  const float* dc4_w     = (const float*)d_in[29];
  const float* dc4_b     = (const float*)d_in[30];
  const float* dc4_ow    = (const float*)d_in[31];
  const float* dc4_ob    = (const float*)d_in[32];
  const float* conv4_w   = (const float*)d_in[33];
  const float* conv4_b   = (const float*)d_in[34];

  // small region first, then big buffers
  float* x0   = (float*)d_ws;             // 131072
  float* T1   = x0 + NPIX;                // 5184
  ushort_t* WF = (ushort_t*)(T1 + 5184);  // 39 * WFL ushorts
  float* stats = (float*)(WF + 39 * WFL); // 33 * STSLOT floats
  float* zpg   = stats + 33 * STSLOT;     // 32 floats: DMA zero page
  float* big   = zpg + 32;
  size_t used_small = (size_t)((char*)big - (char*)d_ws);
  bool fused = ws_size >= used_small + 5ull * NCHW * sizeof(float);

  float* bufX = big;                      // X (conv9x9 out; skip for bn2)
  float* bufT = bufX + NCHW;              // raw conv out / offset-conv out
  float* R3   = bufT + NCHW;              // fused: yA   | legacy: bufT2
  float* R4   = R3 + NCHW;                // fused: yB   | legacy: yA(=yB)
  ushort_t* hiP = (ushort_t*)(R4 + NCHW); // fused only: bf16 hi plane (HWC)
  ushort_t* loP = hiP + NCHW;             //             bf16 lo plane (HWC)

  hipMemsetAsync(stats, 0, 33 * STSLOT * sizeof(float), stream);
  hipMemsetAsync(zpg, 0, 128, stream);

  transpose_w_kernel<<<32, 256, 0, stream>>>(conv1_w, T1, 1, 64, 1, 81);

  prep_wfrag<<<dim3(144, 16), 256, 0, stream>>>(rb_w1,   WF,            4, 64, 36864, WFL);
  prep_wfrag<<<dim3(144, 16), 256, 0, stream>>>(rb_w2,   WF + 16 * WFL, 4, 64, 36864, WFL);
  prep_wfrag<<<dim3(144, 1),  256, 0, stream>>>(conv2_w, WF + 32 * WFL, 4, 64, 36864, WFL);
  prep_wfrag<<<dim3(72, 1),   256, 0, stream>>>(dc2_ow,  WF + 33 * WFL, 2, 27, 15552, WFL);
  prep_wfrag<<<dim3(72, 1),   256, 0, stream>>>(dc3_ow,  WF + 34 * WFL, 2, 27, 15552, WFL);
  prep_wfrag<<<dim3(72, 1),   256, 0, stream>>>(dc4_ow,  WF + 35 * WFL, 2, 27, 15552, WFL);
  prep_wfrag<<<dim3(144, 1),  256, 0, stream>>>(dc2_w,   WF + 36 * WFL, 4, 64, 36864, WFL);
  prep_wfrag<<<dim3(144, 1),  256, 0, stream>>>(dc3_w,   WF + 37 * WFL, 4, 64, 36864, WFL);
  prep_wfrag<<<dim3(36, 1),   256, 0, stream>>>(dc4_w,   WF + 38 * WFL, 1, 1, 576, WFL);

  prep_kernel<<<(NPIX + 255) / 256, 256, 0, stream>>>(LowDEM, Point_Ele, Slope, Distance,
                                                      Level, conv0_w, conv0_b, x0);

  dim3 grid16(16, 16, 2);   // conv9x9
  dim3 gmf(16, 64, 2);      // dcn_mfma / legacy conv (16x4 pixel tiles)
  dim3 gmf8(16, 32, 2);     // chain conv / ofs conv (16x8 pixel tiles)

  conv9x9_kernel<<<grid16, 256, 0, stream>>>(x0, T1, conv1_b, bufX,
                                             fused ? (uint32_t*)hiP : nullptr,
                                             fused ? (uint32_t*)loP : nullptr);

  if (fused) {
    float* yA = R3;
    float* yB = R4;
    // R23: all-HWC chain — 2x4-split DMA convs + streaming bn/split.
    for (int i = 0; i < 16; i++) {
      mfma_conv3_dma<<<gmf8, 256, 0, stream>>>(hiP, loP, WF + (size_t)i * WFL, zpg,
                                               stats + (size_t)(2 * i) * STSLOT, bufT);
      bn_split_hwc<1><<<2048, 256, 0, stream>>>(
          bufT, stats + (size_t)(2 * i) * STSLOT, rb_g1 + i * 64, rb_be1 + i * 64,
          nullptr, nullptr, (uint32_t*)hiP, (uint32_t*)loP);
      mfma_conv3_dma<<<gmf8, 256, 0, stream>>>(hiP, loP, WF + (size_t)(16 + i) * WFL, zpg,
                                               stats + (size_t)(2 * i + 1) * STSLOT, bufT);
      const float* skp = (i == 0) ? bufX : ((i & 1) ? yA : yB);   // y_i
      float* yo = (i & 1) ? yB : yA;                              // y_{i+1}
      bn_split_hwc<2><<<2048, 256, 0, stream>>>(
          bufT, stats + (size_t)(2 * i + 1) * STSLOT, rb_g2 + i * 64, rb_be2 + i * 64,
          skp, yo, (uint32_t*)hiP, (uint32_t*)loP);
    }
    mfma_conv3_dma<<<gmf8, 256, 0, stream>>>(hiP, loP, WF + (size_t)32 * WFL, zpg,
                                             stats + (size_t)32 * STSLOT, bufT);

    float* xT    = R4;          // y16 fp32 dead (its planes fed conv2)
    float* d2out = R3;          // yA dead after i=15
    float* d3out = bufX;        // X dead after bn_add_hwc below
    // x = bn(conv2_out) + X -> xT (HWC) + x planes (for dc2's offset conv)
    bn_add_hwc<<<2048, 256, 0, stream>>>(bufT, stats + 32 * STSLOT, bn2_g, bn2_be,
                                         bufX, xT, (uint32_t*)hiP, (uint32_t*)loP);
    // dc2: DMA offset conv from x planes; dcn emits d2out fp32 + planes
    ofs_conv_dma<<<gmf8, 256, 0, stream>>>(hiP, loP, WF + (size_t)33 * WFL, zpg,
                                           dc2_ob, bufT);
    dcn_mfma<4, 0, 1><<<gmf, 256, 0, stream>>>(xT, bufT, WF + (size_t)36 * WFL, dc2_b,
                                               nullptr, nullptr, d2out, hiP, loP);
    // dc3: DMA offset conv from d2out planes; dcn emits d3out fp32 + planes
    ofs_conv_dma<<<gmf8, 256, 0, stream>>>(hiP, loP, WF + (size_t)34 * WFL, zpg,
                                           dc3_ob, bufT);
    dcn_mfma<4, 0, 1><<<gmf, 256, 0, stream>>>(d2out, bufT, WF + (size_t)37 * WFL, dc3_b,
                                               nullptr, nullptr, d3out, hiP, loP);
    // dc4 + conv4 -> d_out (offset conv from d3out planes)
    ofs_conv_dma<<<gmf8, 256, 0, stream>>>(hiP, loP, WF + (size_t)35 * WFL, zpg,
                                           dc4_ob, bufT);
    dcn_mfma<1, 1, 0><<<gmf, 256, 0, stream>>>(d3out, bufT, WF + (size_t)38 * WFL, dc4_b,
                                               conv4_w, conv4_b, (float*)d_out,
                                               nullptr, nullptr);
  } else {
    float* bufT2 = R3;
    float* bufY  = R4;
    for (int i = 0; i < 16; i++) {
      const float* src = (i == 0) ? bufX : bufY;
      mfma_conv3<4, 0, 1, 64, 0, 0, 0><<<gmf, 256, 0, stream>>>(
          src, nullptr, WF + (size_t)i * WFL, nullptr, nullptr, nullptr, nullptr,
          stats + (2 * i) * STSLOT, nullptr, bufT);
      mfma_conv3<4, 1, 1, 64, 0, 0, 0><<<gmf, 256, 0, stream>>>(
          bufT, nullptr, WF + (size_t)(16 + i) * WFL, nullptr, stats + (2 * i) * STSLOT,
          rb_g1 + i * 64, rb_be1 + i * 64, stats + (2 * i + 1) * STSLOT, nullptr, bufT2);
      bn_apply_add_kernel<<<2048, 256, 0, stream>>>(bufT2, stats + (2 * i + 1) * STSLOT,
                                                    rb_g2 + i * 64, rb_be2 + i * 64, src, bufY);
    }
    mfma_conv3<4, 0, 1, 64, 0, 0, 0><<<gmf, 256, 0, stream>>>(
        bufY, nullptr, WF + (size_t)32 * WFL, nullptr, nullptr, nullptr, nullptr,
        stats + 32 * STSLOT, nullptr, bufT);
    float* xT    = R4;
    float* d2out = R3;
    float* d3out = R4;
    bn_tx_kernel<<<2048, 256, 0, stream>>>(bufT, stats + 32 * STSLOT, bn2_g, bn2_be,
                                           bufX, bufX, xT);
    mfma_conv3<2, 0, 0, 27, 1, 0, 0><<<gmf, 256, 0, stream>>>(
        bufX, nullptr, WF + (size_t)33 * WFL, dc2_ob, nullptr, nullptr, nullptr,
        nullptr, nullptr, bufT);
    dcn_mfma<4, 0, 0><<<gmf, 256, 0, stream>>>(xT, bufT, WF + (size_t)36 * WFL, dc2_b,
                                               nullptr, nullptr, d2out, nullptr, nullptr);
    mfma_conv3<2, 0, 0, 27, 1, 0, 1><<<gmf, 256, 0, stream>>>(
        d2out, nullptr, WF + (size_t)34 * WFL, dc3_ob, nullptr, nullptr, nullptr,
        nullptr, nullptr, bufT);
    dcn_mfma<4, 0, 0><<<gmf, 256, 0, stream>>>(d2out, bufT, WF + (size_t)37 * WFL, dc3_b,
                                               nullptr, nullptr, d3out, nullptr, nullptr);
    mfma_conv3<2, 0, 0, 27, 1, 0, 1><<<gmf, 256, 0, stream>>>(
        d3out, nullptr, WF + (size_t)35 * WFL, dc4_ob, nullptr, nullptr, nullptr,
        nullptr, nullptr, bufT);
    dcn_mfma<1, 1, 0><<<gmf, 256, 0, stream>>>(d3out, bufT, WF + (size_t)38 * WFL, dc4_b,
                                               conv4_w, conv4_b, (float*)d_out,
                                               nullptr, nullptr);
  }
}